// Round 5
// baseline (2245.924 us; speedup 1.0000x reference)
//
#include <hip/hip_runtime.h>
#include <hip/hip_bf16.h>

typedef __hip_bfloat16 bf16_t;
typedef __attribute__((ext_vector_type(8))) short short8;
typedef __attribute__((ext_vector_type(16))) float floatx16;

static __device__ __forceinline__ float b2f(bf16_t v) { return __bfloat162float(v); }
static __device__ __forceinline__ bf16_t f2b(float v) { return __float2bfloat16(v); }
static __device__ __forceinline__ float us2f(unsigned short u) {
    union { unsigned int i; float f; } c; c.i = ((unsigned int)u) << 16; return c.f;
}

// Problem constants
#define NN 50000
#define EE 200000
#define GG 2048
#define BCAP 64   // in-degree cap; mean deg = 4

union U4 { uint4 v; unsigned short s[8]; };

#define FZ16 {0.f,0.f,0.f,0.f,0.f,0.f,0.f,0.f,0.f,0.f,0.f,0.f,0.f,0.f,0.f,0.f}

// 32x32x16 fragment-major layout (A and B operands share it):
//   element (i, k) of an [I x K] K-major matrix lives at
//   ((i/32 * (K/16) + k/16) * 64 + ((k%16)/8)*32 + i%32) * 8 + k%8
// One wave fragment = 64 lanes x short8 = contiguous 1KB.

// ---------------------------------------------------------------------------
// Merged setup: inverted adjacency build + all 4 weight packs in ONE launch
// ---------------------------------------------------------------------------
__device__ __forceinline__ void pack_w1_body(const float* __restrict__ Wa,
                                             const float* __restrict__ Wb,
                                             bf16_t* __restrict__ out,
                                             int K1, int K2, int idx) {
    int K = K1 + K2;
    int KT16 = K >> 4;
    int e = idx & 7;
    int l = (idx >> 3) & 63;
    int tile = idx >> 9;
    int kt = tile % KT16, t = tile / KT16;
    int c = t * 32 + (l & 31);
    int k = kt * 16 + (l >> 5) * 8 + e;
    float v = 0.f;
    if (c < 1000) v = (k < K1) ? Wa[c * K1 + k] : Wb[c * K2 + (k - K1)];
    out[idx] = f2b(v);
}
__device__ __forceinline__ void pack_w2_body(const float* __restrict__ Wa,
                                             const float* __restrict__ Wb,
                                             bf16_t* __restrict__ out,
                                             int OH, int idx) {
    int e = idx & 7;
    int l = (idx >> 3) & 63;
    int tile = idx >> 9;
    int kt2 = tile & 63, o = tile >> 6;   // K=1024 -> 64 k-tiles
    int c = o * 32 + (l & 31);
    int k = kt2 * 16 + (l >> 5) * 8 + e;
    float v = 0.f;
    if (k < 1000) v = (c < OH) ? Wa[c * 1000 + k] : Wb[(c - OH) * 1000 + k];
    out[idx] = f2b(v);
}

#define NB_BUILD 782   // (EE+255)/256
#define NB_P1 512      // 131072/256
#define NB_P2 1024     // 262144/256
#define NB_P3 1024
#define NB_P4 512

__global__ void setup_all(const int* __restrict__ ei, int* __restrict__ cnt,
                          int* __restrict__ bkt,
                          const float* __restrict__ W1_rel, const float* __restrict__ W1_root,
                          const float* __restrict__ W2_rel, const float* __restrict__ W2_root,
                          const float* __restrict__ W3_rel, const float* __restrict__ W3_root,
                          const float* __restrict__ W4_rel, const float* __restrict__ W4_root,
                          bf16_t* __restrict__ W1f, bf16_t* __restrict__ W2f,
                          bf16_t* __restrict__ W3f, bf16_t* __restrict__ W4f) {
    int b = blockIdx.x;
    int tid = threadIdx.x;
    if (b < NB_BUILD) {
        int e = b * 256 + tid;
        if (e < EE) {
            int s = ei[e];
            int d = ei[EE + e];
            int pos = atomicAdd(&cnt[d], 1);
            if (pos < BCAP) bkt[d * BCAP + pos] = s;
        }
    } else if (b < NB_BUILD + NB_P1) {
        pack_w1_body(W1_rel, W1_root, W1f, 64, 64, (b - NB_BUILD) * 256 + tid);
    } else if (b < NB_BUILD + NB_P1 + NB_P2) {
        pack_w2_body(W2_rel, W2_root, W2f, 128, (b - NB_BUILD - NB_P1) * 256 + tid);
    } else if (b < NB_BUILD + NB_P1 + NB_P2 + NB_P3) {
        pack_w1_body(W3_rel, W3_root, W3f, 128, 128, (b - NB_BUILD - NB_P1 - NB_P2) * 256 + tid);
    } else {
        pack_w2_body(W4_rel, W4_root, W4f, 64, (b - NB_BUILD - NB_P1 - NB_P2 - NB_P3) * 256 + tid);
    }
}

// ---------------------------------------------------------------------------
// h2[n] = relu(init[n] + sum nbr y2)   (bf16 [N,128] row-major in/out)
// ---------------------------------------------------------------------------
__global__ void gather_relu_b16(const bf16_t* __restrict__ y2, const bf16_t* __restrict__ init,
                                const int* __restrict__ cnt, const int* __restrict__ bkt,
                                bf16_t* __restrict__ h2) {
    int t = blockIdx.x * 256 + threadIdx.x;
    int n = t >> 4;
    if (n >= NN) return;
    int j = (t & 15) * 8;
    int c = cnt[n]; if (c > BCAP) c = BCAP;
    const int* bp = bkt + n * BCAP;
    U4 u; u.v = *(const uint4*)(init + n * 128 + j);
    float s[8];
    #pragma unroll
    for (int k = 0; k < 8; ++k) s[k] = us2f(u.s[k]);
    int i = 0;
    for (; i + 4 <= c; i += 4) {
        int s0 = bp[i], s1 = bp[i + 1], s2 = bp[i + 2], s3 = bp[i + 3];
        U4 w0, w1, w2, w3;
        w0.v = *(const uint4*)(y2 + (size_t)s0 * 128 + j);
        w1.v = *(const uint4*)(y2 + (size_t)s1 * 128 + j);
        w2.v = *(const uint4*)(y2 + (size_t)s2 * 128 + j);
        w3.v = *(const uint4*)(y2 + (size_t)s3 * 128 + j);
        #pragma unroll
        for (int k = 0; k < 8; ++k)
            s[k] += (us2f(w0.s[k]) + us2f(w1.s[k])) + (us2f(w2.s[k]) + us2f(w3.s[k]));
    }
    for (; i < c; ++i) {
        U4 w; w.v = *(const uint4*)(y2 + (size_t)bp[i] * 128 + j);
        #pragma unroll
        for (int k = 0; k < 8; ++k) s[k] += us2f(w.s[k]);
    }
    alignas(16) bf16_t ob[8];
    #pragma unroll
    for (int k = 0; k < 8; ++k) ob[k] = f2b(fmaxf(s[k], 0.f));
    *(uint4*)(h2 + n * 128 + j) = *(const uint4*)ob;
}

// outF[n] += sum nbr y4   (f32 [N,64] row-major, in-place on d_out)
__global__ void gather_add_f32_64(const float* __restrict__ y4, const int* __restrict__ cnt,
                                  const int* __restrict__ bkt, float* __restrict__ outF) {
    int t = blockIdx.x * 256 + threadIdx.x;
    int n = t >> 4;
    if (n >= NN) return;
    int j = (t & 15) * 4;
    int c = cnt[n]; if (c > BCAP) c = BCAP;
    const int* bp = bkt + n * BCAP;
    float4 sum = *(const float4*)(outF + n * 64 + j);
    int i = 0;
    for (; i + 4 <= c; i += 4) {
        int s0 = bp[i], s1 = bp[i + 1], s2 = bp[i + 2], s3 = bp[i + 3];
        float4 v0 = *(const float4*)(y4 + (size_t)s0 * 64 + j);
        float4 v1 = *(const float4*)(y4 + (size_t)s1 * 64 + j);
        float4 v2 = *(const float4*)(y4 + (size_t)s2 * 64 + j);
        float4 v3 = *(const float4*)(y4 + (size_t)s3 * 64 + j);
        sum.x += (v0.x + v1.x) + (v2.x + v3.x);
        sum.y += (v0.y + v1.y) + (v2.y + v3.y);
        sum.z += (v0.z + v1.z) + (v2.z + v3.z);
        sum.w += (v0.w + v1.w) + (v2.w + v3.w);
    }
    for (; i < c; ++i) {
        float4 v = *(const float4*)(y4 + (size_t)bp[i] * 64 + j);
        sum.x += v.x; sum.y += v.y; sum.z += v.z; sum.w += v.w;
    }
    *(float4*)(outF + n * 64 + j) = sum;
}

// ---------------------------------------------------------------------------
// Fused gather + two-GEMM v11: A-IN-REGISTERS + H DOUBLE-BUFFER + ONE
// BARRIER PER CHUNK. v10 diagnosis: 11 full-drain barriers/block (HIP
// __syncthreads drains vmcnt+lgkmcnt) serialized the latency chain; all
// pipes <20%. v11:
//  - each wave owns node-tile nt=wn&1; loads its A-frags ONCE to regs
//    (K=128: 8 frags = 32 VGPR; K=256: 16 = 64). Stage 1 = register MFMA
//    + independent global W1 loads, zero LDS dependency.
//  - the A-region of smem is re-aliased as the 2nd H buffer; H chunk
//    double-buffered -> ONE barrier per chunk. Safety: stage1(ci+1)
//    writes buf[(ci+1)&1], last read by stage2(ci-1); any wave writing
//    passed barrier(ci), which it reached only after its own stage1(ci),
//    which follows its stage2(ci-1) -> all waves' stage2(ci-1) complete.
//  - W1 read 2x per block (nt duplication), cheap in L2.
// Barriers: 3 + NCH (vs 11). Reg budget (128 cap): K=128: 64 AGPR acc
// + ~57 arch; K=256: 32 AGPR + ~89 arch. Tripwire: spills -> WRITE_SIZE.
//   Stage 1: wave (p=wn>>1, nt=wn&1): CTW col-tiles x its node-tile.
//   Stage 2: wave (og=wn>>1, wr=wn&1): OCT2 out-tiles x node-tile wr.
// Outputs: outcol < NOUT/2 -> yout, else -> initout (+bias2).
// ---------------------------------------------------------------------------
template <int K, int NOUT, int CCOLS, int F32OUT, int SRCF32>
__global__ __launch_bounds__(512, 4) void fused11(
    const void* __restrict__ src, const int* __restrict__ cnt,
    const int* __restrict__ bkt,
    const bf16_t* __restrict__ W1f, const float* __restrict__ bias1,
    const bf16_t* __restrict__ W2f, const float* __restrict__ bias2,
    void* __restrict__ yout, void* __restrict__ initout)
{
    constexpr int KT16 = K / 16;       // A k-frags per node-tile
    constexpr int CT   = CCOLS / 32;   // stage-1 col-tiles per chunk (8 or 4)
    constexpr int CTW  = CT / 4;       // col-tiles per wave (2 or 1)
    constexpr int NCH  = 1024 / CCOLS; // chunks (4 or 8)
    constexpr int KS   = CT * 2;       // 16-deep h-frags per chunk per nt
    constexpr int OT32 = NOUT / 32;
    constexpr int OCT2 = OT32 / 4;     // out tiles per wave (2 or 1)
    constexpr int OH   = NOUT / 2;
    constexpr int SW   = K / 2;        // source row width (64 f32 / 128 bf16)
    constexpr int HALF = K / 16;       // 8-col groups per half
    constexpr int STR  = F32OUT ? (NOUT + 4) : (NOUT + 8);
    constexpr size_t HCHB   = (size_t)64 * CCOLS * 2;           // H chunk bytes
    constexpr size_t ABYTES = (size_t)64 * K * 2;
    constexpr size_t EPIB   = (size_t)64 * STR * (F32OUT ? 4 : 2);
    constexpr size_t S1 = (ABYTES > 2 * HCHB) ? ABYTES : 2 * HCHB;
    constexpr size_t SMEMB = (S1 > EPIB) ? S1 : EPIB;

    __shared__ float b1sl[1024];
    __shared__ float b2sl[128];
    __shared__ __align__(16) char smem[SMEMB];
    bf16_t* Asl = (bf16_t*)smem;       // frag-major A tile (prologue phase only)

    const int tid  = threadIdx.x;
    const int lane = tid & 63;
    const int wn   = tid >> 6;        // 0..7
    const int l31  = lane & 31;
    const int hi   = lane >> 5;
    const int nt   = wn & 1;          // owned node-tile (stage 1)
    const int og   = wn >> 1;         // stage-2 out-col group 0..3
    const int wr   = wn & 1;          // stage-2 node-tile
    const int bm0  = blockIdx.x * 64;

    for (int i = tid; i < 1024; i += 512) b1sl[i] = (i < 1000) ? bias1[i] : 0.f;
    if (tid < OH) b2sl[tid] = bias2[tid];

    // ---- prologue: gather + own-copy directly into Asl (frag-major)
    #pragma unroll
    for (int it = 0; it < (2 * 64 * HALF) / 512; ++it) {
        int task = it * 512 + tid;
        const bool own = task >= 64 * HALF;
        int t2 = own ? task - 64 * HALF : task;
        int i = t2 / HALF, s = t2 - (t2 / HALF) * HALF;
        int n = bm0 + i;
        int j = s * 8;
        float sum[8] = {0.f, 0.f, 0.f, 0.f, 0.f, 0.f, 0.f, 0.f};
        if (n < NN) {
            if (!own) {
                int c = cnt[n]; if (c > BCAP) c = BCAP;
                const int* bp = bkt + n * BCAP;
                int e = 0;
                for (; e + 4 <= c; e += 4) {
                    int s0 = bp[e], s1 = bp[e + 1], s2 = bp[e + 2], s3 = bp[e + 3];
                    if (SRCF32) {
                        const float* r0 = (const float*)src + (size_t)s0 * SW + j;
                        const float* r1 = (const float*)src + (size_t)s1 * SW + j;
                        const float* r2 = (const float*)src + (size_t)s2 * SW + j;
                        const float* r3 = (const float*)src + (size_t)s3 * SW + j;
                        float4 a0 = *(const float4*)r0, b0 = *(const float4*)(r0 + 4);
                        float4 a1 = *(const float4*)r1, b1 = *(const float4*)(r1 + 4);
                        float4 a2 = *(const float4*)r2, b2 = *(const float4*)(r2 + 4);
                        float4 a3 = *(const float4*)r3, b3 = *(const float4*)(r3 + 4);
                        sum[0] += (a0.x + a1.x) + (a2.x + a3.x);
                        sum[1] += (a0.y + a1.y) + (a2.y + a3.y);
                        sum[2] += (a0.z + a1.z) + (a2.z + a3.z);
                        sum[3] += (a0.w + a1.w) + (a2.w + a3.w);
                        sum[4] += (b0.x + b1.x) + (b2.x + b3.x);
                        sum[5] += (b0.y + b1.y) + (b2.y + b3.y);
                        sum[6] += (b0.z + b1.z) + (b2.z + b3.z);
                        sum[7] += (b0.w + b1.w) + (b2.w + b3.w);
                    } else {
                        U4 w0, w1, w2, w3;
                        w0.v = *(const uint4*)((const bf16_t*)src + (size_t)s0 * SW + j);
                        w1.v = *(const uint4*)((const bf16_t*)src + (size_t)s1 * SW + j);
                        w2.v = *(const uint4*)((const bf16_t*)src + (size_t)s2 * SW + j);
                        w3.v = *(const uint4*)((const bf16_t*)src + (size_t)s3 * SW + j);
                        #pragma unroll
                        for (int k = 0; k < 8; ++k)
                            sum[k] += (us2f(w0.s[k]) + us2f(w1.s[k])) + (us2f(w2.s[k]) + us2f(w3.s[k]));
                    }
                }
                for (; e < c; ++e) {
                    int sn = bp[e];
                    if (SRCF32) {
                        const float* r = (const float*)src + (size_t)sn * SW + j;
                        float4 a = *(const float4*)r;
                        float4 b = *(const float4*)(r + 4);
                        sum[0] += a.x; sum[1] += a.y; sum[2] += a.z; sum[3] += a.w;
                        sum[4] += b.x; sum[5] += b.y; sum[6] += b.z; sum[7] += b.w;
                    } else {
                        U4 w; w.v = *(const uint4*)((const bf16_t*)src + (size_t)sn * SW + j);
                        #pragma unroll
                        for (int k = 0; k < 8; ++k) sum[k] += us2f(w.s[k]);
                    }
                }
            } else {
                if (SRCF32) {
                    const float* r = (const float*)src + (size_t)n * SW + j;
                    float4 a = *(const float4*)r;
                    float4 b = *(const float4*)(r + 4);
                    sum[0] = a.x; sum[1] = a.y; sum[2] = a.z; sum[3] = a.w;
                    sum[4] = b.x; sum[5] = b.y; sum[6] = b.z; sum[7] = b.w;
                } else {
                    U4 w; w.v = *(const uint4*)((const bf16_t*)src + (size_t)n * SW + j);
                    #pragma unroll
                    for (int k = 0; k < 8; ++k) sum[k] = us2f(w.s[k]);
                }
            }
        }
        int cc = (own ? K / 2 : 0) + j;           // column in A's K-space
        int off = (((i >> 5) * KT16 + (cc >> 4)) * 64 + ((cc >> 3) & 1) * 32 + (i & 31)) * 8;
        alignas(16) bf16_t ob[8];
        #pragma unroll
        for (int k = 0; k < 8; ++k) ob[k] = f2b(sum[k]);
        *(uint4*)(&Asl[off]) = *(const uint4*)ob;
    }

    __syncthreads();   // Asl + biases ready

    // ---- A-tile -> registers (own node-tile only), then smem is reusable
    short8 af[KT16];
    #pragma unroll
    for (int kk = 0; kk < KT16; ++kk)
        af[kk] = *(const short8*)&Asl[((nt * KT16 + kk) * 64 + lane) * 8];

    __syncthreads();   // all A reads done; smem becomes H double-buffer

    floatx16 acc2[OCT2];
    #pragma unroll
    for (int oo = 0; oo < OCT2; ++oo) acc2[oo] = (floatx16)FZ16;

    for (int ci = 0; ci < NCH; ++ci) {
        bf16_t* Hb = (bf16_t*)(smem + (size_t)(ci & 1) * HCHB);

        // ---- stage 1: pure-reg MFMA; w1 from global (L2-resident)
        floatx16 acc1[CTW];
        #pragma unroll
        for (int t = 0; t < CTW; ++t) acc1[t] = (floatx16)FZ16;

        #pragma unroll
        for (int t = 0; t < CTW; ++t) {
            int gt = ci * CT + (wn >> 1) * CTW + t;   // global h col-tile [0,32)
            const bf16_t* w1p = W1f + (((size_t)gt * KT16) * 64 + lane) * 8;
            #pragma unroll 2
            for (int kk = 0; kk < KT16; ++kk) {
                short8 w1 = *(const short8*)(w1p + (size_t)kk * 512);
                acc1[t] = __builtin_amdgcn_mfma_f32_32x32x16_bf16(w1, af[kk], acc1[t], 0, 0, 0);
            }
        }

        // bias+relu -> frag-major H chunk (own node-tile rows)
        #pragma unroll
        for (int t = 0; t < CTW; ++t) {
            int ct = (wn >> 1) * CTW + t;
            #pragma unroll
            for (int g = 0; g < 4; ++g) {
                float4 bv = *(const float4*)&b1sl[ci * CCOLS + ct * 32 + 8 * g + 4 * hi];
                const float* bvp = (const float*)&bv;
                alignas(8) bf16_t hb[4];
                #pragma unroll
                for (int e = 0; e < 4; ++e)
                    hb[e] = f2b(fmaxf(acc1[t][4 * g + e] + bvp[e], 0.f));
                int off = ((nt * KS + ct * 2 + (g >> 1)) * 64 + (g & 1) * 32 + l31) * 8 + 4 * hi;
                *(uint2*)&Hb[off] = *(const uint2*)hb;
            }
        }

        __syncthreads();   // the ONLY barrier per chunk: H chunk visible

        // ---- stage 2: acc2[oo] += W2(out-tile og*OCT2+oo) x H(node-tile wr)
        const bf16_t* w2p = W2f + ((((size_t)(og * OCT2)) * 64 + ci * KS) * 64 + lane) * 8;
        #pragma unroll 2
        for (int ks = 0; ks < KS; ++ks) {
            short8 hf = *(const short8*)&Hb[((wr * KS + ks) * 64 + lane) * 8];
            #pragma unroll
            for (int oo = 0; oo < OCT2; ++oo) {
                short8 w2v = *(const short8*)(w2p + ((size_t)oo * 64 + ks) * 512);
                acc2[oo] = __builtin_amdgcn_mfma_f32_32x32x16_bf16(w2v, hf, acc2[oo], 0, 0, 0);
            }
        }
    }

    // ---- epilogue: stage acc2(+bias) into LDS [node][outcol] (padded),
    //      then copy full rows out with coalesced line-aligned stores.
    __syncthreads();   // everyone done reading H buffers
    {
        const int r = wr * 32 + l31;   // node row within block
        if (F32OUT) {
            float* st = (float*)smem;
            #pragma unroll
            for (int oo = 0; oo < OCT2; ++oo) {
                int o = og * OCT2 + oo;
                #pragma unroll
                for (int g = 0; g < 4; ++g) {
                    int oc = o * 32 + 8 * g + 4 * hi;   // col in NOUT space
                    const bool isInit = (oc >= OH);
                    int col = isInit ? oc - OH : oc;
                    float4 bv = isInit ? *(const float4*)&b2sl[col]
                                       : make_float4(0.f, 0.f, 0.f, 0.f);
                    const float* bvp = (const float*)&bv;
                    float v[4];
                    #pragma unroll
                    for (int e = 0; e < 4; ++e) v[e] = acc2[oo][4 * g + e] + bvp[e];
                    *(float4*)&st[r * STR + oc] = make_float4(v[0], v[1], v[2], v[3]);
                }
            }
        } else {
            bf16_t* st = (bf16_t*)smem;
            #pragma unroll
            for (int oo = 0; oo < OCT2; ++oo) {
                int o = og * OCT2 + oo;
                #pragma unroll
                for (int g = 0; g < 4; ++g) {
                    int oc = o * 32 + 8 * g + 4 * hi;
                    const bool isInit = (oc >= OH);
                    int col = isInit ? oc - OH : oc;
                    float4 bv = isInit ? *(const float4*)&b2sl[col]
                                       : make_float4(0.f, 0.f, 0.f, 0.f);
                    const float* bvp = (const float*)&bv;
                    alignas(8) bf16_t ob[4];
                    #pragma unroll
                    for (int e = 0; e < 4; ++e) ob[e] = f2b(acc2[oo][4 * g + e] + bvp[e]);
                    *(uint2*)&st[r * STR + oc] = *(const uint2*)ob;
                }
            }
        }
    }
    __syncthreads();
    {
        // 16B chunks per node: f32 NOUT*4/16, bf16 NOUT*2/16 -> both 32.
        constexpr int CH = F32OUT ? (NOUT / 4) : (NOUT / 8);
        constexpr int CHH = CH / 2;    // chunks per half-row
        for (int t = tid; t < 64 * CH; t += 512) {
            int nd = t / CH, c = t - (t / CH) * CH;
            int node = bm0 + nd;
            if (node >= NN) continue;
            const bool isInit = (c >= CHH);
            int ch = isInit ? c - CHH : c;
            if (F32OUT) {
                const float* st = (const float*)smem;
                float4 v = *(const float4*)&st[nd * STR + c * 4];
                float* dst = isInit ? (float*)initout : (float*)yout;
                *(float4*)(dst + (size_t)node * OH + ch * 4) = v;
            } else {
                const bf16_t* st = (const bf16_t*)smem;
                uint4 v = *(const uint4*)&st[nd * STR + c * 8];
                bf16_t* dst = isInit ? (bf16_t*)initout : (bf16_t*)yout;
                *(uint4*)(dst + (size_t)node * OH + ch * 8) = v;
            }
        }
    }
}

// ---------------------------------------------------------------------------
// Mean-pool per graph (batch sorted; binary search), h2 bf16.
// ---------------------------------------------------------------------------
__global__ void pool_kernel(const bf16_t* __restrict__ h2,
                            const int* __restrict__ batch,
                            float* __restrict__ enc, int Nn) {
    int g = blockIdx.x;
    __shared__ int s_lo, s_hi;
    __shared__ float part[128];
    if (threadIdx.x == 0) {
        int lo = 0, hi = Nn;
        while (lo < hi) { int mid = (lo + hi) >> 1; if (batch[mid] < g) lo = mid + 1; else hi = mid; }
        s_lo = lo;
        hi = Nn;
        while (lo < hi) { int mid = (lo + hi) >> 1; if (batch[mid] < g + 1) lo = mid + 1; else hi = mid; }
        s_hi = lo;
    }
    __syncthreads();
    int f = threadIdx.x & 127;
    int ty = threadIdx.x >> 7;   // 0..1
    float sum = 0.f;
    for (int n = s_lo + ty; n < s_hi; n += 2) sum += b2f(h2[n * 128 + f]);
    if (ty == 1) part[f] = sum;
    __syncthreads();
    if (ty == 0) {
        float tot = sum + part[f];
        float cnt = (float)((s_hi - s_lo) > 0 ? (s_hi - s_lo) : 1);
        enc[g * 128 + f] = tot / cnt;
    }
}

// ---------------------------------------------------------------------------
// Launch
// ---------------------------------------------------------------------------
extern "C" void kernel_launch(void* const* d_in, const int* in_sizes, int n_in,
                              void* d_out, int out_size, void* d_ws, size_t ws_size,
                              hipStream_t stream) {
    const float* x       = (const float*)d_in[0];
    const int*   ei      = (const int*)d_in[1];
    const int*   batch   = (const int*)d_in[2];
    const float* W1_rel  = (const float*)d_in[3];
    const float* b1      = (const float*)d_in[4];
    const float* W1_root = (const float*)d_in[5];
    const float* W2_rel  = (const float*)d_in[6];
    const float* b2      = (const float*)d_in[7];
    const float* W2_root = (const float*)d_in[8];
    const float* W3_rel  = (const float*)d_in[9];
    const float* b3      = (const float*)d_in[10];
    const float* W3_root = (const float*)d_in[11];
    const float* W4_rel  = (const float*)d_in[12];
    const float* b4      = (const float*)d_in[13];
    const float* W4_root = (const float*)d_in[14];

    float* outF = (float*)d_out;            // [N,64] then [G,128]
    float* enc  = outF + NN * 64;

    char* ws = (char*)d_ws;                         // ~66 MB
    bf16_t* y2buf  = (bf16_t*)(ws + 0);             // [N,128] bf16
    bf16_t* h2init = (bf16_t*)(ws + 12800000ULL);   // [N,128] bf16
    bf16_t* h2buf  = (bf16_t*)(ws + 25600000ULL);   // [N,128] bf16
    float*  y4buf  = (float*)(ws + 38400000ULL);    // [N,64] f32
    int*    cnt    = (int*)(ws + 51200000ULL);      // [N]
    int*    bkt    = (int*)(ws + 51400064ULL);      // [N*64]
    bf16_t* W1f    = (bf16_t*)(ws + 64200064ULL);   // 1024x128 frag-major
    bf16_t* W2f    = (bf16_t*)(ws + 64462208ULL);   // 256x1024 frag-major
    bf16_t* W3f    = (bf16_t*)(ws + 64986496ULL);   // 1024x256 frag-major
    bf16_t* W4f    = (bf16_t*)(ws + 65510784ULL);   // 128x1024 frag-major

    const int RB64 = (NN + 63) / 64;  // 782

    // ---- adjacency + all weight packs in one launch
    hipMemsetAsync(cnt, 0, NN * sizeof(int), stream);
    setup_all<<<NB_BUILD + NB_P1 + NB_P2 + NB_P3 + NB_P4, 256, 0, stream>>>(
        ei, cnt, bkt, W1_rel, W1_root, W2_rel, W2_root,
        W3_rel, W3_root, W4_rel, W4_root, W1f, W2f, W3f, W4f);

    // ---- L1+L2 fused: A=[gather(x)|x]; h1 on-chip;
    //      y2 = h1@W2_rel^T (bf16), h2init = h1@W2_root^T + b2 (bf16)
    fused11<128, 256, 256, 0, 1><<<RB64, 512, 0, stream>>>(x, cnt, bkt, W1f, b1, W2f, b2, y2buf, h2init);

    // ---- h2 = relu(h2init + gather(y2));  encoded = mean-pool(h2)
    gather_relu_b16<<<(NN * 16 + 255) / 256, 256, 0, stream>>>(y2buf, h2init, cnt, bkt, h2buf);
    pool_kernel<<<GG, 256, 0, stream>>>(h2buf, batch, enc, NN);

    // ---- L3+L4 fused: A=[gather(h2)|h2]; h3 on-chip;
    //      y4 = h3@W4_rel^T (f32), outF = h3@W4_root^T + b4 (f32, direct)
    fused11<256, 128, 128, 1, 0><<<RB64, 512, 0, stream>>>(h2buf, cnt, bkt, W3f, b3, W4f, b4, y4buf, outF);

    // ---- out = outF + gather(y4)
    gather_add_f32_64<<<(NN * 16 + 255) / 256, 256, 0, stream>>>(y4buf, cnt, bkt, outF);
}

// Round 6
// 482.470 us; speedup vs baseline: 4.6551x; 4.6551x over previous
//
#include <hip/hip_runtime.h>
#include <hip/hip_bf16.h>

typedef __hip_bfloat16 bf16_t;
typedef __attribute__((ext_vector_type(8))) short short8;
typedef __attribute__((ext_vector_type(16))) float floatx16;

static __device__ __forceinline__ float b2f(bf16_t v) { return __bfloat162float(v); }
static __device__ __forceinline__ bf16_t f2b(float v) { return __float2bfloat16(v); }
static __device__ __forceinline__ float us2f(unsigned short u) {
    union { unsigned int i; float f; } c; c.i = ((unsigned int)u) << 16; return c.f;
}

// Problem constants
#define NN 50000
#define EE 200000
#define GG 2048
#define BCAP 64   // in-degree cap; mean deg = 4

union U4 { uint4 v; unsigned short s[8]; };

#define FZ16 {0.f,0.f,0.f,0.f,0.f,0.f,0.f,0.f,0.f,0.f,0.f,0.f,0.f,0.f,0.f,0.f}

// 32x32x16 fragment-major layout (A and B operands share it):
//   element (i, k) of an [I x K] K-major matrix lives at
//   ((i/32 * (K/16) + k/16) * 64 + ((k%16)/8)*32 + i%32) * 8 + k%8
// One wave fragment = 64 lanes x short8 = contiguous 1KB.

// ---------------------------------------------------------------------------
// Merged setup: inverted adjacency build + all 4 weight packs in ONE launch
// ---------------------------------------------------------------------------
__device__ __forceinline__ void pack_w1_body(const float* __restrict__ Wa,
                                             const float* __restrict__ Wb,
                                             bf16_t* __restrict__ out,
                                             int K1, int K2, int idx) {
    int K = K1 + K2;
    int KT16 = K >> 4;
    int e = idx & 7;
    int l = (idx >> 3) & 63;
    int tile = idx >> 9;
    int kt = tile % KT16, t = tile / KT16;
    int c = t * 32 + (l & 31);
    int k = kt * 16 + (l >> 5) * 8 + e;
    float v = 0.f;
    if (c < 1000) v = (k < K1) ? Wa[c * K1 + k] : Wb[c * K2 + (k - K1)];
    out[idx] = f2b(v);
}
__device__ __forceinline__ void pack_w2_body(const float* __restrict__ Wa,
                                             const float* __restrict__ Wb,
                                             bf16_t* __restrict__ out,
                                             int OH, int idx) {
    int e = idx & 7;
    int l = (idx >> 3) & 63;
    int tile = idx >> 9;
    int kt2 = tile & 63, o = tile >> 6;   // K=1024 -> 64 k-tiles
    int c = o * 32 + (l & 31);
    int k = kt2 * 16 + (l >> 5) * 8 + e;
    float v = 0.f;
    if (k < 1000) v = (c < OH) ? Wa[c * 1000 + k] : Wb[(c - OH) * 1000 + k];
    out[idx] = f2b(v);
}

#define NB_BUILD 782   // (EE+255)/256
#define NB_P1 512      // 131072/256
#define NB_P2 1024     // 262144/256
#define NB_P3 1024
#define NB_P4 512

__global__ void setup_all(const int* __restrict__ ei, int* __restrict__ cnt,
                          int* __restrict__ bkt,
                          const float* __restrict__ W1_rel, const float* __restrict__ W1_root,
                          const float* __restrict__ W2_rel, const float* __restrict__ W2_root,
                          const float* __restrict__ W3_rel, const float* __restrict__ W3_root,
                          const float* __restrict__ W4_rel, const float* __restrict__ W4_root,
                          bf16_t* __restrict__ W1f, bf16_t* __restrict__ W2f,
                          bf16_t* __restrict__ W3f, bf16_t* __restrict__ W4f) {
    int b = blockIdx.x;
    int tid = threadIdx.x;
    if (b < NB_BUILD) {
        int e = b * 256 + tid;
        if (e < EE) {
            int s = ei[e];
            int d = ei[EE + e];
            int pos = atomicAdd(&cnt[d], 1);
            if (pos < BCAP) bkt[d * BCAP + pos] = s;
        }
    } else if (b < NB_BUILD + NB_P1) {
        pack_w1_body(W1_rel, W1_root, W1f, 64, 64, (b - NB_BUILD) * 256 + tid);
    } else if (b < NB_BUILD + NB_P1 + NB_P2) {
        pack_w2_body(W2_rel, W2_root, W2f, 128, (b - NB_BUILD - NB_P1) * 256 + tid);
    } else if (b < NB_BUILD + NB_P1 + NB_P2 + NB_P3) {
        pack_w1_body(W3_rel, W3_root, W3f, 128, 128, (b - NB_BUILD - NB_P1 - NB_P2) * 256 + tid);
    } else {
        pack_w2_body(W4_rel, W4_root, W4f, 64, (b - NB_BUILD - NB_P1 - NB_P2 - NB_P3) * 256 + tid);
    }
}

// ---------------------------------------------------------------------------
// h2[n] = relu(init[n] + sum nbr y2)  (bf16 [N,128]) + FUSED MEAN-POOL:
// relu'd f32 values are atomically accumulated into encsum[g*128+col]
// (pre-zeroed); pool_div divides by counts afterwards. Replaces the old
// pool_kernel (scalar 2B loads, serial ~24-node loop).
// ---------------------------------------------------------------------------
__global__ void gather_relu_pool(const bf16_t* __restrict__ y2, const bf16_t* __restrict__ init,
                                 const int* __restrict__ cnt, const int* __restrict__ bkt,
                                 const int* __restrict__ batch,
                                 bf16_t* __restrict__ h2, float* __restrict__ encsum) {
    int t = blockIdx.x * 256 + threadIdx.x;
    int n = t >> 4;
    if (n >= NN) return;
    int j = (t & 15) * 8;
    int c = cnt[n]; if (c > BCAP) c = BCAP;
    const int* bp = bkt + n * BCAP;
    U4 u; u.v = *(const uint4*)(init + n * 128 + j);
    float s[8];
    #pragma unroll
    for (int k = 0; k < 8; ++k) s[k] = us2f(u.s[k]);
    int i = 0;
    for (; i + 4 <= c; i += 4) {
        int s0 = bp[i], s1 = bp[i + 1], s2 = bp[i + 2], s3 = bp[i + 3];
        U4 w0, w1, w2, w3;
        w0.v = *(const uint4*)(y2 + (size_t)s0 * 128 + j);
        w1.v = *(const uint4*)(y2 + (size_t)s1 * 128 + j);
        w2.v = *(const uint4*)(y2 + (size_t)s2 * 128 + j);
        w3.v = *(const uint4*)(y2 + (size_t)s3 * 128 + j);
        #pragma unroll
        for (int k = 0; k < 8; ++k)
            s[k] += (us2f(w0.s[k]) + us2f(w1.s[k])) + (us2f(w2.s[k]) + us2f(w3.s[k]));
    }
    for (; i < c; ++i) {
        U4 w; w.v = *(const uint4*)(y2 + (size_t)bp[i] * 128 + j);
        #pragma unroll
        for (int k = 0; k < 8; ++k) s[k] += us2f(w.s[k]);
    }
    alignas(16) bf16_t ob[8];
    #pragma unroll
    for (int k = 0; k < 8; ++k) {
        s[k] = fmaxf(s[k], 0.f);
        ob[k] = f2b(s[k]);
    }
    *(uint4*)(h2 + n * 128 + j) = *(const uint4*)ob;
    int g = batch[n];
    float* ep = encsum + (size_t)g * 128 + j;
    #pragma unroll
    for (int k = 0; k < 8; ++k) atomicAdd(&ep[k], s[k]);
}

// enc[g][f] /= count(g)   (tiny; binary search on sorted batch)
__global__ void pool_div(float* __restrict__ enc, const int* __restrict__ batch, int Nn) {
    int g = blockIdx.x;
    __shared__ int s_lo, s_hi;
    if (threadIdx.x == 0) {
        int lo = 0, hi = Nn;
        while (lo < hi) { int mid = (lo + hi) >> 1; if (batch[mid] < g) lo = mid + 1; else hi = mid; }
        s_lo = lo;
        hi = Nn;
        while (lo < hi) { int mid = (lo + hi) >> 1; if (batch[mid] < g + 1) lo = mid + 1; else hi = mid; }
        s_hi = lo;
    }
    __syncthreads();
    int f = threadIdx.x;
    float cnt = (float)((s_hi - s_lo) > 0 ? (s_hi - s_lo) : 1);
    enc[(size_t)g * 128 + f] /= cnt;
}

// outF[n] += sum nbr y4   (f32 [N,64] row-major, in-place on d_out)
__global__ void gather_add_f32_64(const float* __restrict__ y4, const int* __restrict__ cnt,
                                  const int* __restrict__ bkt, float* __restrict__ outF) {
    int t = blockIdx.x * 256 + threadIdx.x;
    int n = t >> 4;
    if (n >= NN) return;
    int j = (t & 15) * 4;
    int c = cnt[n]; if (c > BCAP) c = BCAP;
    const int* bp = bkt + n * BCAP;
    float4 sum = *(const float4*)(outF + n * 64 + j);
    int i = 0;
    for (; i + 4 <= c; i += 4) {
        int s0 = bp[i], s1 = bp[i + 1], s2 = bp[i + 2], s3 = bp[i + 3];
        float4 v0 = *(const float4*)(y4 + (size_t)s0 * 64 + j);
        float4 v1 = *(const float4*)(y4 + (size_t)s1 * 64 + j);
        float4 v2 = *(const float4*)(y4 + (size_t)s2 * 64 + j);
        float4 v3 = *(const float4*)(y4 + (size_t)s3 * 64 + j);
        sum.x += (v0.x + v1.x) + (v2.x + v3.x);
        sum.y += (v0.y + v1.y) + (v2.y + v3.y);
        sum.z += (v0.z + v1.z) + (v2.z + v3.z);
        sum.w += (v0.w + v1.w) + (v2.w + v3.w);
    }
    for (; i < c; ++i) {
        float4 v = *(const float4*)(y4 + (size_t)bp[i] * 64 + j);
        sum.x += v.x; sum.y += v.y; sum.z += v.z; sum.w += v.w;
    }
    *(float4*)(outF + n * 64 + j) = sum;
}

// ---------------------------------------------------------------------------
// Fused gather + two-GEMM v12 = v9 (known-good 83us) + stage-2 W2 DEDUP for
// NOUT=256: v9's wr-split made wave pairs read identical W2 frags (1MB/block
// duplicated L2). Now wave wn owns out-tile o=wn x BOTH node-tiles: W2 read
// once (512KB/block); hf LDS reads double (LDS pipe ~2.3x L2 BW -> net win).
// acc2 stays 2x16=32 regs -> identical register pressure (no v11 spills).
// NOUT=128 keeps the v9 mapping.
//   Block = 64 nodes (2 node-tiles of 32), 512 threads = 8 waves.
//   Stage 1: wave wn owns hcol-tile (ci*8+wn) x BOTH node tiles.
//   H chunk [64 x 256] bf16, single-buffered (32KB), frag-major.
// Outputs: outcol < NOUT/2 -> yout, else -> initout (+bias2).
// ---------------------------------------------------------------------------
template <int K, int NOUT, int F32OUT, int SRCF32>
__global__ __launch_bounds__(512, 4) void fused12(
    const void* __restrict__ src, const int* __restrict__ cnt,
    const int* __restrict__ bkt,
    const bf16_t* __restrict__ W1f, const float* __restrict__ bias1,
    const bf16_t* __restrict__ W2f, const float* __restrict__ bias2,
    void* __restrict__ yout, void* __restrict__ initout)
{
    constexpr int KT16 = K / 16;      // A k-tiles (16-deep)
    constexpr int OT32 = NOUT / 32;   // out 32-col tiles (8 or 4)
    constexpr int OCT2 = OT32 / 4;    // out tiles per wave, old mapping (2 or 1)
    constexpr int NACC = (NOUT == 256) ? 2 : OCT2;
    constexpr int OH   = NOUT / 2;
    constexpr int SW   = K / 2;       // source row width (64 f32 / 128 bf16)
    constexpr int HALF = K / 16;      // 8-col groups per half (8 or 16)
    constexpr int STR  = F32OUT ? (NOUT + 4) : (NOUT + 8);
    __shared__ float b1sl[1024];
    __shared__ float b2sl[128];
    __shared__ __align__(16) char smem[(size_t)64 * K * 2 + 64 * 256 * 2];
    bf16_t* Asl = (bf16_t*)smem;                        // frag-major A tile [64*K]
    bf16_t* Hsl = (bf16_t*)(smem + (size_t)64 * K * 2); // frag-major H chunk [64*256]

    const int tid  = threadIdx.x;
    const int lane = tid & 63;
    const int wn   = tid >> 6;        // 0..7
    const int l31  = lane & 31;
    const int hi   = lane >> 5;
    const int og   = wn >> 1;         // old stage-2 out-col group
    const int wr   = wn & 1;          // old stage-2 node-tile
    const int bm0  = blockIdx.x * 64;

    for (int i = tid; i < 1024; i += 512) b1sl[i] = (i < 1000) ? bias1[i] : 0.f;
    if (tid < OH) b2sl[tid] = bias2[tid];

    // ---- prologue: gather + own-copy directly into Asl (frag-major)
    #pragma unroll
    for (int it = 0; it < (2 * 64 * HALF) / 512; ++it) {
        int task = it * 512 + tid;
        const bool own = task >= 64 * HALF;
        int t2 = own ? task - 64 * HALF : task;
        int i = t2 / HALF, s = t2 - (t2 / HALF) * HALF;
        int n = bm0 + i;
        int j = s * 8;
        float sum[8] = {0.f, 0.f, 0.f, 0.f, 0.f, 0.f, 0.f, 0.f};
        if (n < NN) {
            if (!own) {
                int c = cnt[n]; if (c > BCAP) c = BCAP;
                const int* bp = bkt + n * BCAP;
                int e = 0;
                for (; e + 4 <= c; e += 4) {
                    int s0 = bp[e], s1 = bp[e + 1], s2 = bp[e + 2], s3 = bp[e + 3];
                    if (SRCF32) {
                        const float* r0 = (const float*)src + (size_t)s0 * SW + j;
                        const float* r1 = (const float*)src + (size_t)s1 * SW + j;
                        const float* r2 = (const float*)src + (size_t)s2 * SW + j;
                        const float* r3 = (const float*)src + (size_t)s3 * SW + j;
                        float4 a0 = *(const float4*)r0, b0 = *(const float4*)(r0 + 4);
                        float4 a1 = *(const float4*)r1, b1 = *(const float4*)(r1 + 4);
                        float4 a2 = *(const float4*)r2, b2 = *(const float4*)(r2 + 4);
                        float4 a3 = *(const float4*)r3, b3 = *(const float4*)(r3 + 4);
                        sum[0] += (a0.x + a1.x) + (a2.x + a3.x);
                        sum[1] += (a0.y + a1.y) + (a2.y + a3.y);
                        sum[2] += (a0.z + a1.z) + (a2.z + a3.z);
                        sum[3] += (a0.w + a1.w) + (a2.w + a3.w);
                        sum[4] += (b0.x + b1.x) + (b2.x + b3.x);
                        sum[5] += (b0.y + b1.y) + (b2.y + b3.y);
                        sum[6] += (b0.z + b1.z) + (b2.z + b3.z);
                        sum[7] += (b0.w + b1.w) + (b2.w + b3.w);
                    } else {
                        U4 w0, w1, w2, w3;
                        w0.v = *(const uint4*)((const bf16_t*)src + (size_t)s0 * SW + j);
                        w1.v = *(const uint4*)((const bf16_t*)src + (size_t)s1 * SW + j);
                        w2.v = *(const uint4*)((const bf16_t*)src + (size_t)s2 * SW + j);
                        w3.v = *(const uint4*)((const bf16_t*)src + (size_t)s3 * SW + j);
                        #pragma unroll
                        for (int k = 0; k < 8; ++k)
                            sum[k] += (us2f(w0.s[k]) + us2f(w1.s[k])) + (us2f(w2.s[k]) + us2f(w3.s[k]));
                    }
                }
                for (; e < c; ++e) {
                    int sn = bp[e];
                    if (SRCF32) {
                        const float* r = (const float*)src + (size_t)sn * SW + j;
                        float4 a = *(const float4*)r;
                        float4 b = *(const float4*)(r + 4);
                        sum[0] += a.x; sum[1] += a.y; sum[2] += a.z; sum[3] += a.w;
                        sum[4] += b.x; sum[5] += b.y; sum[6] += b.z; sum[7] += b.w;
                    } else {
                        U4 w; w.v = *(const uint4*)((const bf16_t*)src + (size_t)sn * SW + j);
                        #pragma unroll
                        for (int k = 0; k < 8; ++k) sum[k] += us2f(w.s[k]);
                    }
                }
            } else {
                if (SRCF32) {
                    const float* r = (const float*)src + (size_t)n * SW + j;
                    float4 a = *(const float4*)r;
                    float4 b = *(const float4*)(r + 4);
                    sum[0] = a.x; sum[1] = a.y; sum[2] = a.z; sum[3] = a.w;
                    sum[4] = b.x; sum[5] = b.y; sum[6] = b.z; sum[7] = b.w;
                } else {
                    U4 w; w.v = *(const uint4*)((const bf16_t*)src + (size_t)n * SW + j);
                    #pragma unroll
                    for (int k = 0; k < 8; ++k) sum[k] = us2f(w.s[k]);
                }
            }
        }
        int cc = (own ? K / 2 : 0) + j;           // column in A's K-space
        int off = (((i >> 5) * KT16 + (cc >> 4)) * 64 + ((cc >> 3) & 1) * 32 + (i & 31)) * 8;
        alignas(16) bf16_t ob[8];
        #pragma unroll
        for (int k = 0; k < 8; ++k) ob[k] = f2b(sum[k]);
        *(uint4*)(&Asl[off]) = *(const uint4*)ob;
    }

    floatx16 acc2[NACC];
    #pragma unroll
    for (int oo = 0; oo < NACC; ++oo) acc2[oo] = (floatx16)FZ16;

    __syncthreads();   // Asl + biases ready

    for (int ci = 0; ci < 4; ++ci) {
        // ---- stage 1: wave computes h-tile (ci*8 + wn) x both node-tiles
        floatx16 acc1[2];
        acc1[0] = (floatx16)FZ16;
        acc1[1] = (floatx16)FZ16;

        const bf16_t* w1p = W1f + (((size_t)(ci * 8 + wn) * KT16) * 64 + lane) * 8;
        #pragma unroll 2
        for (int kk = 0; kk < KT16; ++kk) {
            short8 w1 = *(const short8*)(w1p + (size_t)kk * 512);
            short8 av0 = *(const short8*)&Asl[((0 * KT16 + kk) * 64 + lane) * 8];
            acc1[0] = __builtin_amdgcn_mfma_f32_32x32x16_bf16(w1, av0, acc1[0], 0, 0, 0);
            short8 av1 = *(const short8*)&Asl[((1 * KT16 + kk) * 64 + lane) * 8];
            acc1[1] = __builtin_amdgcn_mfma_f32_32x32x16_bf16(w1, av1, acc1[1], 0, 0, 0);
        }

        __syncthreads();   // previous chunk's stage-2 readers done with Hsl

        // bias+relu -> frag-major H; C/D: node=l31, hcol32=(r&3)+8*(r>>2)+4*hi
        #pragma unroll
        for (int nt2 = 0; nt2 < 2; ++nt2) {
            #pragma unroll
            for (int g = 0; g < 4; ++g) {
                float4 bv = *(const float4*)&b1sl[ci * 256 + wn * 32 + 8 * g + 4 * hi];
                const float* bvp = (const float*)&bv;
                alignas(8) bf16_t hb[4];
                #pragma unroll
                for (int e = 0; e < 4; ++e)
                    hb[e] = f2b(fmaxf(acc1[nt2][4 * g + e] + bvp[e], 0.f));
                int off = ((nt2 * 16 + wn * 2 + (g >> 1)) * 64 + (g & 1) * 32 + l31) * 8 + 4 * hi;
                *(uint2*)&Hsl[off] = *(const uint2*)hb;
            }
        }

        __syncthreads();   // H chunk visible

        // ---- stage 2
        if (NOUT == 256) {
            // dedup mapping: wave wn owns out-tile o=wn x BOTH node-tiles
            const bf16_t* w2p = W2f + (((size_t)wn * 64 + ci * 16) * 64 + lane) * 8;
            #pragma unroll 2
            for (int ks = 0; ks < 16; ++ks) {
                short8 w2v = *(const short8*)(w2p + (size_t)ks * 512);
                short8 hf0 = *(const short8*)&Hsl[((0 * 16 + ks) * 64 + lane) * 8];
                acc2[0] = __builtin_amdgcn_mfma_f32_32x32x16_bf16(w2v, hf0, acc2[0], 0, 0, 0);
                short8 hf1 = *(const short8*)&Hsl[((1 * 16 + ks) * 64 + lane) * 8];
                acc2[1] = __builtin_amdgcn_mfma_f32_32x32x16_bf16(w2v, hf1, acc2[1], 0, 0, 0);
            }
        } else {
            // old mapping: wave (og, wr): OCT2 out-tiles x node-tile wr
            const bf16_t* w2p = W2f + ((((size_t)(og * OCT2)) * 64 + ci * 16) * 64 + lane) * 8;
            #pragma unroll 2
            for (int ks = 0; ks < 16; ++ks) {
                short8 hf = *(const short8*)&Hsl[((wr * 16 + ks) * 64 + lane) * 8];
                #pragma unroll
                for (int oo = 0; oo < OCT2; ++oo) {
                    short8 w2v = *(const short8*)(w2p + ((size_t)oo * 64 + ks) * 512);
                    acc2[oo] = __builtin_amdgcn_mfma_f32_32x32x16_bf16(w2v, hf, acc2[oo], 0, 0, 0);
                }
            }
        }
    }

    // ---- epilogue: stage acc2(+bias) into LDS [node][outcol] (padded),
    //      then copy full rows out with coalesced line-aligned stores.
    __syncthreads();   // everyone done reading Hsl/Asl
    if (NOUT == 256) {
        // wave wn: out-tile o=wn, rows = both node-tiles (bf16 out: F32OUT=0)
        bf16_t* st = (bf16_t*)smem;
        #pragma unroll
        for (int nt2 = 0; nt2 < 2; ++nt2) {
            const int r = nt2 * 32 + l31;
            #pragma unroll
            for (int g = 0; g < 4; ++g) {
                int oc = wn * 32 + 8 * g + 4 * hi;
                const bool isInit = (oc >= OH);
                int col = isInit ? oc - OH : oc;
                float4 bv = isInit ? *(const float4*)&b2sl[col]
                                   : make_float4(0.f, 0.f, 0.f, 0.f);
                const float* bvp = (const float*)&bv;
                alignas(8) bf16_t ob[4];
                #pragma unroll
                for (int e = 0; e < 4; ++e) ob[e] = f2b(acc2[nt2][4 * g + e] + bvp[e]);
                *(uint2*)&st[r * STR + oc] = *(const uint2*)ob;
            }
        }
    } else {
        const int r = wr * 32 + l31;   // node row within block
        if (F32OUT) {
            float* st = (float*)smem;
            #pragma unroll
            for (int oo = 0; oo < OCT2; ++oo) {
                int o = og * OCT2 + oo;
                #pragma unroll
                for (int g = 0; g < 4; ++g) {
                    int oc = o * 32 + 8 * g + 4 * hi;
                    const bool isInit = (oc >= OH);
                    int col = isInit ? oc - OH : oc;
                    float4 bv = isInit ? *(const float4*)&b2sl[col]
                                       : make_float4(0.f, 0.f, 0.f, 0.f);
                    const float* bvp = (const float*)&bv;
                    float v[4];
                    #pragma unroll
                    for (int e = 0; e < 4; ++e) v[e] = acc2[oo][4 * g + e] + bvp[e];
                    *(float4*)&st[r * STR + oc] = make_float4(v[0], v[1], v[2], v[3]);
                }
            }
        } else {
            bf16_t* st = (bf16_t*)smem;
            #pragma unroll
            for (int oo = 0; oo < OCT2; ++oo) {
                int o = og * OCT2 + oo;
                #pragma unroll
                for (int g = 0; g < 4; ++g) {
                    int oc = o * 32 + 8 * g + 4 * hi;
                    const bool isInit = (oc >= OH);
                    int col = isInit ? oc - OH : oc;
                    float4 bv = isInit ? *(const float4*)&b2sl[col]
                                       : make_float4(0.f, 0.f, 0.f, 0.f);
                    const float* bvp = (const float*)&bv;
                    alignas(8) bf16_t ob[4];
                    #pragma unroll
                    for (int e = 0; e < 4; ++e) ob[e] = f2b(acc2[oo][4 * g + e] + bvp[e]);
                    *(uint2*)&st[r * STR + oc] = *(const uint2*)ob;
                }
            }
        }
    }
    __syncthreads();
    {
        // 16B chunks per node: f32 NOUT*4/16, bf16 NOUT*2/16 -> both 32.
        constexpr int CH = F32OUT ? (NOUT / 4) : (NOUT / 8);
        constexpr int CHH = CH / 2;    // chunks per half-row
        for (int t = tid; t < 64 * CH; t += 512) {
            int nd = t / CH, c = t - (t / CH) * CH;
            int node = bm0 + nd;
            if (node >= NN) continue;
            const bool isInit = (c >= CHH);
            int ch = isInit ? c - CHH : c;
            if (F32OUT) {
                const float* st = (const float*)smem;
                float4 v = *(const float4*)&st[nd * STR + c * 4];
                float* dst = isInit ? (float*)initout : (float*)yout;
                *(float4*)(dst + (size_t)node * OH + ch * 4) = v;
            } else {
                const bf16_t* st = (const bf16_t*)smem;
                uint4 v = *(const uint4*)&st[nd * STR + c * 8];
                bf16_t* dst = isInit ? (bf16_t*)initout : (bf16_t*)yout;
                *(uint4*)(dst + (size_t)node * OH + ch * 8) = v;
            }
        }
    }
}

// ---------------------------------------------------------------------------
// Launch
// ---------------------------------------------------------------------------
extern "C" void kernel_launch(void* const* d_in, const int* in_sizes, int n_in,
                              void* d_out, int out_size, void* d_ws, size_t ws_size,
                              hipStream_t stream) {
    const float* x       = (const float*)d_in[0];
    const int*   ei      = (const int*)d_in[1];
    const int*   batch   = (const int*)d_in[2];
    const float* W1_rel  = (const float*)d_in[3];
    const float* b1      = (const float*)d_in[4];
    const float* W1_root = (const float*)d_in[5];
    const float* W2_rel  = (const float*)d_in[6];
    const float* b2      = (const float*)d_in[7];
    const float* W2_root = (const float*)d_in[8];
    const float* W3_rel  = (const float*)d_in[9];
    const float* b3      = (const float*)d_in[10];
    const float* W3_root = (const float*)d_in[11];
    const float* W4_rel  = (const float*)d_in[12];
    const float* b4      = (const float*)d_in[13];
    const float* W4_root = (const float*)d_in[14];

    float* outF = (float*)d_out;            // [N,64] then [G,128]
    float* enc  = outF + NN * 64;

    char* ws = (char*)d_ws;                         // ~66 MB
    bf16_t* y2buf  = (bf16_t*)(ws + 0);             // [N,128] bf16
    bf16_t* h2init = (bf16_t*)(ws + 12800000ULL);   // [N,128] bf16
    bf16_t* h2buf  = (bf16_t*)(ws + 25600000ULL);   // [N,128] bf16
    float*  y4buf  = (float*)(ws + 38400000ULL);    // [N,64] f32
    int*    cnt    = (int*)(ws + 51200000ULL);      // [N]
    int*    bkt    = (int*)(ws + 51400064ULL);      // [N*64]
    bf16_t* W1f    = (bf16_t*)(ws + 64200064ULL);   // 1024x128 frag-major
    bf16_t* W2f    = (bf16_t*)(ws + 64462208ULL);   // 256x1024 frag-major
    bf16_t* W3f    = (bf16_t*)(ws + 64986496ULL);   // 1024x256 frag-major
    bf16_t* W4f    = (bf16_t*)(ws + 65510784ULL);   // 128x1024 frag-major

    const int RB64 = (NN + 63) / 64;  // 782

    // ---- adjacency + all weight packs in one launch; zero enc for atomics
    hipMemsetAsync(cnt, 0, NN * sizeof(int), stream);
    setup_all<<<NB_BUILD + NB_P1 + NB_P2 + NB_P3 + NB_P4, 256, 0, stream>>>(
        ei, cnt, bkt, W1_rel, W1_root, W2_rel, W2_root,
        W3_rel, W3_root, W4_rel, W4_root, W1f, W2f, W3f, W4f);
    hipMemsetAsync(enc, 0, GG * 128 * sizeof(float), stream);

    // ---- L1+L2 fused: A=[gather(x)|x]; h1 on-chip;
    //      y2 = h1@W2_rel^T (bf16), h2init = h1@W2_root^T + b2 (bf16)
    fused12<128, 256, 0, 1><<<RB64, 512, 0, stream>>>(x, cnt, bkt, W1f, b1, W2f, b2, y2buf, h2init);

    // ---- h2 = relu(h2init + gather(y2)); enc-sums via atomics; then divide
    gather_relu_pool<<<(NN * 16 + 255) / 256, 256, 0, stream>>>(y2buf, h2init, cnt, bkt, batch, h2buf, enc);
    pool_div<<<GG, 128, 0, stream>>>(enc, batch, NN);

    // ---- L3+L4 fused: A=[gather(h2)|h2]; h3 on-chip;
    //      y4 = h3@W4_rel^T (f32), outF = h3@W4_root^T + b4 (f32, direct)
    fused12<256, 128, 1, 0><<<RB64, 512, 0, stream>>>(h2buf, cnt, bkt, W3f, b3, W4f, b4, y4buf, outF);

    // ---- out = outF + gather(y4)
    gather_add_f32_64<<<(NN * 16 + 255) / 256, 256, 0, stream>>>(y4buf, cnt, bkt, outF);
}

// Round 7
// 271.770 us; speedup vs baseline: 8.2641x; 1.7753x over previous
//
#include <hip/hip_runtime.h>
#include <hip/hip_bf16.h>

typedef __hip_bfloat16 bf16_t;
typedef __attribute__((ext_vector_type(8))) short short8;
typedef __attribute__((ext_vector_type(16))) float floatx16;

static __device__ __forceinline__ float b2f(bf16_t v) { return __bfloat162float(v); }
static __device__ __forceinline__ bf16_t f2b(float v) { return __float2bfloat16(v); }
static __device__ __forceinline__ float us2f(unsigned short u) {
    union { unsigned int i; float f; } c; c.i = ((unsigned int)u) << 16; return c.f;
}

// Problem constants
#define NN 50000
#define EE 200000
#define GG 2048
#define BCAP 64   // in-degree cap; mean deg = 4

union U4 { uint4 v; unsigned short s[8]; };

#define FZ16 {0.f,0.f,0.f,0.f,0.f,0.f,0.f,0.f,0.f,0.f,0.f,0.f,0.f,0.f,0.f,0.f}

// 32x32x16 fragment-major layout (A and B operands share it):
//   element (i, k) of an [I x K] K-major matrix lives at
//   ((i/32 * (K/16) + k/16) * 64 + ((k%16)/8)*32 + i%32) * 8 + k%8
// One wave fragment = 64 lanes x short8 = contiguous 1KB.

// ---------------------------------------------------------------------------
// Merged setup: inverted adjacency build + all 4 weight packs in ONE launch
// ---------------------------------------------------------------------------
__device__ __forceinline__ void pack_w1_body(const float* __restrict__ Wa,
                                             const float* __restrict__ Wb,
                                             bf16_t* __restrict__ out,
                                             int K1, int K2, int idx) {
    int K = K1 + K2;
    int KT16 = K >> 4;
    int e = idx & 7;
    int l = (idx >> 3) & 63;
    int tile = idx >> 9;
    int kt = tile % KT16, t = tile / KT16;
    int c = t * 32 + (l & 31);
    int k = kt * 16 + (l >> 5) * 8 + e;
    float v = 0.f;
    if (c < 1000) v = (k < K1) ? Wa[c * K1 + k] : Wb[c * K2 + (k - K1)];
    out[idx] = f2b(v);
}
__device__ __forceinline__ void pack_w2_body(const float* __restrict__ Wa,
                                             const float* __restrict__ Wb,
                                             bf16_t* __restrict__ out,
                                             int OH, int idx) {
    int e = idx & 7;
    int l = (idx >> 3) & 63;
    int tile = idx >> 9;
    int kt2 = tile & 63, o = tile >> 6;   // K=1024 -> 64 k-tiles
    int c = o * 32 + (l & 31);
    int k = kt2 * 16 + (l >> 5) * 8 + e;
    float v = 0.f;
    if (k < 1000) v = (c < OH) ? Wa[c * 1000 + k] : Wb[(c - OH) * 1000 + k];
    out[idx] = f2b(v);
}

#define NB_BUILD 782   // (EE+255)/256
#define NB_P1 512      // 131072/256
#define NB_P2 1024     // 262144/256
#define NB_P3 1024
#define NB_P4 512

__global__ void setup_all(const int* __restrict__ ei, int* __restrict__ cnt,
                          int* __restrict__ bkt,
                          const float* __restrict__ W1_rel, const float* __restrict__ W1_root,
                          const float* __restrict__ W2_rel, const float* __restrict__ W2_root,
                          const float* __restrict__ W3_rel, const float* __restrict__ W3_root,
                          const float* __restrict__ W4_rel, const float* __restrict__ W4_root,
                          bf16_t* __restrict__ W1f, bf16_t* __restrict__ W2f,
                          bf16_t* __restrict__ W3f, bf16_t* __restrict__ W4f) {
    int b = blockIdx.x;
    int tid = threadIdx.x;
    if (b < NB_BUILD) {
        int e = b * 256 + tid;
        if (e < EE) {
            int s = ei[e];
            int d = ei[EE + e];
            int pos = atomicAdd(&cnt[d], 1);
            if (pos < BCAP) bkt[d * BCAP + pos] = s;
        }
    } else if (b < NB_BUILD + NB_P1) {
        pack_w1_body(W1_rel, W1_root, W1f, 64, 64, (b - NB_BUILD) * 256 + tid);
    } else if (b < NB_BUILD + NB_P1 + NB_P2) {
        pack_w2_body(W2_rel, W2_root, W2f, 128, (b - NB_BUILD - NB_P1) * 256 + tid);
    } else if (b < NB_BUILD + NB_P1 + NB_P2 + NB_P3) {
        pack_w1_body(W3_rel, W3_root, W3f, 128, 128, (b - NB_BUILD - NB_P1 - NB_P2) * 256 + tid);
    } else {
        pack_w2_body(W4_rel, W4_root, W4f, 64, (b - NB_BUILD - NB_P1 - NB_P2 - NB_P3) * 256 + tid);
    }
}

// ---------------------------------------------------------------------------
// h2[n] = relu(init[n] + sum nbr y2)   (bf16 [N,128] row-major in/out)
// 4-way batched neighbor loads.  NO atomics (round-6 lesson: device-scope
// f32 atomicAdd across XCDs = ~16x HBM write amplification, 212MB written).
// ---------------------------------------------------------------------------
__global__ void gather_relu_b16(const bf16_t* __restrict__ y2, const bf16_t* __restrict__ init,
                                const int* __restrict__ cnt, const int* __restrict__ bkt,
                                bf16_t* __restrict__ h2) {
    int t = blockIdx.x * 256 + threadIdx.x;
    int n = t >> 4;
    if (n >= NN) return;
    int j = (t & 15) * 8;
    int c = cnt[n]; if (c > BCAP) c = BCAP;
    const int* bp = bkt + n * BCAP;
    U4 u; u.v = *(const uint4*)(init + n * 128 + j);
    float s[8];
    #pragma unroll
    for (int k = 0; k < 8; ++k) s[k] = us2f(u.s[k]);
    int i = 0;
    for (; i + 4 <= c; i += 4) {
        int s0 = bp[i], s1 = bp[i + 1], s2 = bp[i + 2], s3 = bp[i + 3];
        U4 w0, w1, w2, w3;
        w0.v = *(const uint4*)(y2 + (size_t)s0 * 128 + j);
        w1.v = *(const uint4*)(y2 + (size_t)s1 * 128 + j);
        w2.v = *(const uint4*)(y2 + (size_t)s2 * 128 + j);
        w3.v = *(const uint4*)(y2 + (size_t)s3 * 128 + j);
        #pragma unroll
        for (int k = 0; k < 8; ++k)
            s[k] += (us2f(w0.s[k]) + us2f(w1.s[k])) + (us2f(w2.s[k]) + us2f(w3.s[k]));
    }
    for (; i < c; ++i) {
        U4 w; w.v = *(const uint4*)(y2 + (size_t)bp[i] * 128 + j);
        #pragma unroll
        for (int k = 0; k < 8; ++k) s[k] += us2f(w.s[k]);
    }
    alignas(16) bf16_t ob[8];
    #pragma unroll
    for (int k = 0; k < 8; ++k) ob[k] = f2b(fmaxf(s[k], 0.f));
    *(uint4*)(h2 + n * 128 + j) = *(const uint4*)ob;
}

// ---------------------------------------------------------------------------
// Mean-pool per graph (batch sorted; binary search), h2 bf16.
// 256 threads: 2 node-parallel waves halve the serial node chain.
// ---------------------------------------------------------------------------
__global__ void pool_kernel(const bf16_t* __restrict__ h2,
                            const int* __restrict__ batch,
                            float* __restrict__ enc, int Nn) {
    int g = blockIdx.x;
    __shared__ int s_lo, s_hi;
    __shared__ float part[128];
    if (threadIdx.x == 0) {
        int lo = 0, hi = Nn;
        while (lo < hi) { int mid = (lo + hi) >> 1; if (batch[mid] < g) lo = mid + 1; else hi = mid; }
        s_lo = lo;
        hi = Nn;
        while (lo < hi) { int mid = (lo + hi) >> 1; if (batch[mid] < g + 1) lo = mid + 1; else hi = mid; }
        s_hi = lo;
    }
    __syncthreads();
    int f = threadIdx.x & 127;
    int ty = threadIdx.x >> 7;   // 0..1
    float sum = 0.f;
    for (int n = s_lo + ty; n < s_hi; n += 2) sum += b2f(h2[n * 128 + f]);
    if (ty == 1) part[f] = sum;
    __syncthreads();
    if (ty == 0) {
        float tot = sum + part[f];
        float cnt = (float)((s_hi - s_lo) > 0 ? (s_hi - s_lo) : 1);
        enc[g * 128 + f] = tot / cnt;
    }
}

// outF[n] += sum nbr y4   (f32 [N,64] row-major, in-place on d_out)
__global__ void gather_add_f32_64(const float* __restrict__ y4, const int* __restrict__ cnt,
                                  const int* __restrict__ bkt, float* __restrict__ outF) {
    int t = blockIdx.x * 256 + threadIdx.x;
    int n = t >> 4;
    if (n >= NN) return;
    int j = (t & 15) * 4;
    int c = cnt[n]; if (c > BCAP) c = BCAP;
    const int* bp = bkt + n * BCAP;
    float4 sum = *(const float4*)(outF + n * 64 + j);
    int i = 0;
    for (; i + 4 <= c; i += 4) {
        int s0 = bp[i], s1 = bp[i + 1], s2 = bp[i + 2], s3 = bp[i + 3];
        float4 v0 = *(const float4*)(y4 + (size_t)s0 * 64 + j);
        float4 v1 = *(const float4*)(y4 + (size_t)s1 * 64 + j);
        float4 v2 = *(const float4*)(y4 + (size_t)s2 * 64 + j);
        float4 v3 = *(const float4*)(y4 + (size_t)s3 * 64 + j);
        sum.x += (v0.x + v1.x) + (v2.x + v3.x);
        sum.y += (v0.y + v1.y) + (v2.y + v3.y);
        sum.z += (v0.z + v1.z) + (v2.z + v3.z);
        sum.w += (v0.w + v1.w) + (v2.w + v3.w);
    }
    for (; i < c; ++i) {
        float4 v = *(const float4*)(y4 + (size_t)bp[i] * 64 + j);
        sum.x += v.x; sum.y += v.y; sum.z += v.z; sum.w += v.w;
    }
    *(float4*)(outF + n * 64 + j) = sum;
}

// ---------------------------------------------------------------------------
// Fused gather + two-GEMM v13 = v12 (W2-dedup for NOUT=256) + 4-DEEP BATCHED
// WEIGHT LOADS in both MFMA stages. Latency analysis (r3/r4): kernels are
// latency-bound on L2-resident weight loads (~250cy); barriers drain vmcnt
// each chunk so only intra-phase ILP helps. 8-deep prefetch spilled at the
// 128-reg cap (v7); <=2-deep hides nothing (v9/v10). 4-deep: issue 4 loads
// (16 VGPR), consume with 8 MFMAs. Peak live set ~121 < 128.
// Tripwire: WRITE_SIZE > 30MB = spills -> reduce depth.
//   Block = 64 nodes (2 node-tiles of 32), 512 threads = 8 waves.
//   Stage 1: wave wn owns hcol-tile (ci*8+wn) x BOTH node tiles.
//   H chunk [64 x 256] bf16, single-buffered (32KB), frag-major.
//   Stage 2 NOUT=256: wave wn owns out-tile wn x BOTH node-tiles (W2 dedup).
//   Stage 2 NOUT=128: wave (og, wr): 1 out-tile x node-tile wr.
// Outputs: outcol < NOUT/2 -> yout, else -> initout (+bias2).
// ---------------------------------------------------------------------------
template <int K, int NOUT, int F32OUT, int SRCF32>
__global__ __launch_bounds__(512, 4) void fused13(
    const void* __restrict__ src, const int* __restrict__ cnt,
    const int* __restrict__ bkt,
    const bf16_t* __restrict__ W1f, const float* __restrict__ bias1,
    const bf16_t* __restrict__ W2f, const float* __restrict__ bias2,
    void* __restrict__ yout, void* __restrict__ initout)
{
    constexpr int KT16 = K / 16;      // A k-tiles (16-deep), 8 or 16
    constexpr int OT32 = NOUT / 32;   // out 32-col tiles (8 or 4)
    constexpr int OCT2 = OT32 / 4;    // out tiles per wave, old mapping (2 or 1)
    constexpr int NACC = (NOUT == 256) ? 2 : OCT2;
    constexpr int OH   = NOUT / 2;
    constexpr int SW   = K / 2;       // source row width (64 f32 / 128 bf16)
    constexpr int HALF = K / 16;      // 8-col groups per half (8 or 16)
    constexpr int STR  = F32OUT ? (NOUT + 4) : (NOUT + 8);
    __shared__ float b1sl[1024];
    __shared__ float b2sl[128];
    __shared__ __align__(16) char smem[(size_t)64 * K * 2 + 64 * 256 * 2];
    bf16_t* Asl = (bf16_t*)smem;                        // frag-major A tile [64*K]
    bf16_t* Hsl = (bf16_t*)(smem + (size_t)64 * K * 2); // frag-major H chunk [64*256]

    const int tid  = threadIdx.x;
    const int lane = tid & 63;
    const int wn   = tid >> 6;        // 0..7
    const int l31  = lane & 31;
    const int hi   = lane >> 5;
    const int og   = wn >> 1;         // old stage-2 out-col group
    const int wr   = wn & 1;          // old stage-2 node-tile
    const int bm0  = blockIdx.x * 64;

    for (int i = tid; i < 1024; i += 512) b1sl[i] = (i < 1000) ? bias1[i] : 0.f;
    if (tid < OH) b2sl[tid] = bias2[tid];

    // ---- prologue: gather + own-copy directly into Asl (frag-major)
    #pragma unroll
    for (int it = 0; it < (2 * 64 * HALF) / 512; ++it) {
        int task = it * 512 + tid;
        const bool own = task >= 64 * HALF;
        int t2 = own ? task - 64 * HALF : task;
        int i = t2 / HALF, s = t2 - (t2 / HALF) * HALF;
        int n = bm0 + i;
        int j = s * 8;
        float sum[8] = {0.f, 0.f, 0.f, 0.f, 0.f, 0.f, 0.f, 0.f};
        if (n < NN) {
            if (!own) {
                int c = cnt[n]; if (c > BCAP) c = BCAP;
                const int* bp = bkt + n * BCAP;
                int e = 0;
                for (; e + 4 <= c; e += 4) {
                    int s0 = bp[e], s1 = bp[e + 1], s2 = bp[e + 2], s3 = bp[e + 3];
                    if (SRCF32) {
                        const float* r0 = (const float*)src + (size_t)s0 * SW + j;
                        const float* r1 = (const float*)src + (size_t)s1 * SW + j;
                        const float* r2 = (const float*)src + (size_t)s2 * SW + j;
                        const float* r3 = (const float*)src + (size_t)s3 * SW + j;
                        float4 a0 = *(const float4*)r0, b0 = *(const float4*)(r0 + 4);
                        float4 a1 = *(const float4*)r1, b1 = *(const float4*)(r1 + 4);
                        float4 a2 = *(const float4*)r2, b2 = *(const float4*)(r2 + 4);
                        float4 a3 = *(const float4*)r3, b3 = *(const float4*)(r3 + 4);
                        sum[0] += (a0.x + a1.x) + (a2.x + a3.x);
                        sum[1] += (a0.y + a1.y) + (a2.y + a3.y);
                        sum[2] += (a0.z + a1.z) + (a2.z + a3.z);
                        sum[3] += (a0.w + a1.w) + (a2.w + a3.w);
                        sum[4] += (b0.x + b1.x) + (b2.x + b3.x);
                        sum[5] += (b0.y + b1.y) + (b2.y + b3.y);
                        sum[6] += (b0.z + b1.z) + (b2.z + b3.z);
                        sum[7] += (b0.w + b1.w) + (b2.w + b3.w);
                    } else {
                        U4 w0, w1, w2, w3;
                        w0.v = *(const uint4*)((const bf16_t*)src + (size_t)s0 * SW + j);
                        w1.v = *(const uint4*)((const bf16_t*)src + (size_t)s1 * SW + j);
                        w2.v = *(const uint4*)((const bf16_t*)src + (size_t)s2 * SW + j);
                        w3.v = *(const uint4*)((const bf16_t*)src + (size_t)s3 * SW + j);
                        #pragma unroll
                        for (int k = 0; k < 8; ++k)
                            sum[k] += (us2f(w0.s[k]) + us2f(w1.s[k])) + (us2f(w2.s[k]) + us2f(w3.s[k]));
                    }
                }
                for (; e < c; ++e) {
                    int sn = bp[e];
                    if (SRCF32) {
                        const float* r = (const float*)src + (size_t)sn * SW + j;
                        float4 a = *(const float4*)r;
                        float4 b = *(const float4*)(r + 4);
                        sum[0] += a.x; sum[1] += a.y; sum[2] += a.z; sum[3] += a.w;
                        sum[4] += b.x; sum[5] += b.y; sum[6] += b.z; sum[7] += b.w;
                    } else {
                        U4 w; w.v = *(const uint4*)((const bf16_t*)src + (size_t)sn * SW + j);
                        #pragma unroll
                        for (int k = 0; k < 8; ++k) sum[k] += us2f(w.s[k]);
                    }
                }
            } else {
                if (SRCF32) {
                    const float* r = (const float*)src + (size_t)n * SW + j;
                    float4 a = *(const float4*)r;
                    float4 b = *(const float4*)(r + 4);
                    sum[0] = a.x; sum[1] = a.y; sum[2] = a.z; sum[3] = a.w;
                    sum[4] = b.x; sum[5] = b.y; sum[6] = b.z; sum[7] = b.w;
                } else {
                    U4 w; w.v = *(const uint4*)((const bf16_t*)src + (size_t)n * SW + j);
                    #pragma unroll
                    for (int k = 0; k < 8; ++k) sum[k] = us2f(w.s[k]);
                }
            }
        }
        int cc = (own ? K / 2 : 0) + j;           // column in A's K-space
        int off = (((i >> 5) * KT16 + (cc >> 4)) * 64 + ((cc >> 3) & 1) * 32 + (i & 31)) * 8;
        alignas(16) bf16_t ob[8];
        #pragma unroll
        for (int k = 0; k < 8; ++k) ob[k] = f2b(sum[k]);
        *(uint4*)(&Asl[off]) = *(const uint4*)ob;
    }

    floatx16 acc2[NACC];
    #pragma unroll
    for (int oo = 0; oo < NACC; ++oo) acc2[oo] = (floatx16)FZ16;

    __syncthreads();   // Asl + biases ready

    for (int ci = 0; ci < 4; ++ci) {
        // ---- stage 1: wave computes h-tile (ci*8 + wn) x both node-tiles
        //      4-deep batched w1 loads (16 VGPR), 8 MFMAs per batch.
        floatx16 acc1[2];
        acc1[0] = (floatx16)FZ16;
        acc1[1] = (floatx16)FZ16;

        const bf16_t* w1p = W1f + (((size_t)(ci * 8 + wn) * KT16) * 64 + lane) * 8;
        #pragma unroll
        for (int kh = 0; kh < KT16 / 4; ++kh) {
            short8 w1v[4];
            #pragma unroll
            for (int u = 0; u < 4; ++u)
                w1v[u] = *(const short8*)(w1p + (size_t)(kh * 4 + u) * 512);
            #pragma unroll
            for (int u = 0; u < 4; ++u) {
                int kk = kh * 4 + u;
                short8 av0 = *(const short8*)&Asl[((0 * KT16 + kk) * 64 + lane) * 8];
                acc1[0] = __builtin_amdgcn_mfma_f32_32x32x16_bf16(w1v[u], av0, acc1[0], 0, 0, 0);
                short8 av1 = *(const short8*)&Asl[((1 * KT16 + kk) * 64 + lane) * 8];
                acc1[1] = __builtin_amdgcn_mfma_f32_32x32x16_bf16(w1v[u], av1, acc1[1], 0, 0, 0);
            }
        }

        __syncthreads();   // previous chunk's stage-2 readers done with Hsl

        // bias+relu -> frag-major H; C/D: node=l31, hcol32=(r&3)+8*(r>>2)+4*hi
        #pragma unroll
        for (int nt2 = 0; nt2 < 2; ++nt2) {
            #pragma unroll
            for (int g = 0; g < 4; ++g) {
                float4 bv = *(const float4*)&b1sl[ci * 256 + wn * 32 + 8 * g + 4 * hi];
                const float* bvp = (const float*)&bv;
                alignas(8) bf16_t hb[4];
                #pragma unroll
                for (int e = 0; e < 4; ++e)
                    hb[e] = f2b(fmaxf(acc1[nt2][4 * g + e] + bvp[e], 0.f));
                int off = ((nt2 * 16 + wn * 2 + (g >> 1)) * 64 + (g & 1) * 32 + l31) * 8 + 4 * hi;
                *(uint2*)&Hsl[off] = *(const uint2*)hb;
            }
        }

        __syncthreads();   // H chunk visible

        // ---- stage 2 (4-deep batched w2 loads)
        if (NOUT == 256) {
            // dedup mapping: wave wn owns out-tile o=wn x BOTH node-tiles
            const bf16_t* w2p = W2f + (((size_t)wn * 64 + ci * 16) * 64 + lane) * 8;
            #pragma unroll
            for (int kg = 0; kg < 4; ++kg) {
                short8 w2v[4];
                #pragma unroll
                for (int u = 0; u < 4; ++u)
                    w2v[u] = *(const short8*)(w2p + (size_t)(kg * 4 + u) * 512);
                #pragma unroll
                for (int u = 0; u < 4; ++u) {
                    int ks = kg * 4 + u;
                    short8 hf0 = *(const short8*)&Hsl[((0 * 16 + ks) * 64 + lane) * 8];
                    acc2[0] = __builtin_amdgcn_mfma_f32_32x32x16_bf16(w2v[u], hf0, acc2[0], 0, 0, 0);
                    short8 hf1 = *(const short8*)&Hsl[((1 * 16 + ks) * 64 + lane) * 8];
                    acc2[1] = __builtin_amdgcn_mfma_f32_32x32x16_bf16(w2v[u], hf1, acc2[1], 0, 0, 0);
                }
            }
        } else {
            // old mapping: wave (og, wr): 1 out-tile x node-tile wr
            const bf16_t* w2p = W2f + ((((size_t)og) * 64 + ci * 16) * 64 + lane) * 8;
            #pragma unroll
            for (int kg = 0; kg < 4; ++kg) {
                short8 w2v[4];
                #pragma unroll
                for (int u = 0; u < 4; ++u)
                    w2v[u] = *(const short8*)(w2p + (size_t)(kg * 4 + u) * 512);
                #pragma unroll
                for (int u = 0; u < 4; ++u) {
                    int ks = kg * 4 + u;
                    short8 hf = *(const short8*)&Hsl[((wr * 16 + ks) * 64 + lane) * 8];
                    acc2[0] = __builtin_amdgcn_mfma_f32_32x32x16_bf16(w2v[u], hf, acc2[0], 0, 0, 0);
                }
            }
        }
    }

    // ---- epilogue: stage acc2(+bias) into LDS [node][outcol] (padded),
    //      then copy full rows out with coalesced line-aligned stores.
    __syncthreads();   // everyone done reading Hsl/Asl
    if (NOUT == 256) {
        // wave wn: out-tile o=wn, rows = both node-tiles (bf16 out: F32OUT=0)
        bf16_t* st = (bf16_t*)smem;
        #pragma unroll
        for (int nt2 = 0; nt2 < 2; ++nt2) {
            const int r = nt2 * 32 + l31;
            #pragma unroll
            for (int g = 0; g < 4; ++g) {
                int oc = wn * 32 + 8 * g + 4 * hi;
                const bool isInit = (oc >= OH);
                int col = isInit ? oc - OH : oc;
                float4 bv = isInit ? *(const float4*)&b2sl[col]
                                   : make_float4(0.f, 0.f, 0.f, 0.f);
                const float* bvp = (const float*)&bv;
                alignas(8) bf16_t ob[4];
                #pragma unroll
                for (int e = 0; e < 4; ++e) ob[e] = f2b(acc2[nt2][4 * g + e] + bvp[e]);
                *(uint2*)&st[r * STR + oc] = *(const uint2*)ob;
            }
        }
    } else {
        const int r = wr * 32 + l31;   // node row within block
        if (F32OUT) {
            float* st = (float*)smem;
            #pragma unroll
            for (int oo = 0; oo < OCT2; ++oo) {
                int o = og * OCT2 + oo;
                #pragma unroll
                for (int g = 0; g < 4; ++g) {
                    int oc = o * 32 + 8 * g + 4 * hi;
                    const bool isInit = (oc >= OH);
                    int col = isInit ? oc - OH : oc;
                    float4 bv = isInit ? *(const float4*)&b2sl[col]
                                       : make_float4(0.f, 0.f, 0.f, 0.f);
                    const float* bvp = (const float*)&bv;
                    float v[4];
                    #pragma unroll
                    for (int e = 0; e < 4; ++e) v[e] = acc2[oo][4 * g + e] + bvp[e];
                    *(float4*)&st[r * STR + oc] = make_float4(v[0], v[1], v[2], v[3]);
                }
            }
        } else {
            bf16_t* st = (bf16_t*)smem;
            #pragma unroll
            for (int oo = 0; oo < OCT2; ++oo) {
                int o = og * OCT2 + oo;
                #pragma unroll
                for (int g = 0; g < 4; ++g) {
                    int oc = o * 32 + 8 * g + 4 * hi;
                    const bool isInit = (oc >= OH);
                    int col = isInit ? oc - OH : oc;
                    float4 bv = isInit ? *(const float4*)&b2sl[col]
                                       : make_float4(0.f, 0.f, 0.f, 0.f);
                    const float* bvp = (const float*)&bv;
                    alignas(8) bf16_t ob[4];
                    #pragma unroll
                    for (int e = 0; e < 4; ++e) ob[e] = f2b(acc2[oo][4 * g + e] + bvp[e]);
                    *(uint2*)&st[r * STR + oc] = *(const uint2*)ob;
                }
            }
        }
    }
    __syncthreads();
    {
        // 16B chunks per node: f32 NOUT*4/16, bf16 NOUT*2/16 -> both 32.
        constexpr int CH = F32OUT ? (NOUT / 4) : (NOUT / 8);
        constexpr int CHH = CH / 2;    // chunks per half-row
        for (int t = tid; t < 64 * CH; t += 512) {
            int nd = t / CH, c = t - (t / CH) * CH;
            int node = bm0 + nd;
            if (node >= NN) continue;
            const bool isInit = (c >= CHH);
            int ch = isInit ? c - CHH : c;
            if (F32OUT) {
                const float* st = (const float*)smem;
                float4 v = *(const float4*)&st[nd * STR + c * 4];
                float* dst = isInit ? (float*)initout : (float*)yout;
                *(float4*)(dst + (size_t)node * OH + ch * 4) = v;
            } else {
                const bf16_t* st = (const bf16_t*)smem;
                uint4 v = *(const uint4*)&st[nd * STR + c * 8];
                bf16_t* dst = isInit ? (bf16_t*)initout : (bf16_t*)yout;
                *(uint4*)(dst + (size_t)node * OH + ch * 8) = v;
            }
        }
    }
}

// ---------------------------------------------------------------------------
// Launch
// ---------------------------------------------------------------------------
extern "C" void kernel_launch(void* const* d_in, const int* in_sizes, int n_in,
                              void* d_out, int out_size, void* d_ws, size_t ws_size,
                              hipStream_t stream) {
    const float* x       = (const float*)d_in[0];
    const int*   ei      = (const int*)d_in[1];
    const int*   batch   = (const int*)d_in[2];
    const float* W1_rel  = (const float*)d_in[3];
    const float* b1      = (const float*)d_in[4];
    const float* W1_root = (const float*)d_in[5];
    const float* W2_rel  = (const float*)d_in[6];
    const float* b2      = (const float*)d_in[7];
    const float* W2_root = (const float*)d_in[8];
    const float* W3_rel  = (const float*)d_in[9];
    const float* b3      = (const float*)d_in[10];
    const float* W3_root = (const float*)d_in[11];
    const float* W4_rel  = (const float*)d_in[12];
    const float* b4      = (const float*)d_in[13];
    const float* W4_root = (const float*)d_in[14];

    float* outF = (float*)d_out;            // [N,64] then [G,128]
    float* enc  = outF + NN * 64;

    char* ws = (char*)d_ws;                         // ~66 MB
    bf16_t* y2buf  = (bf16_t*)(ws + 0);             // [N,128] bf16
    bf16_t* h2init = (bf16_t*)(ws + 12800000ULL);   // [N,128] bf16
    bf16_t* h2buf  = (bf16_t*)(ws + 25600000ULL);   // [N,128] bf16
    float*  y4buf  = (float*)(ws + 38400000ULL);    // [N,64] f32
    int*    cnt    = (int*)(ws + 51200000ULL);      // [N]
    int*    bkt    = (int*)(ws + 51400064ULL);      // [N*64]
    bf16_t* W1f    = (bf16_t*)(ws + 64200064ULL);   // 1024x128 frag-major
    bf16_t* W2f    = (bf16_t*)(ws + 64462208ULL);   // 256x1024 frag-major
    bf16_t* W3f    = (bf16_t*)(ws + 64986496ULL);   // 1024x256 frag-major
    bf16_t* W4f    = (bf16_t*)(ws + 65510784ULL);   // 128x1024 frag-major

    const int RB64 = (NN + 63) / 64;  // 782

    // ---- adjacency + all weight packs in one launch
    hipMemsetAsync(cnt, 0, NN * sizeof(int), stream);
    setup_all<<<NB_BUILD + NB_P1 + NB_P2 + NB_P3 + NB_P4, 256, 0, stream>>>(
        ei, cnt, bkt, W1_rel, W1_root, W2_rel, W2_root,
        W3_rel, W3_root, W4_rel, W4_root, W1f, W2f, W3f, W4f);

    // ---- L1+L2 fused: A=[gather(x)|x]; h1 on-chip;
    //      y2 = h1@W2_rel^T (bf16), h2init = h1@W2_root^T + b2 (bf16)
    fused13<128, 256, 0, 1><<<RB64, 512, 0, stream>>>(x, cnt, bkt, W1f, b1, W2f, b2, y2buf, h2init);

    // ---- h2 = relu(h2init + gather(y2));  encoded = mean-pool(h2)
    gather_relu_b16<<<(NN * 16 + 255) / 256, 256, 0, stream>>>(y2buf, h2init, cnt, bkt, h2buf);
    pool_kernel<<<GG, 256, 0, stream>>>(h2buf, batch, enc, NN);

    // ---- L3+L4 fused: A=[gather(h2)|h2]; h3 on-chip;
    //      y4 = h3@W4_rel^T (f32), outF = h3@W4_root^T + b4 (f32, direct)
    fused13<256, 128, 1, 0><<<RB64, 512, 0, stream>>>(h2buf, cnt, bkt, W3f, b3, W4f, b4, y4buf, outF);

    // ---- out = outF + gather(y4)
    gather_add_f32_64<<<(NN * 16 + 255) / 256, 256, 0, stream>>>(y4buf, cnt, bkt, outF);
}

// Round 9
// 267.135 us; speedup vs baseline: 8.4075x; 1.0174x over previous
//
#include <hip/hip_runtime.h>
#include <hip/hip_bf16.h>

typedef __hip_bfloat16 bf16_t;
typedef __attribute__((ext_vector_type(8))) short short8;
typedef __attribute__((ext_vector_type(16))) float floatx16;

static __device__ __forceinline__ float b2f(bf16_t v) { return __bfloat162float(v); }
static __device__ __forceinline__ bf16_t f2b(float v) { return __float2bfloat16(v); }
static __device__ __forceinline__ float us2f(unsigned short u) {
    union { unsigned int i; float f; } c; c.i = ((unsigned int)u) << 16; return c.f;
}

// Problem constants
#define NN 50000
#define EE 200000
#define GG 2048
#define BCAP 64   // in-degree cap; mean deg = 4

union U4 { uint4 v; unsigned short s[8]; };
union U2 { uint2 v; unsigned short s[4]; };

#define FZ16 {0.f,0.f,0.f,0.f,0.f,0.f,0.f,0.f,0.f,0.f,0.f,0.f,0.f,0.f,0.f,0.f}

// 32x32x16 fragment-major layout (A and B operands share it):
//   element (i, k) of an [I x K] K-major matrix lives at
//   ((i/32 * (K/16) + k/16) * 64 + ((k%16)/8)*32 + i%32) * 8 + k%8
// One wave fragment = 64 lanes x short8 = contiguous 1KB.

// ---------------------------------------------------------------------------
// Merged setup: inverted adjacency build + all 4 weight packs in ONE launch
// ---------------------------------------------------------------------------
__device__ __forceinline__ void pack_w1_body(const float* __restrict__ Wa,
                                             const float* __restrict__ Wb,
                                             bf16_t* __restrict__ out,
                                             int K1, int K2, int idx) {
    int K = K1 + K2;
    int KT16 = K >> 4;
    int e = idx & 7;
    int l = (idx >> 3) & 63;
    int tile = idx >> 9;
    int kt = tile % KT16, t = tile / KT16;
    int c = t * 32 + (l & 31);
    int k = kt * 16 + (l >> 5) * 8 + e;
    float v = 0.f;
    if (c < 1000) v = (k < K1) ? Wa[c * K1 + k] : Wb[c * K2 + (k - K1)];
    out[idx] = f2b(v);
}
__device__ __forceinline__ void pack_w2_body(const float* __restrict__ Wa,
                                             const float* __restrict__ Wb,
                                             bf16_t* __restrict__ out,
                                             int OH, int idx) {
    int e = idx & 7;
    int l = (idx >> 3) & 63;
    int tile = idx >> 9;
    int kt2 = tile & 63, o = tile >> 6;   // K=1024 -> 64 k-tiles
    int c = o * 32 + (l & 31);
    int k = kt2 * 16 + (l >> 5) * 8 + e;
    float v = 0.f;
    if (k < 1000) v = (c < OH) ? Wa[c * 1000 + k] : Wb[(c - OH) * 1000 + k];
    out[idx] = f2b(v);
}

#define NB_BUILD 782   // (EE+255)/256
#define NB_P1 512      // 131072/256
#define NB_P2 1024     // 262144/256
#define NB_P3 1024
#define NB_P4 512

__global__ void setup_all(const int* __restrict__ ei, int* __restrict__ cnt,
                          int* __restrict__ bkt,
                          const float* __restrict__ W1_rel, const float* __restrict__ W1_root,
                          const float* __restrict__ W2_rel, const float* __restrict__ W2_root,
                          const float* __restrict__ W3_rel, const float* __restrict__ W3_root,
                          const float* __restrict__ W4_rel, const float* __restrict__ W4_root,
                          bf16_t* __restrict__ W1f, bf16_t* __restrict__ W2f,
                          bf16_t* __restrict__ W3f, bf16_t* __restrict__ W4f) {
    int b = blockIdx.x;
    int tid = threadIdx.x;
    if (b < NB_BUILD) {
        int e = b * 256 + tid;
        if (e < EE) {
            int s = ei[e];
            int d = ei[EE + e];
            int pos = atomicAdd(&cnt[d], 1);
            if (pos < BCAP) bkt[d * BCAP + pos] = s;
        }
    } else if (b < NB_BUILD + NB_P1) {
        pack_w1_body(W1_rel, W1_root, W1f, 64, 64, (b - NB_BUILD) * 256 + tid);
    } else if (b < NB_BUILD + NB_P1 + NB_P2) {
        pack_w2_body(W2_rel, W2_root, W2f, 128, (b - NB_BUILD - NB_P1) * 256 + tid);
    } else if (b < NB_BUILD + NB_P1 + NB_P2 + NB_P3) {
        pack_w1_body(W3_rel, W3_root, W3f, 128, 128, (b - NB_BUILD - NB_P1 - NB_P2) * 256 + tid);
    } else {
        pack_w2_body(W4_rel, W4_root, W4f, 64, (b - NB_BUILD - NB_P1 - NB_P2 - NB_P3) * 256 + tid);
    }
}

// ---------------------------------------------------------------------------
// Per-graph fused gather+relu+mean-pool (one block = one graph; batch sorted).
// h2[n] = relu(init[n] + sum nbr y2); enc[g] = mean over graph's h2 rows.
// Pool partials reduced in LDS (round-6 lesson: NO cross-XCD f32 atomics).
// 256 threads = 16 node-slots x 16 col-groups of 8.
// ---------------------------------------------------------------------------
__global__ void gather_relu_pool(const bf16_t* __restrict__ y2, const bf16_t* __restrict__ init,
                                 const int* __restrict__ cnt, const int* __restrict__ bkt,
                                 const int* __restrict__ batch,
                                 bf16_t* __restrict__ h2, float* __restrict__ enc, int Nn) {
    int g = blockIdx.x;
    __shared__ int s_lo, s_hi;
    __shared__ float red[16][128];   // 8KB partials
    if (threadIdx.x == 0) {
        int lo = 0, hi = Nn;
        while (lo < hi) { int mid = (lo + hi) >> 1; if (batch[mid] < g) lo = mid + 1; else hi = mid; }
        s_lo = lo;
        hi = Nn;
        while (lo < hi) { int mid = (lo + hi) >> 1; if (batch[mid] < g + 1) lo = mid + 1; else hi = mid; }
        s_hi = lo;
    }
    __syncthreads();
    const int lo = s_lo, hi = s_hi;
    const int slot = threadIdx.x >> 4;      // 0..15 node slot
    const int j = (threadIdx.x & 15) * 8;   // col group
    float psum[8] = {0.f,0.f,0.f,0.f,0.f,0.f,0.f,0.f};
    for (int n = lo + slot; n < hi; n += 16) {
        int c = cnt[n]; if (c > BCAP) c = BCAP;
        const int* bp = bkt + n * BCAP;
        U4 u; u.v = *(const uint4*)(init + (size_t)n * 128 + j);
        float s[8];
        #pragma unroll
        for (int k = 0; k < 8; ++k) s[k] = us2f(u.s[k]);
        int i = 0;
        for (; i + 4 <= c; i += 4) {
            int s0 = bp[i], s1 = bp[i + 1], s2 = bp[i + 2], s3 = bp[i + 3];
            U4 w0, w1, w2, w3;
            w0.v = *(const uint4*)(y2 + (size_t)s0 * 128 + j);
            w1.v = *(const uint4*)(y2 + (size_t)s1 * 128 + j);
            w2.v = *(const uint4*)(y2 + (size_t)s2 * 128 + j);
            w3.v = *(const uint4*)(y2 + (size_t)s3 * 128 + j);
            #pragma unroll
            for (int k = 0; k < 8; ++k)
                s[k] += (us2f(w0.s[k]) + us2f(w1.s[k])) + (us2f(w2.s[k]) + us2f(w3.s[k]));
        }
        for (; i < c; ++i) {
            U4 w; w.v = *(const uint4*)(y2 + (size_t)bp[i] * 128 + j);
            #pragma unroll
            for (int k = 0; k < 8; ++k) s[k] += us2f(w.s[k]);
        }
        alignas(16) bf16_t ob[8];
        #pragma unroll
        for (int k = 0; k < 8; ++k) {
            s[k] = fmaxf(s[k], 0.f);
            psum[k] += s[k];
            ob[k] = f2b(s[k]);
        }
        *(uint4*)(h2 + (size_t)n * 128 + j) = *(const uint4*)ob;
    }
    #pragma unroll
    for (int k = 0; k < 8; ++k) red[slot][j + k] = psum[k];
    __syncthreads();
    if (threadIdx.x < 128) {
        int c = threadIdx.x;
        float tot = 0.f;
        #pragma unroll
        for (int r = 0; r < 16; ++r) tot += red[r][c];
        float n = (float)((hi - lo) > 0 ? (hi - lo) : 1);
        enc[(size_t)g * 128 + c] = tot / n;
    }
}

// outF[n] += sum nbr y4   (y4 now bf16 [N,64]; outF f32 in-place on d_out)
__global__ void gather_add_b16_64(const bf16_t* __restrict__ y4, const int* __restrict__ cnt,
                                  const int* __restrict__ bkt, float* __restrict__ outF) {
    int t = blockIdx.x * 256 + threadIdx.x;
    int n = t >> 4;
    if (n >= NN) return;
    int j = (t & 15) * 4;
    int c = cnt[n]; if (c > BCAP) c = BCAP;
    const int* bp = bkt + n * BCAP;
    float4 sum = *(const float4*)(outF + n * 64 + j);
    int i = 0;
    for (; i + 4 <= c; i += 4) {
        int s0 = bp[i], s1 = bp[i + 1], s2 = bp[i + 2], s3 = bp[i + 3];
        U2 w0, w1, w2, w3;
        w0.v = *(const uint2*)(y4 + (size_t)s0 * 64 + j);
        w1.v = *(const uint2*)(y4 + (size_t)s1 * 64 + j);
        w2.v = *(const uint2*)(y4 + (size_t)s2 * 64 + j);
        w3.v = *(const uint2*)(y4 + (size_t)s3 * 64 + j);
        sum.x += (us2f(w0.s[0]) + us2f(w1.s[0])) + (us2f(w2.s[0]) + us2f(w3.s[0]));
        sum.y += (us2f(w0.s[1]) + us2f(w1.s[1])) + (us2f(w2.s[1]) + us2f(w3.s[1]));
        sum.z += (us2f(w0.s[2]) + us2f(w1.s[2])) + (us2f(w2.s[2]) + us2f(w3.s[2]));
        sum.w += (us2f(w0.s[3]) + us2f(w1.s[3])) + (us2f(w2.s[3]) + us2f(w3.s[3]));
    }
    for (; i < c; ++i) {
        U2 w; w.v = *(const uint2*)(y4 + (size_t)bp[i] * 64 + j);
        sum.x += us2f(w.s[0]); sum.y += us2f(w.s[1]);
        sum.z += us2f(w.s[2]); sum.w += us2f(w.s[3]);
    }
    *(float4*)(outF + n * 64 + j) = sum;
}

// ---------------------------------------------------------------------------
// Fused gather + two-GEMM v14 = v13 (4-deep batched weight loads, W2-dedup
// for NOUT=256) + YBF16: for the NOUT=128 instantiation the yout half (y4,
// internal intermediate) is written bf16 while initout (d_out) stays f32 --
// halves fused2's y-write and gather_add's neighbor-read traffic.
//   Block = 64 nodes (2 node-tiles of 32), 512 threads = 8 waves.
//   Stage 1: wave wn owns hcol-tile (ci*8+wn) x BOTH node tiles.
//   H chunk [64 x 256] bf16, single-buffered (32KB), frag-major.
//   Stage 2 NOUT=256: wave wn owns out-tile wn x BOTH node-tiles (W2 dedup).
//   Stage 2 NOUT=128: wave (og, wr): 1 out-tile x node-tile wr.
// Outputs: outcol < NOUT/2 -> yout, else -> initout (+bias2).
// ---------------------------------------------------------------------------
template <int K, int NOUT, int F32OUT, int YBF16, int SRCF32>
__global__ __launch_bounds__(512, 4) void fused14(
    const void* __restrict__ src, const int* __restrict__ cnt,
    const int* __restrict__ bkt,
    const bf16_t* __restrict__ W1f, const float* __restrict__ bias1,
    const bf16_t* __restrict__ W2f, const float* __restrict__ bias2,
    void* __restrict__ yout, void* __restrict__ initout)
{
    constexpr int KT16 = K / 16;      // A k-tiles (16-deep), 8 or 16
    constexpr int OT32 = NOUT / 32;   // out 32-col tiles (8 or 4)
    constexpr int OCT2 = OT32 / 4;    // out tiles per wave, old mapping (2 or 1)
    constexpr int NACC = (NOUT == 256) ? 2 : OCT2;
    constexpr int OH   = NOUT / 2;
    constexpr int SW   = K / 2;       // source row width (64 f32 / 128 bf16)
    constexpr int HALF = K / 16;      // 8-col groups per half (8 or 16)
    constexpr int STR  = F32OUT ? (NOUT + 4) : (NOUT + 8);
    __shared__ float b1sl[1024];
    __shared__ float b2sl[128];
    __shared__ __align__(16) char smem[(size_t)64 * K * 2 + 64 * 256 * 2];
    bf16_t* Asl = (bf16_t*)smem;                        // frag-major A tile [64*K]
    bf16_t* Hsl = (bf16_t*)(smem + (size_t)64 * K * 2); // frag-major H chunk [64*256]

    const int tid  = threadIdx.x;
    const int lane = tid & 63;
    const int wn   = tid >> 6;        // 0..7
    const int l31  = lane & 31;
    const int hi   = lane >> 5;
    const int og   = wn >> 1;         // old stage-2 out-col group
    const int wr   = wn & 1;          // old stage-2 node-tile
    const int bm0  = blockIdx.x * 64;

    for (int i = tid; i < 1024; i += 512) b1sl[i] = (i < 1000) ? bias1[i] : 0.f;
    if (tid < OH) b2sl[tid] = bias2[tid];

    // ---- prologue: gather + own-copy directly into Asl (frag-major)
    #pragma unroll
    for (int it = 0; it < (2 * 64 * HALF) / 512; ++it) {
        int task = it * 512 + tid;
        const bool own = task >= 64 * HALF;
        int t2 = own ? task - 64 * HALF : task;
        int i = t2 / HALF, s = t2 - (t2 / HALF) * HALF;
        int n = bm0 + i;
        int j = s * 8;
        float sum[8] = {0.f, 0.f, 0.f, 0.f, 0.f, 0.f, 0.f, 0.f};
        if (n < NN) {
            if (!own) {
                int c = cnt[n]; if (c > BCAP) c = BCAP;
                const int* bp = bkt + n * BCAP;
                int e = 0;
                for (; e + 4 <= c; e += 4) {
                    int s0 = bp[e], s1 = bp[e + 1], s2 = bp[e + 2], s3 = bp[e + 3];
                    if (SRCF32) {
                        const float* r0 = (const float*)src + (size_t)s0 * SW + j;
                        const float* r1 = (const float*)src + (size_t)s1 * SW + j;
                        const float* r2 = (const float*)src + (size_t)s2 * SW + j;
                        const float* r3 = (const float*)src + (size_t)s3 * SW + j;
                        float4 a0 = *(const float4*)r0, b0 = *(const float4*)(r0 + 4);
                        float4 a1 = *(const float4*)r1, b1 = *(const float4*)(r1 + 4);
                        float4 a2 = *(const float4*)r2, b2 = *(const float4*)(r2 + 4);
                        float4 a3 = *(const float4*)r3, b3 = *(const float4*)(r3 + 4);
                        sum[0] += (a0.x + a1.x) + (a2.x + a3.x);
                        sum[1] += (a0.y + a1.y) + (a2.y + a3.y);
                        sum[2] += (a0.z + a1.z) + (a2.z + a3.z);
                        sum[3] += (a0.w + a1.w) + (a2.w + a3.w);
                        sum[4] += (b0.x + b1.x) + (b2.x + b3.x);
                        sum[5] += (b0.y + b1.y) + (b2.y + b3.y);
                        sum[6] += (b0.z + b1.z) + (b2.z + b3.z);
                        sum[7] += (b0.w + b1.w) + (b2.w + b3.w);
                    } else {
                        U4 w0, w1, w2, w3;
                        w0.v = *(const uint4*)((const bf16_t*)src + (size_t)s0 * SW + j);
                        w1.v = *(const uint4*)((const bf16_t*)src + (size_t)s1 * SW + j);
                        w2.v = *(const uint4*)((const bf16_t*)src + (size_t)s2 * SW + j);
                        w3.v = *(const uint4*)((const bf16_t*)src + (size_t)s3 * SW + j);
                        #pragma unroll
                        for (int k = 0; k < 8; ++k)
                            sum[k] += (us2f(w0.s[k]) + us2f(w1.s[k])) + (us2f(w2.s[k]) + us2f(w3.s[k]));
                    }
                }
                for (; e < c; ++e) {
                    int sn = bp[e];
                    if (SRCF32) {
                        const float* r = (const float*)src + (size_t)sn * SW + j;
                        float4 a = *(const float4*)r;
                        float4 b = *(const float4*)(r + 4);
                        sum[0] += a.x; sum[1] += a.y; sum[2] += a.z; sum[3] += a.w;
                        sum[4] += b.x; sum[5] += b.y; sum[6] += b.z; sum[7] += b.w;
                    } else {
                        U4 w; w.v = *(const uint4*)((const bf16_t*)src + (size_t)sn * SW + j);
                        #pragma unroll
                        for (int k = 0; k < 8; ++k) sum[k] += us2f(w.s[k]);
                    }
                }
            } else {
                if (SRCF32) {
                    const float* r = (const float*)src + (size_t)n * SW + j;
                    float4 a = *(const float4*)r;
                    float4 b = *(const float4*)(r + 4);
                    sum[0] = a.x; sum[1] = a.y; sum[2] = a.z; sum[3] = a.w;
                    sum[4] = b.x; sum[5] = b.y; sum[6] = b.z; sum[7] = b.w;
                } else {
                    U4 w; w.v = *(const uint4*)((const bf16_t*)src + (size_t)n * SW + j);
                    #pragma unroll
                    for (int k = 0; k < 8; ++k) sum[k] = us2f(w.s[k]);
                }
            }
        }
        int cc = (own ? K / 2 : 0) + j;           // column in A's K-space
        int off = (((i >> 5) * KT16 + (cc >> 4)) * 64 + ((cc >> 3) & 1) * 32 + (i & 31)) * 8;
        alignas(16) bf16_t ob[8];
        #pragma unroll
        for (int k = 0; k < 8; ++k) ob[k] = f2b(sum[k]);
        *(uint4*)(&Asl[off]) = *(const uint4*)ob;
    }

    floatx16 acc2[NACC];
    #pragma unroll
    for (int oo = 0; oo < NACC; ++oo) acc2[oo] = (floatx16)FZ16;

    __syncthreads();   // Asl + biases ready

    for (int ci = 0; ci < 4; ++ci) {
        // ---- stage 1: wave computes h-tile (ci*8 + wn) x both node-tiles
        //      4-deep batched w1 loads (16 VGPR), 8 MFMAs per batch.
        floatx16 acc1[2];
        acc1[0] = (floatx16)FZ16;
        acc1[1] = (floatx16)FZ16;

        const bf16_t* w1p = W1f + (((size_t)(ci * 8 + wn) * KT16) * 64 + lane) * 8;
        #pragma unroll
        for (int kh = 0; kh < KT16 / 4; ++kh) {
            short8 w1v[4];
            #pragma unroll
            for (int u = 0; u < 4; ++u)
                w1v[u] = *(const short8*)(w1p + (size_t)(kh * 4 + u) * 512);
            #pragma unroll
            for (int u = 0; u < 4; ++u) {
                int kk = kh * 4 + u;
                short8 av0 = *(const short8*)&Asl[((0 * KT16 + kk) * 64 + lane) * 8];
                acc1[0] = __builtin_amdgcn_mfma_f32_32x32x16_bf16(w1v[u], av0, acc1[0], 0, 0, 0);
                short8 av1 = *(const short8*)&Asl[((1 * KT16 + kk) * 64 + lane) * 8];
                acc1[1] = __builtin_amdgcn_mfma_f32_32x32x16_bf16(w1v[u], av1, acc1[1], 0, 0, 0);
            }
        }

        __syncthreads();   // previous chunk's stage-2 readers done with Hsl

        // bias+relu -> frag-major H; C/D: node=l31, hcol32=(r&3)+8*(r>>2)+4*hi
        #pragma unroll
        for (int nt2 = 0; nt2 < 2; ++nt2) {
            #pragma unroll
            for (int g = 0; g < 4; ++g) {
                float4 bv = *(const float4*)&b1sl[ci * 256 + wn * 32 + 8 * g + 4 * hi];
                const float* bvp = (const float*)&bv;
                alignas(8) bf16_t hb[4];
                #pragma unroll
                for (int e = 0; e < 4; ++e)
                    hb[e] = f2b(fmaxf(acc1[nt2][4 * g + e] + bvp[e], 0.f));
                int off = ((nt2 * 16 + wn * 2 + (g >> 1)) * 64 + (g & 1) * 32 + l31) * 8 + 4 * hi;
                *(uint2*)&Hsl[off] = *(const uint2*)hb;
            }
        }

        __syncthreads();   // H chunk visible

        // ---- stage 2 (4-deep batched w2 loads)
        if (NOUT == 256) {
            // dedup mapping: wave wn owns out-tile o=wn x BOTH node-tiles
            const bf16_t* w2p = W2f + (((size_t)wn * 64 + ci * 16) * 64 + lane) * 8;
            #pragma unroll
            for (int kg = 0; kg < 4; ++kg) {
                short8 w2v[4];
                #pragma unroll
                for (int u = 0; u < 4; ++u)
                    w2v[u] = *(const short8*)(w2p + (size_t)(kg * 4 + u) * 512);
                #pragma unroll
                for (int u = 0; u < 4; ++u) {
                    int ks = kg * 4 + u;
                    short8 hf0 = *(const short8*)&Hsl[((0 * 16 + ks) * 64 + lane) * 8];
                    acc2[0] = __builtin_amdgcn_mfma_f32_32x32x16_bf16(w2v[u], hf0, acc2[0], 0, 0, 0);
                    short8 hf1 = *(const short8*)&Hsl[((1 * 16 + ks) * 64 + lane) * 8];
                    acc2[1] = __builtin_amdgcn_mfma_f32_32x32x16_bf16(w2v[u], hf1, acc2[1], 0, 0, 0);
                }
            }
        } else {
            // old mapping: wave (og, wr): 1 out-tile x node-tile wr
            const bf16_t* w2p = W2f + ((((size_t)og) * 64 + ci * 16) * 64 + lane) * 8;
            #pragma unroll
            for (int kg = 0; kg < 4; ++kg) {
                short8 w2v[4];
                #pragma unroll
                for (int u = 0; u < 4; ++u)
                    w2v[u] = *(const short8*)(w2p + (size_t)(kg * 4 + u) * 512);
                #pragma unroll
                for (int u = 0; u < 4; ++u) {
                    int ks = kg * 4 + u;
                    short8 hf = *(const short8*)&Hsl[((wr * 16 + ks) * 64 + lane) * 8];
                    acc2[0] = __builtin_amdgcn_mfma_f32_32x32x16_bf16(w2v[u], hf, acc2[0], 0, 0, 0);
                }
            }
        }
    }

    // ---- epilogue: stage acc2(+bias) into LDS [node][outcol] (padded),
    //      then copy full rows out with coalesced line-aligned stores.
    __syncthreads();   // everyone done reading Hsl/Asl
    if (NOUT == 256) {
        // wave wn: out-tile o=wn, rows = both node-tiles (bf16 out: F32OUT=0)
        bf16_t* st = (bf16_t*)smem;
        #pragma unroll
        for (int nt2 = 0; nt2 < 2; ++nt2) {
            const int r = nt2 * 32 + l31;
            #pragma unroll
            for (int g = 0; g < 4; ++g) {
                int oc = wn * 32 + 8 * g + 4 * hi;
                const bool isInit = (oc >= OH);
                int col = isInit ? oc - OH : oc;
                float4 bv = isInit ? *(const float4*)&b2sl[col]
                                   : make_float4(0.f, 0.f, 0.f, 0.f);
                const float* bvp = (const float*)&bv;
                alignas(8) bf16_t ob[4];
                #pragma unroll
                for (int e = 0; e < 4; ++e) ob[e] = f2b(acc2[nt2][4 * g + e] + bvp[e]);
                *(uint2*)&st[r * STR + oc] = *(const uint2*)ob;
            }
        }
    } else {
        const int r = wr * 32 + l31;   // node row within block
        float* st = (float*)smem;      // f32 staging (F32OUT=1 for NOUT=128)
        #pragma unroll
        for (int oo = 0; oo < OCT2; ++oo) {
            int o = og * OCT2 + oo;
            #pragma unroll
            for (int g = 0; g < 4; ++g) {
                int oc = o * 32 + 8 * g + 4 * hi;
                const bool isInit = (oc >= OH);
                int col = isInit ? oc - OH : oc;
                float4 bv = isInit ? *(const float4*)&b2sl[col]
                                   : make_float4(0.f, 0.f, 0.f, 0.f);
                const float* bvp = (const float*)&bv;
                float v[4];
                #pragma unroll
                for (int e = 0; e < 4; ++e) v[e] = acc2[oo][4 * g + e] + bvp[e];
                *(float4*)&st[r * STR + oc] = make_float4(v[0], v[1], v[2], v[3]);
            }
        }
    }
    __syncthreads();
    if (NOUT == 256) {
        // bf16 out, both halves: 16B chunks per node = 32
        constexpr int CH = NOUT / 8;
        constexpr int CHH = CH / 2;
        const bf16_t* st = (const bf16_t*)smem;
        for (int t = tid; t < 64 * CH; t += 512) {
            int nd = t / CH, c = t - (t / CH) * CH;
            int node = bm0 + nd;
            if (node >= NN) continue;
            const bool isInit = (c >= CHH);
            int ch = isInit ? c - CHH : c;
            uint4 v = *(const uint4*)&st[nd * STR + c * 8];
            bf16_t* dst = isInit ? (bf16_t*)initout : (bf16_t*)yout;
            *(uint4*)(dst + (size_t)node * OH + ch * 8) = v;
        }
    } else {
        const float* st = (const float*)smem;
        // init half (cols OH..NOUT-1 of staging) -> f32 initout, 16B chunks
        for (int t = tid; t < 64 * (OH / 4); t += 512) {
            int nd = t / (OH / 4), c = t - (t / (OH / 4)) * (OH / 4);
            int node = bm0 + nd;
            if (node >= NN) continue;
            float4 v = *(const float4*)&st[nd * STR + OH + c * 4];
            *(float4*)((float*)initout + (size_t)node * OH + c * 4) = v;
        }
        // y half (cols 0..OH-1) -> yout (bf16 if YBF16 else f32)
        if (YBF16) {
            for (int t = tid; t < 64 * (OH / 8); t += 512) {
                int nd = t / (OH / 8), c = t - (t / (OH / 8)) * (OH / 8);
                int node = bm0 + nd;
                if (node >= NN) continue;
                float4 a = *(const float4*)&st[nd * STR + c * 8];
                float4 b = *(const float4*)&st[nd * STR + c * 8 + 4];
                alignas(16) bf16_t ob[8];
                ob[0] = f2b(a.x); ob[1] = f2b(a.y); ob[2] = f2b(a.z); ob[3] = f2b(a.w);
                ob[4] = f2b(b.x); ob[5] = f2b(b.y); ob[6] = f2b(b.z); ob[7] = f2b(b.w);
                *(uint4*)((bf16_t*)yout + (size_t)node * OH + c * 8) = *(const uint4*)ob;
            }
        } else {
            for (int t = tid; t < 64 * (OH / 4); t += 512) {
                int nd = t / (OH / 4), c = t - (t / (OH / 4)) * (OH / 4);
                int node = bm0 + nd;
                if (node >= NN) continue;
                float4 v = *(const float4*)&st[nd * STR + c * 4];
                *(float4*)((float*)yout + (size_t)node * OH + c * 4) = v;
            }
        }
    }
}

// ---------------------------------------------------------------------------
// Launch
// ---------------------------------------------------------------------------
extern "C" void kernel_launch(void* const* d_in, const int* in_sizes, int n_in,
                              void* d_out, int out_size, void* d_ws, size_t ws_size,
                              hipStream_t stream) {
    const float* x       = (const float*)d_in[0];
    const int*   ei      = (const int*)d_in[1];
    const int*   batch   = (const int*)d_in[2];
    const float* W1_rel  = (const float*)d_in[3];
    const float* b1      = (const float*)d_in[4];
    const float* W1_root = (const float*)d_in[5];
    const float* W2_rel  = (const float*)d_in[6];
    const float* b2      = (const float*)d_in[7];
    const float* W2_root = (const float*)d_in[8];
    const float* W3_rel  = (const float*)d_in[9];
    const float* b3      = (const float*)d_in[10];
    const float* W3_root = (const float*)d_in[11];
    const float* W4_rel  = (const float*)d_in[12];
    const float* b4      = (const float*)d_in[13];
    const float* W4_root = (const float*)d_in[14];

    float* outF = (float*)d_out;            // [N,64] then [G,128]
    float* enc  = outF + NN * 64;

    char* ws = (char*)d_ws;                         // ~66 MB
    bf16_t* y2buf  = (bf16_t*)(ws + 0);             // [N,128] bf16
    bf16_t* h2init = (bf16_t*)(ws + 12800000ULL);   // [N,128] bf16
    bf16_t* h2buf  = (bf16_t*)(ws + 25600000ULL);   // [N,128] bf16
    bf16_t* y4buf  = (bf16_t*)(ws + 38400000ULL);   // [N,64] bf16
    int*    cnt    = (int*)(ws + 51200000ULL);      // [N]
    int*    bkt    = (int*)(ws + 51400064ULL);      // [N*64]
    bf16_t* W1f    = (bf16_t*)(ws + 64200064ULL);   // 1024x128 frag-major
    bf16_t* W2f    = (bf16_t*)(ws + 64462208ULL);   // 256x1024 frag-major
    bf16_t* W3f    = (bf16_t*)(ws + 64986496ULL);   // 1024x256 frag-major
    bf16_t* W4f    = (bf16_t*)(ws + 65510784ULL);   // 128x1024 frag-major

    const int RB64 = (NN + 63) / 64;  // 782

    // ---- adjacency + all weight packs in one launch
    hipMemsetAsync(cnt, 0, NN * sizeof(int), stream);
    setup_all<<<NB_BUILD + NB_P1 + NB_P2 + NB_P3 + NB_P4, 256, 0, stream>>>(
        ei, cnt, bkt, W1_rel, W1_root, W2_rel, W2_root,
        W3_rel, W3_root, W4_rel, W4_root, W1f, W2f, W3f, W4f);

    // ---- L1+L2 fused: A=[gather(x)|x]; h1 on-chip;
    //      y2 = h1@W2_rel^T (bf16), h2init = h1@W2_root^T + b2 (bf16)
    fused14<128, 256, 0, 0, 1><<<RB64, 512, 0, stream>>>(x, cnt, bkt, W1f, b1, W2f, b2, y2buf, h2init);

    // ---- h2 = relu(h2init + gather(y2)); encoded = mean-pool(h2), fused
    gather_relu_pool<<<GG, 256, 0, stream>>>(y2buf, h2init, cnt, bkt, batch, h2buf, enc, NN);

    // ---- L3+L4 fused: A=[gather(h2)|h2]; h3 on-chip;
    //      y4 = h3@W4_rel^T (bf16), outF = h3@W4_root^T + b4 (f32, direct)
    fused14<256, 128, 1, 1, 0><<<RB64, 512, 0, stream>>>(h2buf, cnt, bkt, W3f, b3, W4f, b4, y4buf, outF);

    // ---- out = outF + gather(y4)   (y4 bf16 halves neighbor-read traffic)
    gather_add_b16_64<<<(NN * 16 + 255) / 256, 256, 0, stream>>>(y4buf, cnt, bkt, outF);
}

// Round 10
// 266.886 us; speedup vs baseline: 8.4153x; 1.0009x over previous
//
#include <hip/hip_runtime.h>
#include <hip/hip_bf16.h>

typedef __hip_bfloat16 bf16_t;
typedef __attribute__((ext_vector_type(8))) short short8;
typedef __attribute__((ext_vector_type(16))) float floatx16;

static __device__ __forceinline__ float b2f(bf16_t v) { return __bfloat162float(v); }
static __device__ __forceinline__ bf16_t f2b(float v) { return __float2bfloat16(v); }
static __device__ __forceinline__ float us2f(unsigned short u) {
    union { unsigned int i; float f; } c; c.i = ((unsigned int)u) << 16; return c.f;
}

// LDS-only barrier: __syncthreads() drains vmcnt(0)+lgkmcnt(0); every barrier
// in the fused kernel only guards LDS state, so draining in-flight GLOBAL
// (weight) loads is pure waste. s_waitcnt lgkmcnt(0) orders ds_write/ds_read;
// "memory" clobbers stop the compiler moving LDS ops across the pair.
static __device__ __forceinline__ void barrier_lds() {
    asm volatile("s_waitcnt lgkmcnt(0)" ::: "memory");
    __builtin_amdgcn_s_barrier();
    asm volatile("" ::: "memory");
}

// Problem constants
#define NN 50000
#define EE 200000
#define GG 2048
#define BCAP 64   // in-degree cap; mean deg = 4

union U4 { uint4 v; unsigned short s[8]; };
union U2 { uint2 v; unsigned short s[4]; };

#define FZ16 {0.f,0.f,0.f,0.f,0.f,0.f,0.f,0.f,0.f,0.f,0.f,0.f,0.f,0.f,0.f,0.f}

// 32x32x16 fragment-major layout (A and B operands share it):
//   element (i, k) of an [I x K] K-major matrix lives at
//   ((i/32 * (K/16) + k/16) * 64 + ((k%16)/8)*32 + i%32) * 8 + k%8
// One wave fragment = 64 lanes x short8 = contiguous 1KB.

// ---------------------------------------------------------------------------
// Merged setup: inverted adjacency build + all 4 weight packs in ONE launch
// ---------------------------------------------------------------------------
__device__ __forceinline__ void pack_w1_body(const float* __restrict__ Wa,
                                             const float* __restrict__ Wb,
                                             bf16_t* __restrict__ out,
                                             int K1, int K2, int idx) {
    int K = K1 + K2;
    int KT16 = K >> 4;
    int e = idx & 7;
    int l = (idx >> 3) & 63;
    int tile = idx >> 9;
    int kt = tile % KT16, t = tile / KT16;
    int c = t * 32 + (l & 31);
    int k = kt * 16 + (l >> 5) * 8 + e;
    float v = 0.f;
    if (c < 1000) v = (k < K1) ? Wa[c * K1 + k] : Wb[c * K2 + (k - K1)];
    out[idx] = f2b(v);
}
__device__ __forceinline__ void pack_w2_body(const float* __restrict__ Wa,
                                             const float* __restrict__ Wb,
                                             bf16_t* __restrict__ out,
                                             int OH, int idx) {
    int e = idx & 7;
    int l = (idx >> 3) & 63;
    int tile = idx >> 9;
    int kt2 = tile & 63, o = tile >> 6;   // K=1024 -> 64 k-tiles
    int c = o * 32 + (l & 31);
    int k = kt2 * 16 + (l >> 5) * 8 + e;
    float v = 0.f;
    if (k < 1000) v = (c < OH) ? Wa[c * 1000 + k] : Wb[(c - OH) * 1000 + k];
    out[idx] = f2b(v);
}

#define NB_BUILD 782   // (EE+255)/256
#define NB_P1 512      // 131072/256
#define NB_P2 1024     // 262144/256
#define NB_P3 1024
#define NB_P4 512

__global__ void setup_all(const int* __restrict__ ei, int* __restrict__ cnt,
                          int* __restrict__ bkt,
                          const float* __restrict__ W1_rel, const float* __restrict__ W1_root,
                          const float* __restrict__ W2_rel, const float* __restrict__ W2_root,
                          const float* __restrict__ W3_rel, const float* __restrict__ W3_root,
                          const float* __restrict__ W4_rel, const float* __restrict__ W4_root,
                          bf16_t* __restrict__ W1f, bf16_t* __restrict__ W2f,
                          bf16_t* __restrict__ W3f, bf16_t* __restrict__ W4f) {
    int b = blockIdx.x;
    int tid = threadIdx.x;
    if (b < NB_BUILD) {
        int e = b * 256 + tid;
        if (e < EE) {
            int s = ei[e];
            int d = ei[EE + e];
            int pos = atomicAdd(&cnt[d], 1);
            if (pos < BCAP) bkt[d * BCAP + pos] = s;
        }
    } else if (b < NB_BUILD + NB_P1) {
        pack_w1_body(W1_rel, W1_root, W1f, 64, 64, (b - NB_BUILD) * 256 + tid);
    } else if (b < NB_BUILD + NB_P1 + NB_P2) {
        pack_w2_body(W2_rel, W2_root, W2f, 128, (b - NB_BUILD - NB_P1) * 256 + tid);
    } else if (b < NB_BUILD + NB_P1 + NB_P2 + NB_P3) {
        pack_w1_body(W3_rel, W3_root, W3f, 128, 128, (b - NB_BUILD - NB_P1 - NB_P2) * 256 + tid);
    } else {
        pack_w2_body(W4_rel, W4_root, W4f, 64, (b - NB_BUILD - NB_P1 - NB_P2 - NB_P3) * 256 + tid);
    }
}

// ---------------------------------------------------------------------------
// Per-graph fused gather+relu+mean-pool (one block = one graph; batch sorted).
// h2[n] = relu(init[n] + sum nbr y2); enc[g] = mean over graph's h2 rows.
// Pool partials reduced in LDS (round-6 lesson: NO cross-XCD f32 atomics).
// 256 threads = 16 node-slots x 16 col-groups of 8.
// ---------------------------------------------------------------------------
__global__ void gather_relu_pool(const bf16_t* __restrict__ y2, const bf16_t* __restrict__ init,
                                 const int* __restrict__ cnt, const int* __restrict__ bkt,
                                 const int* __restrict__ batch,
                                 bf16_t* __restrict__ h2, float* __restrict__ enc, int Nn) {
    int g = blockIdx.x;
    __shared__ int s_lo, s_hi;
    __shared__ float red[16][128];   // 8KB partials
    if (threadIdx.x == 0) {
        int lo = 0, hi = Nn;
        while (lo < hi) { int mid = (lo + hi) >> 1; if (batch[mid] < g) lo = mid + 1; else hi = mid; }
        s_lo = lo;
        hi = Nn;
        while (lo < hi) { int mid = (lo + hi) >> 1; if (batch[mid] < g + 1) lo = mid + 1; else hi = mid; }
        s_hi = lo;
    }
    __syncthreads();
    const int lo = s_lo, hi = s_hi;
    const int slot = threadIdx.x >> 4;      // 0..15 node slot
    const int j = (threadIdx.x & 15) * 8;   // col group
    float psum[8] = {0.f,0.f,0.f,0.f,0.f,0.f,0.f,0.f};
    for (int n = lo + slot; n < hi; n += 16) {
        int c = cnt[n]; if (c > BCAP) c = BCAP;
        const int* bp = bkt + n * BCAP;
        U4 u; u.v = *(const uint4*)(init + (size_t)n * 128 + j);
        float s[8];
        #pragma unroll
        for (int k = 0; k < 8; ++k) s[k] = us2f(u.s[k]);
        int i = 0;
        for (; i + 4 <= c; i += 4) {
            int s0 = bp[i], s1 = bp[i + 1], s2 = bp[i + 2], s3 = bp[i + 3];
            U4 w0, w1, w2, w3;
            w0.v = *(const uint4*)(y2 + (size_t)s0 * 128 + j);
            w1.v = *(const uint4*)(y2 + (size_t)s1 * 128 + j);
            w2.v = *(const uint4*)(y2 + (size_t)s2 * 128 + j);
            w3.v = *(const uint4*)(y2 + (size_t)s3 * 128 + j);
            #pragma unroll
            for (int k = 0; k < 8; ++k)
                s[k] += (us2f(w0.s[k]) + us2f(w1.s[k])) + (us2f(w2.s[k]) + us2f(w3.s[k]));
        }
        for (; i < c; ++i) {
            U4 w; w.v = *(const uint4*)(y2 + (size_t)bp[i] * 128 + j);
            #pragma unroll
            for (int k = 0; k < 8; ++k) s[k] += us2f(w.s[k]);
        }
        alignas(16) bf16_t ob[8];
        #pragma unroll
        for (int k = 0; k < 8; ++k) {
            s[k] = fmaxf(s[k], 0.f);
            psum[k] += s[k];
            ob[k] = f2b(s[k]);
        }
        *(uint4*)(h2 + (size_t)n * 128 + j) = *(const uint4*)ob;
    }
    #pragma unroll
    for (int k = 0; k < 8; ++k) red[slot][j + k] = psum[k];
    __syncthreads();
    if (threadIdx.x < 128) {
        int c = threadIdx.x;
        float tot = 0.f;
        #pragma unroll
        for (int r = 0; r < 16; ++r) tot += red[r][c];
        float n = (float)((hi - lo) > 0 ? (hi - lo) : 1);
        enc[(size_t)g * 128 + c] = tot / n;
    }
}

// outF[n] += sum nbr y4   (y4 bf16 [N,64]; outF f32 in-place on d_out)
__global__ void gather_add_b16_64(const bf16_t* __restrict__ y4, const int* __restrict__ cnt,
                                  const int* __restrict__ bkt, float* __restrict__ outF) {
    int t = blockIdx.x * 256 + threadIdx.x;
    int n = t >> 4;
    if (n >= NN) return;
    int j = (t & 15) * 4;
    int c = cnt[n]; if (c > BCAP) c = BCAP;
    const int* bp = bkt + n * BCAP;
    float4 sum = *(const float4*)(outF + n * 64 + j);
    int i = 0;
    for (; i + 4 <= c; i += 4) {
        int s0 = bp[i], s1 = bp[i + 1], s2 = bp[i + 2], s3 = bp[i + 3];
        U2 w0, w1, w2, w3;
        w0.v = *(const uint2*)(y4 + (size_t)s0 * 64 + j);
        w1.v = *(const uint2*)(y4 + (size_t)s1 * 64 + j);
        w2.v = *(const uint2*)(y4 + (size_t)s2 * 64 + j);
        w3.v = *(const uint2*)(y4 + (size_t)s3 * 64 + j);
        sum.x += (us2f(w0.s[0]) + us2f(w1.s[0])) + (us2f(w2.s[0]) + us2f(w3.s[0]));
        sum.y += (us2f(w0.s[1]) + us2f(w1.s[1])) + (us2f(w2.s[1]) + us2f(w3.s[1]));
        sum.z += (us2f(w0.s[2]) + us2f(w1.s[2])) + (us2f(w2.s[2]) + us2f(w3.s[2]));
        sum.w += (us2f(w0.s[3]) + us2f(w1.s[3])) + (us2f(w2.s[3]) + us2f(w3.s[3]));
    }
    for (; i < c; ++i) {
        U2 w; w.v = *(const uint2*)(y4 + (size_t)bp[i] * 64 + j);
        sum.x += us2f(w.s[0]); sum.y += us2f(w.s[1]);
        sum.z += us2f(w.s[2]); sum.w += us2f(w.s[3]);
    }
    *(float4*)(outF + n * 64 + j) = sum;
}

// ---------------------------------------------------------------------------
// Fused gather + two-GEMM v15 = v14 + LDS-ONLY BARRIERS: __syncthreads()
// drains vmcnt(0) (all in-flight global weight loads) at every barrier; the
// 9 barriers/block only guard LDS, so v15 uses lgkmcnt(0)+raw s_barrier,
// letting weight loads stay in flight across chunk boundaries (T4 idea).
//   Block = 64 nodes (2 node-tiles of 32), 512 threads = 8 waves.
//   Stage 1: wave wn owns hcol-tile (ci*8+wn) x BOTH node tiles; 4-deep
//            batched w1 loads.
//   H chunk [64 x 256] bf16, single-buffered (32KB), frag-major.
//   Stage 2 NOUT=256: wave wn owns out-tile wn x BOTH node-tiles (W2 dedup).
//   Stage 2 NOUT=128: wave (og, wr): 1 out-tile x node-tile wr.
// Outputs: outcol < NOUT/2 -> yout (bf16 if YBF16), else initout (+bias2).
// ---------------------------------------------------------------------------
template <int K, int NOUT, int F32OUT, int YBF16, int SRCF32>
__global__ __launch_bounds__(512, 4) void fused15(
    const void* __restrict__ src, const int* __restrict__ cnt,
    const int* __restrict__ bkt,
    const bf16_t* __restrict__ W1f, const float* __restrict__ bias1,
    const bf16_t* __restrict__ W2f, const float* __restrict__ bias2,
    void* __restrict__ yout, void* __restrict__ initout)
{
    constexpr int KT16 = K / 16;      // A k-tiles (16-deep), 8 or 16
    constexpr int OT32 = NOUT / 32;   // out 32-col tiles (8 or 4)
    constexpr int OCT2 = OT32 / 4;    // out tiles per wave, old mapping (2 or 1)
    constexpr int NACC = (NOUT == 256) ? 2 : OCT2;
    constexpr int OH   = NOUT / 2;
    constexpr int SW   = K / 2;       // source row width (64 f32 / 128 bf16)
    constexpr int HALF = K / 16;      // 8-col groups per half (8 or 16)
    constexpr int STR  = F32OUT ? (NOUT + 4) : (NOUT + 8);
    __shared__ float b1sl[1024];
    __shared__ float b2sl[128];
    __shared__ __align__(16) char smem[(size_t)64 * K * 2 + 64 * 256 * 2];
    bf16_t* Asl = (bf16_t*)smem;                        // frag-major A tile [64*K]
    bf16_t* Hsl = (bf16_t*)(smem + (size_t)64 * K * 2); // frag-major H chunk [64*256]

    const int tid  = threadIdx.x;
    const int lane = tid & 63;
    const int wn   = tid >> 6;        // 0..7
    const int l31  = lane & 31;
    const int hi   = lane >> 5;
    const int og   = wn >> 1;         // old stage-2 out-col group
    const int wr   = wn & 1;          // old stage-2 node-tile
    const int bm0  = blockIdx.x * 64;

    for (int i = tid; i < 1024; i += 512) b1sl[i] = (i < 1000) ? bias1[i] : 0.f;
    if (tid < OH) b2sl[tid] = bias2[tid];

    // ---- prologue: gather + own-copy directly into Asl (frag-major)
    #pragma unroll
    for (int it = 0; it < (2 * 64 * HALF) / 512; ++it) {
        int task = it * 512 + tid;
        const bool own = task >= 64 * HALF;
        int t2 = own ? task - 64 * HALF : task;
        int i = t2 / HALF, s = t2 - (t2 / HALF) * HALF;
        int n = bm0 + i;
        int j = s * 8;
        float sum[8] = {0.f, 0.f, 0.f, 0.f, 0.f, 0.f, 0.f, 0.f};
        if (n < NN) {
            if (!own) {
                int c = cnt[n]; if (c > BCAP) c = BCAP;
                const int* bp = bkt + n * BCAP;
                int e = 0;
                for (; e + 4 <= c; e += 4) {
                    int s0 = bp[e], s1 = bp[e + 1], s2 = bp[e + 2], s3 = bp[e + 3];
                    if (SRCF32) {
                        const float* r0 = (const float*)src + (size_t)s0 * SW + j;
                        const float* r1 = (const float*)src + (size_t)s1 * SW + j;
                        const float* r2 = (const float*)src + (size_t)s2 * SW + j;
                        const float* r3 = (const float*)src + (size_t)s3 * SW + j;
                        float4 a0 = *(const float4*)r0, b0 = *(const float4*)(r0 + 4);
                        float4 a1 = *(const float4*)r1, b1 = *(const float4*)(r1 + 4);
                        float4 a2 = *(const float4*)r2, b2 = *(const float4*)(r2 + 4);
                        float4 a3 = *(const float4*)r3, b3 = *(const float4*)(r3 + 4);
                        sum[0] += (a0.x + a1.x) + (a2.x + a3.x);
                        sum[1] += (a0.y + a1.y) + (a2.y + a3.y);
                        sum[2] += (a0.z + a1.z) + (a2.z + a3.z);
                        sum[3] += (a0.w + a1.w) + (a2.w + a3.w);
                        sum[4] += (b0.x + b1.x) + (b2.x + b3.x);
                        sum[5] += (b0.y + b1.y) + (b2.y + b3.y);
                        sum[6] += (b0.z + b1.z) + (b2.z + b3.z);
                        sum[7] += (b0.w + b1.w) + (b2.w + b3.w);
                    } else {
                        U4 w0, w1, w2, w3;
                        w0.v = *(const uint4*)((const bf16_t*)src + (size_t)s0 * SW + j);
                        w1.v = *(const uint4*)((const bf16_t*)src + (size_t)s1 * SW + j);
                        w2.v = *(const uint4*)((const bf16_t*)src + (size_t)s2 * SW + j);
                        w3.v = *(const uint4*)((const bf16_t*)src + (size_t)s3 * SW + j);
                        #pragma unroll
                        for (int k = 0; k < 8; ++k)
                            sum[k] += (us2f(w0.s[k]) + us2f(w1.s[k])) + (us2f(w2.s[k]) + us2f(w3.s[k]));
                    }
                }
                for (; e < c; ++e) {
                    int sn = bp[e];
                    if (SRCF32) {
                        const float* r = (const float*)src + (size_t)sn * SW + j;
                        float4 a = *(const float4*)r;
                        float4 b = *(const float4*)(r + 4);
                        sum[0] += a.x; sum[1] += a.y; sum[2] += a.z; sum[3] += a.w;
                        sum[4] += b.x; sum[5] += b.y; sum[6] += b.z; sum[7] += b.w;
                    } else {
                        U4 w; w.v = *(const uint4*)((const bf16_t*)src + (size_t)sn * SW + j);
                        #pragma unroll
                        for (int k = 0; k < 8; ++k) sum[k] += us2f(w.s[k]);
                    }
                }
            } else {
                if (SRCF32) {
                    const float* r = (const float*)src + (size_t)n * SW + j;
                    float4 a = *(const float4*)r;
                    float4 b = *(const float4*)(r + 4);
                    sum[0] = a.x; sum[1] = a.y; sum[2] = a.z; sum[3] = a.w;
                    sum[4] = b.x; sum[5] = b.y; sum[6] = b.z; sum[7] = b.w;
                } else {
                    U4 w; w.v = *(const uint4*)((const bf16_t*)src + (size_t)n * SW + j);
                    #pragma unroll
                    for (int k = 0; k < 8; ++k) sum[k] = us2f(w.s[k]);
                }
            }
        }
        int cc = (own ? K / 2 : 0) + j;           // column in A's K-space
        int off = (((i >> 5) * KT16 + (cc >> 4)) * 64 + ((cc >> 3) & 1) * 32 + (i & 31)) * 8;
        alignas(16) bf16_t ob[8];
        #pragma unroll
        for (int k = 0; k < 8; ++k) ob[k] = f2b(sum[k]);
        *(uint4*)(&Asl[off]) = *(const uint4*)ob;
    }

    floatx16 acc2[NACC];
    #pragma unroll
    for (int oo = 0; oo < NACC; ++oo) acc2[oo] = (floatx16)FZ16;

    barrier_lds();   // Asl + biases ready (LDS-only dependency)

    for (int ci = 0; ci < 4; ++ci) {
        // ---- stage 1: wave computes h-tile (ci*8 + wn) x both node-tiles
        //      4-deep batched w1 loads (16 VGPR), 8 MFMAs per batch.
        floatx16 acc1[2];
        acc1[0] = (floatx16)FZ16;
        acc1[1] = (floatx16)FZ16;

        const bf16_t* w1p = W1f + (((size_t)(ci * 8 + wn) * KT16) * 64 + lane) * 8;
        #pragma unroll
        for (int kh = 0; kh < KT16 / 4; ++kh) {
            short8 w1v[4];
            #pragma unroll
            for (int u = 0; u < 4; ++u)
                w1v[u] = *(const short8*)(w1p + (size_t)(kh * 4 + u) * 512);
            #pragma unroll
            for (int u = 0; u < 4; ++u) {
                int kk = kh * 4 + u;
                short8 av0 = *(const short8*)&Asl[((0 * KT16 + kk) * 64 + lane) * 8];
                acc1[0] = __builtin_amdgcn_mfma_f32_32x32x16_bf16(w1v[u], av0, acc1[0], 0, 0, 0);
                short8 av1 = *(const short8*)&Asl[((1 * KT16 + kk) * 64 + lane) * 8];
                acc1[1] = __builtin_amdgcn_mfma_f32_32x32x16_bf16(w1v[u], av1, acc1[1], 0, 0, 0);
            }
        }

        barrier_lds();   // previous chunk's stage-2 readers done with Hsl

        // bias+relu -> frag-major H; C/D: node=l31, hcol32=(r&3)+8*(r>>2)+4*hi
        #pragma unroll
        for (int nt2 = 0; nt2 < 2; ++nt2) {
            #pragma unroll
            for (int g = 0; g < 4; ++g) {
                float4 bv = *(const float4*)&b1sl[ci * 256 + wn * 32 + 8 * g + 4 * hi];
                const float* bvp = (const float*)&bv;
                alignas(8) bf16_t hb[4];
                #pragma unroll
                for (int e = 0; e < 4; ++e)
                    hb[e] = f2b(fmaxf(acc1[nt2][4 * g + e] + bvp[e], 0.f));
                int off = ((nt2 * 16 + wn * 2 + (g >> 1)) * 64 + (g & 1) * 32 + l31) * 8 + 4 * hi;
                *(uint2*)&Hsl[off] = *(const uint2*)hb;
            }
        }

        barrier_lds();   // H chunk visible

        // ---- stage 2 (4-deep batched w2 loads)
        if (NOUT == 256) {
            // dedup mapping: wave wn owns out-tile o=wn x BOTH node-tiles
            const bf16_t* w2p = W2f + (((size_t)wn * 64 + ci * 16) * 64 + lane) * 8;
            #pragma unroll
            for (int kg = 0; kg < 4; ++kg) {
                short8 w2v[4];
                #pragma unroll
                for (int u = 0; u < 4; ++u)
                    w2v[u] = *(const short8*)(w2p + (size_t)(kg * 4 + u) * 512);
                #pragma unroll
                for (int u = 0; u < 4; ++u) {
                    int ks = kg * 4 + u;
                    short8 hf0 = *(const short8*)&Hsl[((0 * 16 + ks) * 64 + lane) * 8];
                    acc2[0] = __builtin_amdgcn_mfma_f32_32x32x16_bf16(w2v[u], hf0, acc2[0], 0, 0, 0);
                    short8 hf1 = *(const short8*)&Hsl[((1 * 16 + ks) * 64 + lane) * 8];
                    acc2[1] = __builtin_amdgcn_mfma_f32_32x32x16_bf16(w2v[u], hf1, acc2[1], 0, 0, 0);
                }
            }
        } else {
            // old mapping: wave (og, wr): 1 out-tile x node-tile wr
            const bf16_t* w2p = W2f + ((((size_t)og) * 64 + ci * 16) * 64 + lane) * 8;
            #pragma unroll
            for (int kg = 0; kg < 4; ++kg) {
                short8 w2v[4];
                #pragma unroll
                for (int u = 0; u < 4; ++u)
                    w2v[u] = *(const short8*)(w2p + (size_t)(kg * 4 + u) * 512);
                #pragma unroll
                for (int u = 0; u < 4; ++u) {
                    int ks = kg * 4 + u;
                    short8 hf = *(const short8*)&Hsl[((wr * 16 + ks) * 64 + lane) * 8];
                    acc2[0] = __builtin_amdgcn_mfma_f32_32x32x16_bf16(w2v[u], hf, acc2[0], 0, 0, 0);
                }
            }
        }
    }

    // ---- epilogue: stage acc2(+bias) into LDS [node][outcol] (padded),
    //      then copy full rows out with coalesced line-aligned stores.
    barrier_lds();   // everyone done reading Hsl/Asl (LDS-only dependency)
    if (NOUT == 256) {
        // wave wn: out-tile o=wn, rows = both node-tiles (bf16 out: F32OUT=0)
        bf16_t* st = (bf16_t*)smem;
        #pragma unroll
        for (int nt2 = 0; nt2 < 2; ++nt2) {
            const int r = nt2 * 32 + l31;
            #pragma unroll
            for (int g = 0; g < 4; ++g) {
                int oc = wn * 32 + 8 * g + 4 * hi;
                const bool isInit = (oc >= OH);
                int col = isInit ? oc - OH : oc;
                float4 bv = isInit ? *(const float4*)&b2sl[col]
                                   : make_float4(0.f, 0.f, 0.f, 0.f);
                const float* bvp = (const float*)&bv;
                alignas(8) bf16_t ob[4];
                #pragma unroll
                for (int e = 0; e < 4; ++e) ob[e] = f2b(acc2[nt2][4 * g + e] + bvp[e]);
                *(uint2*)&st[r * STR + oc] = *(const uint2*)ob;
            }
        }
    } else {
        const int r = wr * 32 + l31;   // node row within block
        float* st = (float*)smem;      // f32 staging (F32OUT=1 for NOUT=128)
        #pragma unroll
        for (int oo = 0; oo < OCT2; ++oo) {
            int o = og * OCT2 + oo;
            #pragma unroll
            for (int g = 0; g < 4; ++g) {
                int oc = o * 32 + 8 * g + 4 * hi;
                const bool isInit = (oc >= OH);
                int col = isInit ? oc - OH : oc;
                float4 bv = isInit ? *(const float4*)&b2sl[col]
                                   : make_float4(0.f, 0.f, 0.f, 0.f);
                const float* bvp = (const float*)&bv;
                float v[4];
                #pragma unroll
                for (int e = 0; e < 4; ++e) v[e] = acc2[oo][4 * g + e] + bvp[e];
                *(float4*)&st[r * STR + oc] = make_float4(v[0], v[1], v[2], v[3]);
            }
        }
    }
    barrier_lds();   // staging written
    if (NOUT == 256) {
        // bf16 out, both halves: 16B chunks per node = 32
        constexpr int CH = NOUT / 8;
        constexpr int CHH = CH / 2;
        const bf16_t* st = (const bf16_t*)smem;
        for (int t = tid; t < 64 * CH; t += 512) {
            int nd = t / CH, c = t - (t / CH) * CH;
            int node = bm0 + nd;
            if (node >= NN) continue;
            const bool isInit = (c >= CHH);
            int ch = isInit ? c - CHH : c;
            uint4 v = *(const uint4*)&st[nd * STR + c * 8];
            bf16_t* dst = isInit ? (bf16_t*)initout : (bf16_t*)yout;
            *(uint4*)(dst + (size_t)node * OH + ch * 8) = v;
        }
    } else {
        const float* st = (const float*)smem;
        // init half (cols OH..NOUT-1 of staging) -> f32 initout, 16B chunks
        for (int t = tid; t < 64 * (OH / 4); t += 512) {
            int nd = t / (OH / 4), c = t - (t / (OH / 4)) * (OH / 4);
            int node = bm0 + nd;
            if (node >= NN) continue;
            float4 v = *(const float4*)&st[nd * STR + OH + c * 4];
            *(float4*)((float*)initout + (size_t)node * OH + c * 4) = v;
        }
        // y half (cols 0..OH-1) -> yout (bf16 if YBF16 else f32)
        if (YBF16) {
            for (int t = tid; t < 64 * (OH / 8); t += 512) {
                int nd = t / (OH / 8), c = t - (t / (OH / 8)) * (OH / 8);
                int node = bm0 + nd;
                if (node >= NN) continue;
                float4 a = *(const float4*)&st[nd * STR + c * 8];
                float4 b = *(const float4*)&st[nd * STR + c * 8 + 4];
                alignas(16) bf16_t ob[8];
                ob[0] = f2b(a.x); ob[1] = f2b(a.y); ob[2] = f2b(a.z); ob[3] = f2b(a.w);
                ob[4] = f2b(b.x); ob[5] = f2b(b.y); ob[6] = f2b(b.z); ob[7] = f2b(b.w);
                *(uint4*)((bf16_t*)yout + (size_t)node * OH + c * 8) = *(const uint4*)ob;
            }
        } else {
            for (int t = tid; t < 64 * (OH / 4); t += 512) {
                int nd = t / (OH / 4), c = t - (t / (OH / 4)) * (OH / 4);
                int node = bm0 + nd;
                if (node >= NN) continue;
                float4 v = *(const float4*)&st[nd * STR + c * 4];
                *(float4*)((float*)yout + (size_t)node * OH + c * 4) = v;
            }
        }
    }
}

// ---------------------------------------------------------------------------
// Launch
// ---------------------------------------------------------------------------
extern "C" void kernel_launch(void* const* d_in, const int* in_sizes, int n_in,
                              void* d_out, int out_size, void* d_ws, size_t ws_size,
                              hipStream_t stream) {
    const float* x       = (const float*)d_in[0];
    const int*   ei      = (const int*)d_in[1];
    const int*   batch   = (const int*)d_in[2];
    const float* W1_rel  = (const float*)d_in[3];
    const float* b1      = (const float*)d_in[4];
    const float* W1_root = (const float*)d_in[5];
    const float* W2_rel  = (const float*)d_in[6];
    const float* b2      = (const float*)d_in[7];
    const float* W2_root = (const float*)d_in[8];
    const float* W3_rel  = (const float*)d_in[9];
    const float* b3      = (const float*)d_in[10];
    const float* W3_root = (const float*)d_in[11];
    const float* W4_rel  = (const float*)d_in[12];
    const float* b4      = (const float*)d_in[13];
    const float* W4_root = (const float*)d_in[14];

    float* outF = (float*)d_out;            // [N,64] then [G,128]
    float* enc  = outF + NN * 64;

    char* ws = (char*)d_ws;                         // ~66 MB
    bf16_t* y2buf  = (bf16_t*)(ws + 0);             // [N,128] bf16
    bf16_t* h2init = (bf16_t*)(ws + 12800000ULL);   // [N,128] bf16
    bf16_t* h2buf  = (bf16_t*)(ws + 25600000ULL);   // [N,128] bf16
    bf16_t* y4buf  = (bf16_t*)(ws + 38400000ULL);   // [N,64] bf16
    int*    cnt    = (int*)(ws + 51200000ULL);      // [N]
    int*    bkt    = (int*)(ws + 51400064ULL);      // [N*64]
    bf16_t* W1f    = (bf16_t*)(ws + 64200064ULL);   // 1024x128 frag-major
    bf16_t* W2f    = (bf16_t*)(ws + 64462208ULL);   // 256x1024 frag-major
    bf16_t* W3f    = (bf16_t*)(ws + 64986496ULL);   // 1024x256 frag-major
    bf16_t* W4f    = (bf16_t*)(ws + 65510784ULL);   // 128x1024 frag-major

    const int RB64 = (NN + 63) / 64;  // 782

    // ---- adjacency + all weight packs in one launch
    hipMemsetAsync(cnt, 0, NN * sizeof(int), stream);
    setup_all<<<NB_BUILD + NB_P1 + NB_P2 + NB_P3 + NB_P4, 256, 0, stream>>>(
        ei, cnt, bkt, W1_rel, W1_root, W2_rel, W2_root,
        W3_rel, W3_root, W4_rel, W4_root, W1f, W2f, W3f, W4f);

    // ---- L1+L2 fused: A=[gather(x)|x]; h1 on-chip;
    //      y2 = h1@W2_rel^T (bf16), h2init = h1@W2_root^T + b2 (bf16)
    fused15<128, 256, 0, 0, 1><<<RB64, 512, 0, stream>>>(x, cnt, bkt, W1f, b1, W2f, b2, y2buf, h2init);

    // ---- h2 = relu(h2init + gather(y2)); encoded = mean-pool(h2), fused
    gather_relu_pool<<<GG, 256, 0, stream>>>(y2buf, h2init, cnt, bkt, batch, h2buf, enc, NN);

    // ---- L3+L4 fused: A=[gather(h2)|h2]; h3 on-chip;
    //      y4 = h3@W4_rel^T (bf16), outF = h3@W4_root^T + b4 (f32, direct)
    fused15<256, 128, 1, 1, 0><<<RB64, 512, 0, stream>>>(h2buf, cnt, bkt, W3f, b3, W4f, b4, y4buf, outF);

    // ---- out = outF + gather(y4)   (y4 bf16 halves neighbor-read traffic)
    gather_add_b16_64<<<(NN * 16 + 255) / 256, 256, 0, stream>>>(y4buf, cnt, bkt, outF);
}

// Round 11
// 260.567 us; speedup vs baseline: 8.6194x; 1.0243x over previous
//
#include <hip/hip_runtime.h>
#include <hip/hip_bf16.h>

typedef __hip_bfloat16 bf16_t;
typedef __attribute__((ext_vector_type(8))) short short8;
typedef __attribute__((ext_vector_type(16))) float floatx16;

static __device__ __forceinline__ float b2f(bf16_t v) { return __bfloat162float(v); }
static __device__ __forceinline__ bf16_t f2b(float v) { return __float2bfloat16(v); }
static __device__ __forceinline__ float us2f(unsigned short u) {
    union { unsigned int i; float f; } c; c.i = ((unsigned int)u) << 16; return c.f;
}

// LDS-only barrier (r9: neutral vs __syncthreads, kept — theoretically right).
static __device__ __forceinline__ void barrier_lds() {
    asm volatile("s_waitcnt lgkmcnt(0)" ::: "memory");
    __builtin_amdgcn_s_barrier();
    asm volatile("" ::: "memory");
}

// Problem constants
#define NN 50000
#define EE 200000
#define GG 2048
#define BCAP 64   // in-degree cap; mean deg = 4

union U4 { uint4 v; unsigned short s[8]; };
union U2 { uint2 v; unsigned short s[4]; };

#define FZ16 {0.f,0.f,0.f,0.f,0.f,0.f,0.f,0.f,0.f,0.f,0.f,0.f,0.f,0.f,0.f,0.f}

// 32x32x16 fragment-major layout (A and B operands share it):
//   element (i, k) of an [I x K] K-major matrix lives at
//   ((i/32 * (K/16) + k/16) * 64 + ((k%16)/8)*32 + i%32) * 8 + k%8
// One wave fragment = 64 lanes x short8 = contiguous 1KB.

// ---------------------------------------------------------------------------
// Merged setup: inverted adjacency build + all 4 weight packs in ONE launch
// ---------------------------------------------------------------------------
__device__ __forceinline__ void pack_w1_body(const float* __restrict__ Wa,
                                             const float* __restrict__ Wb,
                                             bf16_t* __restrict__ out,
                                             int K1, int K2, int idx) {
    int K = K1 + K2;
    int KT16 = K >> 4;
    int e = idx & 7;
    int l = (idx >> 3) & 63;
    int tile = idx >> 9;
    int kt = tile % KT16, t = tile / KT16;
    int c = t * 32 + (l & 31);
    int k = kt * 16 + (l >> 5) * 8 + e;
    float v = 0.f;
    if (c < 1000) v = (k < K1) ? Wa[c * K1 + k] : Wb[c * K2 + (k - K1)];
    out[idx] = f2b(v);
}
__device__ __forceinline__ void pack_w2_body(const float* __restrict__ Wa,
                                             const float* __restrict__ Wb,
                                             bf16_t* __restrict__ out,
                                             int OH, int idx) {
    int e = idx & 7;
    int l = (idx >> 3) & 63;
    int tile = idx >> 9;
    int kt2 = tile & 63, o = tile >> 6;   // K=1024 -> 64 k-tiles
    int c = o * 32 + (l & 31);
    int k = kt2 * 16 + (l >> 5) * 8 + e;
    float v = 0.f;
    if (k < 1000) v = (c < OH) ? Wa[c * 1000 + k] : Wb[(c - OH) * 1000 + k];
    out[idx] = f2b(v);
}

#define NB_BUILD 782   // (EE+255)/256
#define NB_P1 512      // 131072/256
#define NB_P2 1024     // 262144/256
#define NB_P3 1024
#define NB_P4 512

__global__ void setup_all(const int* __restrict__ ei, int* __restrict__ cnt,
                          int* __restrict__ bkt,
                          const float* __restrict__ W1_rel, const float* __restrict__ W1_root,
                          const float* __restrict__ W2_rel, const float* __restrict__ W2_root,
                          const float* __restrict__ W3_rel, const float* __restrict__ W3_root,
                          const float* __restrict__ W4_rel, const float* __restrict__ W4_root,
                          bf16_t* __restrict__ W1f, bf16_t* __restrict__ W2f,
                          bf16_t* __restrict__ W3f, bf16_t* __restrict__ W4f) {
    int b = blockIdx.x;
    int tid = threadIdx.x;
    if (b < NB_BUILD) {
        int e = b * 256 + tid;
        if (e < EE) {
            int s = ei[e];
            int d = ei[EE + e];
            int pos = atomicAdd(&cnt[d], 1);
            if (pos < BCAP) bkt[d * BCAP + pos] = s;
        }
    } else if (b < NB_BUILD + NB_P1) {
        pack_w1_body(W1_rel, W1_root, W1f, 64, 64, (b - NB_BUILD) * 256 + tid);
    } else if (b < NB_BUILD + NB_P1 + NB_P2) {
        pack_w2_body(W2_rel, W2_root, W2f, 128, (b - NB_BUILD - NB_P1) * 256 + tid);
    } else if (b < NB_BUILD + NB_P1 + NB_P2 + NB_P3) {
        pack_w1_body(W3_rel, W3_root, W3f, 128, 128, (b - NB_BUILD - NB_P1 - NB_P2) * 256 + tid);
    } else {
        pack_w2_body(W4_rel, W4_root, W4f, 64, (b - NB_BUILD - NB_P1 - NB_P2 - NB_P3) * 256 + tid);
    }
}

// ---------------------------------------------------------------------------
// Per-graph fused gather+relu+mean-pool (one block = one graph; batch sorted).
// ---------------------------------------------------------------------------
__global__ void gather_relu_pool(const bf16_t* __restrict__ y2, const bf16_t* __restrict__ init,
                                 const int* __restrict__ cnt, const int* __restrict__ bkt,
                                 const int* __restrict__ batch,
                                 bf16_t* __restrict__ h2, float* __restrict__ enc, int Nn) {
    int g = blockIdx.x;
    __shared__ int s_lo, s_hi;
    __shared__ float red[16][128];   // 8KB partials
    if (threadIdx.x == 0) {
        int lo = 0, hi = Nn;
        while (lo < hi) { int mid = (lo + hi) >> 1; if (batch[mid] < g) lo = mid + 1; else hi = mid; }
        s_lo = lo;
        hi = Nn;
        while (lo < hi) { int mid = (lo + hi) >> 1; if (batch[mid] < g + 1) lo = mid + 1; else hi = mid; }
        s_hi = lo;
    }
    __syncthreads();
    const int lo = s_lo, hi = s_hi;
    const int slot = threadIdx.x >> 4;      // 0..15 node slot
    const int j = (threadIdx.x & 15) * 8;   // col group
    float psum[8] = {0.f,0.f,0.f,0.f,0.f,0.f,0.f,0.f};
    for (int n = lo + slot; n < hi; n += 16) {
        int c = cnt[n]; if (c > BCAP) c = BCAP;
        const int* bp = bkt + n * BCAP;
        U4 u; u.v = *(const uint4*)(init + (size_t)n * 128 + j);
        float s[8];
        #pragma unroll
        for (int k = 0; k < 8; ++k) s[k] = us2f(u.s[k]);
        int i = 0;
        for (; i + 4 <= c; i += 4) {
            int s0 = bp[i], s1 = bp[i + 1], s2 = bp[i + 2], s3 = bp[i + 3];
            U4 w0, w1, w2, w3;
            w0.v = *(const uint4*)(y2 + (size_t)s0 * 128 + j);
            w1.v = *(const uint4*)(y2 + (size_t)s1 * 128 + j);
            w2.v = *(const uint4*)(y2 + (size_t)s2 * 128 + j);
            w3.v = *(const uint4*)(y2 + (size_t)s3 * 128 + j);
            #pragma unroll
            for (int k = 0; k < 8; ++k)
                s[k] += (us2f(w0.s[k]) + us2f(w1.s[k])) + (us2f(w2.s[k]) + us2f(w3.s[k]));
        }
        for (; i < c; ++i) {
            U4 w; w.v = *(const uint4*)(y2 + (size_t)bp[i] * 128 + j);
            #pragma unroll
            for (int k = 0; k < 8; ++k) s[k] += us2f(w.s[k]);
        }
        alignas(16) bf16_t ob[8];
        #pragma unroll
        for (int k = 0; k < 8; ++k) {
            s[k] = fmaxf(s[k], 0.f);
            psum[k] += s[k];
            ob[k] = f2b(s[k]);
        }
        *(uint4*)(h2 + (size_t)n * 128 + j) = *(const uint4*)ob;
    }
    #pragma unroll
    for (int k = 0; k < 8; ++k) red[slot][j + k] = psum[k];
    __syncthreads();
    if (threadIdx.x < 128) {
        int c = threadIdx.x;
        float tot = 0.f;
        #pragma unroll
        for (int r = 0; r < 16; ++r) tot += red[r][c];
        float n = (float)((hi - lo) > 0 ? (hi - lo) : 1);
        enc[(size_t)g * 128 + c] = tot / n;
    }
}

// outF[n] += sum nbr y4   (y4 bf16 [N,64]; outF f32 in-place on d_out)
__global__ void gather_add_b16_64(const bf16_t* __restrict__ y4, const int* __restrict__ cnt,
                                  const int* __restrict__ bkt, float* __restrict__ outF) {
    int t = blockIdx.x * 256 + threadIdx.x;
    int n = t >> 4;
    if (n >= NN) return;
    int j = (t & 15) * 4;
    int c = cnt[n]; if (c > BCAP) c = BCAP;
    const int* bp = bkt + n * BCAP;
    float4 sum = *(const float4*)(outF + n * 64 + j);
    int i = 0;
    for (; i + 4 <= c; i += 4) {
        int s0 = bp[i], s1 = bp[i + 1], s2 = bp[i + 2], s3 = bp[i + 3];
        U2 w0, w1, w2, w3;
        w0.v = *(const uint2*)(y4 + (size_t)s0 * 64 + j);
        w1.v = *(const uint2*)(y4 + (size_t)s1 * 64 + j);
        w2.v = *(const uint2*)(y4 + (size_t)s2 * 64 + j);
        w3.v = *(const uint2*)(y4 + (size_t)s3 * 64 + j);
        sum.x += (us2f(w0.s[0]) + us2f(w1.s[0])) + (us2f(w2.s[0]) + us2f(w3.s[0]));
        sum.y += (us2f(w0.s[1]) + us2f(w1.s[1])) + (us2f(w2.s[1]) + us2f(w3.s[1]));
        sum.z += (us2f(w0.s[2]) + us2f(w1.s[2])) + (us2f(w2.s[2]) + us2f(w3.s[2]));
        sum.w += (us2f(w0.s[3]) + us2f(w1.s[3])) + (us2f(w2.s[3]) + us2f(w3.s[3]));
    }
    for (; i < c; ++i) {
        U2 w; w.v = *(const uint2*)(y4 + (size_t)bp[i] * 64 + j);
        sum.x += us2f(w.s[0]); sum.y += us2f(w.s[1]);
        sum.z += us2f(w.s[2]); sum.w += us2f(w.s[3]);
    }
    *(float4*)(outF + n * 64 + j) = sum;
}

// ---------------------------------------------------------------------------
// Fused gather + two-GEMM v16 = v15 + (a) 8-DEEP batched weight loads for the
// NOUT=128 instantiation (acc = 48 regs there vs 64 in NOUT=256 -> room for
// w[8]=32 regs; peak ~115 < 128; #pragma unroll 1 on the batch loop stops
// v7-style hoisting of all frags), halving latency-exposed batch rounds in
// both stages; (b) s_setprio(1) around MFMA clusters (T5: 2 independent
// blocks/CU at different phases -> scheduler favors MFMA-entering block).
//   Block = 64 nodes (2 node-tiles of 32), 512 threads = 8 waves.
//   Stage 1: wave wn owns hcol-tile (ci*8+wn) x BOTH node tiles.
//   H chunk [64 x 256] bf16, single-buffered (32KB), frag-major.
//   Stage 2 NOUT=256: wave wn owns out-tile wn x BOTH node-tiles (W2 dedup).
//   Stage 2 NOUT=128: wave (og, wr): 1 out-tile x node-tile wr.
// Outputs: outcol < NOUT/2 -> yout (bf16 if YBF16), else initout (+bias2).
// ---------------------------------------------------------------------------
template <int K, int NOUT, int F32OUT, int YBF16, int SRCF32>
__global__ __launch_bounds__(512, 4) void fused16(
    const void* __restrict__ src, const int* __restrict__ cnt,
    const int* __restrict__ bkt,
    const bf16_t* __restrict__ W1f, const float* __restrict__ bias1,
    const bf16_t* __restrict__ W2f, const float* __restrict__ bias2,
    void* __restrict__ yout, void* __restrict__ initout)
{
    constexpr int KT16 = K / 16;      // A k-tiles (16-deep), 8 or 16
    constexpr int OT32 = NOUT / 32;   // out 32-col tiles (8 or 4)
    constexpr int OCT2 = OT32 / 4;    // out tiles per wave, old mapping (2 or 1)
    constexpr int NACC = (NOUT == 256) ? 2 : OCT2;
    constexpr int OH   = NOUT / 2;
    constexpr int SW   = K / 2;       // source row width (64 f32 / 128 bf16)
    constexpr int HALF = K / 16;      // 8-col groups per half (8 or 16)
    constexpr int STR  = F32OUT ? (NOUT + 4) : (NOUT + 8);
    __shared__ float b1sl[1024];
    __shared__ float b2sl[128];
    __shared__ __align__(16) char smem[(size_t)64 * K * 2 + 64 * 256 * 2];
    bf16_t* Asl = (bf16_t*)smem;                        // frag-major A tile [64*K]
    bf16_t* Hsl = (bf16_t*)(smem + (size_t)64 * K * 2); // frag-major H chunk [64*256]

    const int tid  = threadIdx.x;
    const int lane = tid & 63;
    const int wn   = tid >> 6;        // 0..7
    const int l31  = lane & 31;
    const int hi   = lane >> 5;
    const int og   = wn >> 1;         // old stage-2 out-col group
    const int wr   = wn & 1;          // old stage-2 node-tile
    const int bm0  = blockIdx.x * 64;

    for (int i = tid; i < 1024; i += 512) b1sl[i] = (i < 1000) ? bias1[i] : 0.f;
    if (tid < OH) b2sl[tid] = bias2[tid];

    // ---- prologue: gather + own-copy directly into Asl (frag-major)
    #pragma unroll
    for (int it = 0; it < (2 * 64 * HALF) / 512; ++it) {
        int task = it * 512 + tid;
        const bool own = task >= 64 * HALF;
        int t2 = own ? task - 64 * HALF : task;
        int i = t2 / HALF, s = t2 - (t2 / HALF) * HALF;
        int n = bm0 + i;
        int j = s * 8;
        float sum[8] = {0.f, 0.f, 0.f, 0.f, 0.f, 0.f, 0.f, 0.f};
        if (n < NN) {
            if (!own) {
                int c = cnt[n]; if (c > BCAP) c = BCAP;
                const int* bp = bkt + n * BCAP;
                int e = 0;
                for (; e + 4 <= c; e += 4) {
                    int s0 = bp[e], s1 = bp[e + 1], s2 = bp[e + 2], s3 = bp[e + 3];
                    if (SRCF32) {
                        const float* r0 = (const float*)src + (size_t)s0 * SW + j;
                        const float* r1 = (const float*)src + (size_t)s1 * SW + j;
                        const float* r2 = (const float*)src + (size_t)s2 * SW + j;
                        const float* r3 = (const float*)src + (size_t)s3 * SW + j;
                        float4 a0 = *(const float4*)r0, b0 = *(const float4*)(r0 + 4);
                        float4 a1 = *(const float4*)r1, b1 = *(const float4*)(r1 + 4);
                        float4 a2 = *(const float4*)r2, b2 = *(const float4*)(r2 + 4);
                        float4 a3 = *(const float4*)r3, b3 = *(const float4*)(r3 + 4);
                        sum[0] += (a0.x + a1.x) + (a2.x + a3.x);
                        sum[1] += (a0.y + a1.y) + (a2.y + a3.y);
                        sum[2] += (a0.z + a1.z) + (a2.z + a3.z);
                        sum[3] += (a0.w + a1.w) + (a2.w + a3.w);
                        sum[4] += (b0.x + b1.x) + (b2.x + b3.x);
                        sum[5] += (b0.y + b1.y) + (b2.y + b3.y);
                        sum[6] += (b0.z + b1.z) + (b2.z + b3.z);
                        sum[7] += (b0.w + b1.w) + (b2.w + b3.w);
                    } else {
                        U4 w0, w1, w2, w3;
                        w0.v = *(const uint4*)((const bf16_t*)src + (size_t)s0 * SW + j);
                        w1.v = *(const uint4*)((const bf16_t*)src + (size_t)s1 * SW + j);
                        w2.v = *(const uint4*)((const bf16_t*)src + (size_t)s2 * SW + j);
                        w3.v = *(const uint4*)((const bf16_t*)src + (size_t)s3 * SW + j);
                        #pragma unroll
                        for (int k = 0; k < 8; ++k)
                            sum[k] += (us2f(w0.s[k]) + us2f(w1.s[k])) + (us2f(w2.s[k]) + us2f(w3.s[k]));
                    }
                }
                for (; e < c; ++e) {
                    int sn = bp[e];
                    if (SRCF32) {
                        const float* r = (const float*)src + (size_t)sn * SW + j;
                        float4 a = *(const float4*)r;
                        float4 b = *(const float4*)(r + 4);
                        sum[0] += a.x; sum[1] += a.y; sum[2] += a.z; sum[3] += a.w;
                        sum[4] += b.x; sum[5] += b.y; sum[6] += b.z; sum[7] += b.w;
                    } else {
                        U4 w; w.v = *(const uint4*)((const bf16_t*)src + (size_t)sn * SW + j);
                        #pragma unroll
                        for (int k = 0; k < 8; ++k) sum[k] += us2f(w.s[k]);
                    }
                }
            } else {
                if (SRCF32) {
                    const float* r = (const float*)src + (size_t)n * SW + j;
                    float4 a = *(const float4*)r;
                    float4 b = *(const float4*)(r + 4);
                    sum[0] = a.x; sum[1] = a.y; sum[2] = a.z; sum[3] = a.w;
                    sum[4] = b.x; sum[5] = b.y; sum[6] = b.z; sum[7] = b.w;
                } else {
                    U4 w; w.v = *(const uint4*)((const bf16_t*)src + (size_t)n * SW + j);
                    #pragma unroll
                    for (int k = 0; k < 8; ++k) sum[k] = us2f(w.s[k]);
                }
            }
        }
        int cc = (own ? K / 2 : 0) + j;           // column in A's K-space
        int off = (((i >> 5) * KT16 + (cc >> 4)) * 64 + ((cc >> 3) & 1) * 32 + (i & 31)) * 8;
        alignas(16) bf16_t ob[8];
        #pragma unroll
        for (int k = 0; k < 8; ++k) ob[k] = f2b(sum[k]);
        *(uint4*)(&Asl[off]) = *(const uint4*)ob;
    }

    floatx16 acc2[NACC];
    #pragma unroll
    for (int oo = 0; oo < NACC; ++oo) acc2[oo] = (floatx16)FZ16;

    barrier_lds();   // Asl + biases ready

    for (int ci = 0; ci < 4; ++ci) {
        // ---- stage 1: wave computes h-tile (ci*8 + wn) x both node-tiles
        floatx16 acc1[2];
        acc1[0] = (floatx16)FZ16;
        acc1[1] = (floatx16)FZ16;

        const bf16_t* w1p = W1f + (((size_t)(ci * 8 + wn) * KT16) * 64 + lane) * 8;
        if (NOUT == 128) {
            // 8-deep batches (acc headroom: 48 acc + 32 w < 128), unroll 1
            // stops the compiler hoisting all KT16 frags (v7 spill mode).
            #pragma unroll 1
            for (int kh = 0; kh < KT16 / 8; ++kh) {
                short8 w1v[8];
                #pragma unroll
                for (int u = 0; u < 8; ++u)
                    w1v[u] = *(const short8*)(w1p + (size_t)(kh * 8 + u) * 512);
                __builtin_amdgcn_s_setprio(1);
                #pragma unroll
                for (int u = 0; u < 8; ++u) {
                    int kk = kh * 8 + u;
                    short8 av0 = *(const short8*)&Asl[((0 * KT16 + kk) * 64 + lane) * 8];
                    acc1[0] = __builtin_amdgcn_mfma_f32_32x32x16_bf16(w1v[u], av0, acc1[0], 0, 0, 0);
                    short8 av1 = *(const short8*)&Asl[((1 * KT16 + kk) * 64 + lane) * 8];
                    acc1[1] = __builtin_amdgcn_mfma_f32_32x32x16_bf16(w1v[u], av1, acc1[1], 0, 0, 0);
                }
                __builtin_amdgcn_s_setprio(0);
            }
        } else {
            #pragma unroll
            for (int kh = 0; kh < KT16 / 4; ++kh) {
                short8 w1v[4];
                #pragma unroll
                for (int u = 0; u < 4; ++u)
                    w1v[u] = *(const short8*)(w1p + (size_t)(kh * 4 + u) * 512);
                __builtin_amdgcn_s_setprio(1);
                #pragma unroll
                for (int u = 0; u < 4; ++u) {
                    int kk = kh * 4 + u;
                    short8 av0 = *(const short8*)&Asl[((0 * KT16 + kk) * 64 + lane) * 8];
                    acc1[0] = __builtin_amdgcn_mfma_f32_32x32x16_bf16(w1v[u], av0, acc1[0], 0, 0, 0);
                    short8 av1 = *(const short8*)&Asl[((1 * KT16 + kk) * 64 + lane) * 8];
                    acc1[1] = __builtin_amdgcn_mfma_f32_32x32x16_bf16(w1v[u], av1, acc1[1], 0, 0, 0);
                }
                __builtin_amdgcn_s_setprio(0);
            }
        }

        barrier_lds();   // previous chunk's stage-2 readers done with Hsl

        // bias+relu -> frag-major H; C/D: node=l31, hcol32=(r&3)+8*(r>>2)+4*hi
        #pragma unroll
        for (int nt2 = 0; nt2 < 2; ++nt2) {
            #pragma unroll
            for (int g = 0; g < 4; ++g) {
                float4 bv = *(const float4*)&b1sl[ci * 256 + wn * 32 + 8 * g + 4 * hi];
                const float* bvp = (const float*)&bv;
                alignas(8) bf16_t hb[4];
                #pragma unroll
                for (int e = 0; e < 4; ++e)
                    hb[e] = f2b(fmaxf(acc1[nt2][4 * g + e] + bvp[e], 0.f));
                int off = ((nt2 * 16 + wn * 2 + (g >> 1)) * 64 + (g & 1) * 32 + l31) * 8 + 4 * hi;
                *(uint2*)&Hsl[off] = *(const uint2*)hb;
            }
        }

        barrier_lds();   // H chunk visible

        // ---- stage 2
        if (NOUT == 256) {
            // dedup mapping: wave wn owns out-tile o=wn x BOTH node-tiles
            const bf16_t* w2p = W2f + (((size_t)wn * 64 + ci * 16) * 64 + lane) * 8;
            #pragma unroll
            for (int kg = 0; kg < 4; ++kg) {
                short8 w2v[4];
                #pragma unroll
                for (int u = 0; u < 4; ++u)
                    w2v[u] = *(const short8*)(w2p + (size_t)(kg * 4 + u) * 512);
                __builtin_amdgcn_s_setprio(1);
                #pragma unroll
                for (int u = 0; u < 4; ++u) {
                    int ks = kg * 4 + u;
                    short8 hf0 = *(const short8*)&Hsl[((0 * 16 + ks) * 64 + lane) * 8];
                    acc2[0] = __builtin_amdgcn_mfma_f32_32x32x16_bf16(w2v[u], hf0, acc2[0], 0, 0, 0);
                    short8 hf1 = *(const short8*)&Hsl[((1 * 16 + ks) * 64 + lane) * 8];
                    acc2[1] = __builtin_amdgcn_mfma_f32_32x32x16_bf16(w2v[u], hf1, acc2[1], 0, 0, 0);
                }
                __builtin_amdgcn_s_setprio(0);
            }
        } else {
            // old mapping: wave (og, wr): 1 out-tile x node-tile wr; 8-deep
            const bf16_t* w2p = W2f + ((((size_t)og) * 64 + ci * 16) * 64 + lane) * 8;
            #pragma unroll 1
            for (int kg = 0; kg < 2; ++kg) {
                short8 w2v[8];
                #pragma unroll
                for (int u = 0; u < 8; ++u)
                    w2v[u] = *(const short8*)(w2p + (size_t)(kg * 8 + u) * 512);
                __builtin_amdgcn_s_setprio(1);
                #pragma unroll
                for (int u = 0; u < 8; ++u) {
                    int ks = kg * 8 + u;
                    short8 hf = *(const short8*)&Hsl[((wr * 16 + ks) * 64 + lane) * 8];
                    acc2[0] = __builtin_amdgcn_mfma_f32_32x32x16_bf16(w2v[u], hf, acc2[0], 0, 0, 0);
                }
                __builtin_amdgcn_s_setprio(0);
            }
        }
    }

    // ---- epilogue: stage acc2(+bias) into LDS [node][outcol] (padded),
    //      then copy full rows out with coalesced line-aligned stores.
    barrier_lds();   // everyone done reading Hsl/Asl
    if (NOUT == 256) {
        bf16_t* st = (bf16_t*)smem;
        #pragma unroll
        for (int nt2 = 0; nt2 < 2; ++nt2) {
            const int r = nt2 * 32 + l31;
            #pragma unroll
            for (int g = 0; g < 4; ++g) {
                int oc = wn * 32 + 8 * g + 4 * hi;
                const bool isInit = (oc >= OH);
                int col = isInit ? oc - OH : oc;
                float4 bv = isInit ? *(const float4*)&b2sl[col]
                                   : make_float4(0.f, 0.f, 0.f, 0.f);
                const float* bvp = (const float*)&bv;
                alignas(8) bf16_t ob[4];
                #pragma unroll
                for (int e = 0; e < 4; ++e) ob[e] = f2b(acc2[nt2][4 * g + e] + bvp[e]);
                *(uint2*)&st[r * STR + oc] = *(const uint2*)ob;
            }
        }
    } else {
        const int r = wr * 32 + l31;   // node row within block
        float* st = (float*)smem;      // f32 staging (F32OUT=1 for NOUT=128)
        #pragma unroll
        for (int oo = 0; oo < OCT2; ++oo) {
            int o = og * OCT2 + oo;
            #pragma unroll
            for (int g = 0; g < 4; ++g) {
                int oc = o * 32 + 8 * g + 4 * hi;
                const bool isInit = (oc >= OH);
                int col = isInit ? oc - OH : oc;
                float4 bv = isInit ? *(const float4*)&b2sl[col]
                                   : make_float4(0.f, 0.f, 0.f, 0.f);
                const float* bvp = (const float*)&bv;
                float v[4];
                #pragma unroll
                for (int e = 0; e < 4; ++e) v[e] = acc2[oo][4 * g + e] + bvp[e];
                *(float4*)&st[r * STR + oc] = make_float4(v[0], v[1], v[2], v[3]);
            }
        }
    }
    barrier_lds();   // staging written
    if (NOUT == 256) {
        constexpr int CH = NOUT / 8;
        constexpr int CHH = CH / 2;
        const bf16_t* st = (const bf16_t*)smem;
        for (int t = tid; t < 64 * CH; t += 512) {
            int nd = t / CH, c = t - (t / CH) * CH;
            int node = bm0 + nd;
            if (node >= NN) continue;
            const bool isInit = (c >= CHH);
            int ch = isInit ? c - CHH : c;
            uint4 v = *(const uint4*)&st[nd * STR + c * 8];
            bf16_t* dst = isInit ? (bf16_t*)initout : (bf16_t*)yout;
            *(uint4*)(dst + (size_t)node * OH + ch * 8) = v;
        }
    } else {
        const float* st = (const float*)smem;
        for (int t = tid; t < 64 * (OH / 4); t += 512) {
            int nd = t / (OH / 4), c = t - (t / (OH / 4)) * (OH / 4);
            int node = bm0 + nd;
            if (node >= NN) continue;
            float4 v = *(const float4*)&st[nd * STR + OH + c * 4];
            *(float4*)((float*)initout + (size_t)node * OH + c * 4) = v;
        }
        if (YBF16) {
            for (int t = tid; t < 64 * (OH / 8); t += 512) {
                int nd = t / (OH / 8), c = t - (t / (OH / 8)) * (OH / 8);
                int node = bm0 + nd;
                if (node >= NN) continue;
                float4 a = *(const float4*)&st[nd * STR + c * 8];
                float4 b = *(const float4*)&st[nd * STR + c * 8 + 4];
                alignas(16) bf16_t ob[8];
                ob[0] = f2b(a.x); ob[1] = f2b(a.y); ob[2] = f2b(a.z); ob[3] = f2b(a.w);
                ob[4] = f2b(b.x); ob[5] = f2b(b.y); ob[6] = f2b(b.z); ob[7] = f2b(b.w);
                *(uint4*)((bf16_t*)yout + (size_t)node * OH + c * 8) = *(const uint4*)ob;
            }
        } else {
            for (int t = tid; t < 64 * (OH / 4); t += 512) {
                int nd = t / (OH / 4), c = t - (t / (OH / 4)) * (OH / 4);
                int node = bm0 + nd;
                if (node >= NN) continue;
                float4 v = *(const float4*)&st[nd * STR + c * 4];
                *(float4*)((float*)yout + (size_t)node * OH + c * 4) = v;
            }
        }
    }
}

// ---------------------------------------------------------------------------
// Launch
// ---------------------------------------------------------------------------
extern "C" void kernel_launch(void* const* d_in, const int* in_sizes, int n_in,
                              void* d_out, int out_size, void* d_ws, size_t ws_size,
                              hipStream_t stream) {
    const float* x       = (const float*)d_in[0];
    const int*   ei      = (const int*)d_in[1];
    const int*   batch   = (const int*)d_in[2];
    const float* W1_rel  = (const float*)d_in[3];
    const float* b1      = (const float*)d_in[4];
    const float* W1_root = (const float*)d_in[5];
    const float* W2_rel  = (const float*)d_in[6];
    const float* b2      = (const float*)d_in[7];
    const float* W2_root = (const float*)d_in[8];
    const float* W3_rel  = (const float*)d_in[9];
    const float* b3      = (const float*)d_in[10];
    const float* W3_root = (const float*)d_in[11];
    const float* W4_rel  = (const float*)d_in[12];
    const float* b4      = (const float*)d_in[13];
    const float* W4_root = (const float*)d_in[14];

    float* outF = (float*)d_out;            // [N,64] then [G,128]
    float* enc  = outF + NN * 64;

    char* ws = (char*)d_ws;                         // ~66 MB
    bf16_t* y2buf  = (bf16_t*)(ws + 0);             // [N,128] bf16
    bf16_t* h2init = (bf16_t*)(ws + 12800000ULL);   // [N,128] bf16
    bf16_t* h2buf  = (bf16_t*)(ws + 25600000ULL);   // [N,128] bf16
    bf16_t* y4buf  = (bf16_t*)(ws + 38400000ULL);   // [N,64] bf16
    int*    cnt    = (int*)(ws + 51200000ULL);      // [N]
    int*    bkt    = (int*)(ws + 51400064ULL);      // [N*64]
    bf16_t* W1f    = (bf16_t*)(ws + 64200064ULL);   // 1024x128 frag-major
    bf16_t* W2f    = (bf16_t*)(ws + 64462208ULL);   // 256x1024 frag-major
    bf16_t* W3f    = (bf16_t*)(ws + 64986496ULL);   // 1024x256 frag-major
    bf16_t* W4f    = (bf16_t*)(ws + 65510784ULL);   // 128x1024 frag-major

    const int RB64 = (NN + 63) / 64;  // 782

    // ---- adjacency + all weight packs in one launch
    hipMemsetAsync(cnt, 0, NN * sizeof(int), stream);
    setup_all<<<NB_BUILD + NB_P1 + NB_P2 + NB_P3 + NB_P4, 256, 0, stream>>>(
        ei, cnt, bkt, W1_rel, W1_root, W2_rel, W2_root,
        W3_rel, W3_root, W4_rel, W4_root, W1f, W2f, W3f, W4f);

    // ---- L1+L2 fused: A=[gather(x)|x]; h1 on-chip;
    //      y2 = h1@W2_rel^T (bf16), h2init = h1@W2_root^T + b2 (bf16)
    fused16<128, 256, 0, 0, 1><<<RB64, 512, 0, stream>>>(x, cnt, bkt, W1f, b1, W2f, b2, y2buf, h2init);

    // ---- h2 = relu(h2init + gather(y2)); encoded = mean-pool(h2), fused
    gather_relu_pool<<<GG, 256, 0, stream>>>(y2buf, h2init, cnt, bkt, batch, h2buf, enc, NN);

    // ---- L3+L4 fused: A=[gather(h2)|h2]; h3 on-chip;
    //      y4 = h3@W4_rel^T (bf16), outF = h3@W4_root^T + b4 (f32, direct)
    fused16<256, 128, 1, 1, 0><<<RB64, 512, 0, stream>>>(h2buf, cnt, bkt, W3f, b3, W4f, b4, y4buf, outF);

    // ---- out = outF + gather(y4)   (y4 bf16 halves neighbor-read traffic)
    gather_add_b16_64<<<(NN * 16 + 255) / 256, 256, 0, stream>>>(y4buf, cnt, bkt, outF);
}

// Round 12
// 259.451 us; speedup vs baseline: 8.6564x; 1.0043x over previous
//
#include <hip/hip_runtime.h>
#include <hip/hip_bf16.h>

typedef __hip_bfloat16 bf16_t;
typedef __attribute__((ext_vector_type(8))) short short8;
typedef __attribute__((ext_vector_type(16))) float floatx16;

static __device__ __forceinline__ float b2f(bf16_t v) { return __bfloat162float(v); }
static __device__ __forceinline__ bf16_t f2b(float v) { return __float2bfloat16(v); }
static __device__ __forceinline__ float us2f(unsigned short u) {
    union { unsigned int i; float f; } c; c.i = ((unsigned int)u) << 16; return c.f;
}

// LDS-only barrier: does NOT drain vmcnt -> global loads issued before the
// barrier stay in flight across it (v17 exploits this for weight prefetch).
static __device__ __forceinline__ void barrier_lds() {
    asm volatile("s_waitcnt lgkmcnt(0)" ::: "memory");
    __builtin_amdgcn_s_barrier();
    asm volatile("" ::: "memory");
}

// Problem constants
#define NN 50000
#define EE 200000
#define GG 2048
#define BCAP 64   // in-degree cap; mean deg = 4

union U4 { uint4 v; unsigned short s[8]; };
union U2 { uint2 v; unsigned short s[4]; };

#define FZ16 {0.f,0.f,0.f,0.f,0.f,0.f,0.f,0.f,0.f,0.f,0.f,0.f,0.f,0.f,0.f,0.f}

// 32x32x16 fragment-major layout (A and B operands share it):
//   element (i, k) of an [I x K] K-major matrix lives at
//   ((i/32 * (K/16) + k/16) * 64 + ((k%16)/8)*32 + i%32) * 8 + k%8
// One wave fragment = 64 lanes x short8 = contiguous 1KB.

// ---------------------------------------------------------------------------
// Merged setup: inverted adjacency build + all 4 weight packs in ONE launch
// ---------------------------------------------------------------------------
__device__ __forceinline__ void pack_w1_body(const float* __restrict__ Wa,
                                             const float* __restrict__ Wb,
                                             bf16_t* __restrict__ out,
                                             int K1, int K2, int idx) {
    int K = K1 + K2;
    int KT16 = K >> 4;
    int e = idx & 7;
    int l = (idx >> 3) & 63;
    int tile = idx >> 9;
    int kt = tile % KT16, t = tile / KT16;
    int c = t * 32 + (l & 31);
    int k = kt * 16 + (l >> 5) * 8 + e;
    float v = 0.f;
    if (c < 1000) v = (k < K1) ? Wa[c * K1 + k] : Wb[c * K2 + (k - K1)];
    out[idx] = f2b(v);
}
__device__ __forceinline__ void pack_w2_body(const float* __restrict__ Wa,
                                             const float* __restrict__ Wb,
                                             bf16_t* __restrict__ out,
                                             int OH, int idx) {
    int e = idx & 7;
    int l = (idx >> 3) & 63;
    int tile = idx >> 9;
    int kt2 = tile & 63, o = tile >> 6;   // K=1024 -> 64 k-tiles
    int c = o * 32 + (l & 31);
    int k = kt2 * 16 + (l >> 5) * 8 + e;
    float v = 0.f;
    if (k < 1000) v = (c < OH) ? Wa[c * 1000 + k] : Wb[(c - OH) * 1000 + k];
    out[idx] = f2b(v);
}

#define NB_BUILD 782   // (EE+255)/256
#define NB_P1 512      // 131072/256
#define NB_P2 1024     // 262144/256
#define NB_P3 1024
#define NB_P4 512

__global__ void setup_all(const int* __restrict__ ei, int* __restrict__ cnt,
                          int* __restrict__ bkt,
                          const float* __restrict__ W1_rel, const float* __restrict__ W1_root,
                          const float* __restrict__ W2_rel, const float* __restrict__ W2_root,
                          const float* __restrict__ W3_rel, const float* __restrict__ W3_root,
                          const float* __restrict__ W4_rel, const float* __restrict__ W4_root,
                          bf16_t* __restrict__ W1f, bf16_t* __restrict__ W2f,
                          bf16_t* __restrict__ W3f, bf16_t* __restrict__ W4f) {
    int b = blockIdx.x;
    int tid = threadIdx.x;
    if (b < NB_BUILD) {
        int e = b * 256 + tid;
        if (e < EE) {
            int s = ei[e];
            int d = ei[EE + e];
            int pos = atomicAdd(&cnt[d], 1);
            if (pos < BCAP) bkt[d * BCAP + pos] = s;
        }
    } else if (b < NB_BUILD + NB_P1) {
        pack_w1_body(W1_rel, W1_root, W1f, 64, 64, (b - NB_BUILD) * 256 + tid);
    } else if (b < NB_BUILD + NB_P1 + NB_P2) {
        pack_w2_body(W2_rel, W2_root, W2f, 128, (b - NB_BUILD - NB_P1) * 256 + tid);
    } else if (b < NB_BUILD + NB_P1 + NB_P2 + NB_P3) {
        pack_w1_body(W3_rel, W3_root, W3f, 128, 128, (b - NB_BUILD - NB_P1 - NB_P2) * 256 + tid);
    } else {
        pack_w2_body(W4_rel, W4_root, W4f, 64, (b - NB_BUILD - NB_P1 - NB_P2 - NB_P3) * 256 + tid);
    }
}

// ---------------------------------------------------------------------------
// Per-graph fused gather+relu+mean-pool (one block = one graph; batch sorted).
// ---------------------------------------------------------------------------
__global__ void gather_relu_pool(const bf16_t* __restrict__ y2, const bf16_t* __restrict__ init,
                                 const int* __restrict__ cnt, const int* __restrict__ bkt,
                                 const int* __restrict__ batch,
                                 bf16_t* __restrict__ h2, float* __restrict__ enc, int Nn) {
    int g = blockIdx.x;
    __shared__ int s_lo, s_hi;
    __shared__ float red[16][128];   // 8KB partials
    if (threadIdx.x == 0) {
        int lo = 0, hi = Nn;
        while (lo < hi) { int mid = (lo + hi) >> 1; if (batch[mid] < g) lo = mid + 1; else hi = mid; }
        s_lo = lo;
        hi = Nn;
        while (lo < hi) { int mid = (lo + hi) >> 1; if (batch[mid] < g + 1) lo = mid + 1; else hi = mid; }
        s_hi = lo;
    }
    __syncthreads();
    const int lo = s_lo, hi = s_hi;
    const int slot = threadIdx.x >> 4;      // 0..15 node slot
    const int j = (threadIdx.x & 15) * 8;   // col group
    float psum[8] = {0.f,0.f,0.f,0.f,0.f,0.f,0.f,0.f};
    for (int n = lo + slot; n < hi; n += 16) {
        int c = cnt[n]; if (c > BCAP) c = BCAP;
        const int* bp = bkt + n * BCAP;
        U4 u; u.v = *(const uint4*)(init + (size_t)n * 128 + j);
        float s[8];
        #pragma unroll
        for (int k = 0; k < 8; ++k) s[k] = us2f(u.s[k]);
        int i = 0;
        for (; i + 4 <= c; i += 4) {
            int s0 = bp[i], s1 = bp[i + 1], s2 = bp[i + 2], s3 = bp[i + 3];
            U4 w0, w1, w2, w3;
            w0.v = *(const uint4*)(y2 + (size_t)s0 * 128 + j);
            w1.v = *(const uint4*)(y2 + (size_t)s1 * 128 + j);
            w2.v = *(const uint4*)(y2 + (size_t)s2 * 128 + j);
            w3.v = *(const uint4*)(y2 + (size_t)s3 * 128 + j);
            #pragma unroll
            for (int k = 0; k < 8; ++k)
                s[k] += (us2f(w0.s[k]) + us2f(w1.s[k])) + (us2f(w2.s[k]) + us2f(w3.s[k]));
        }
        for (; i < c; ++i) {
            U4 w; w.v = *(const uint4*)(y2 + (size_t)bp[i] * 128 + j);
            #pragma unroll
            for (int k = 0; k < 8; ++k) s[k] += us2f(w.s[k]);
        }
        alignas(16) bf16_t ob[8];
        #pragma unroll
        for (int k = 0; k < 8; ++k) {
            s[k] = fmaxf(s[k], 0.f);
            psum[k] += s[k];
            ob[k] = f2b(s[k]);
        }
        *(uint4*)(h2 + (size_t)n * 128 + j) = *(const uint4*)ob;
    }
    #pragma unroll
    for (int k = 0; k < 8; ++k) red[slot][j + k] = psum[k];
    __syncthreads();
    if (threadIdx.x < 128) {
        int c = threadIdx.x;
        float tot = 0.f;
        #pragma unroll
        for (int r = 0; r < 16; ++r) tot += red[r][c];
        float n = (float)((hi - lo) > 0 ? (hi - lo) : 1);
        enc[(size_t)g * 128 + c] = tot / n;
    }
}

// outF[n] += sum nbr y4   (y4 bf16 [N,64]; outF f32 in-place on d_out)
__global__ void gather_add_b16_64(const bf16_t* __restrict__ y4, const int* __restrict__ cnt,
                                  const int* __restrict__ bkt, float* __restrict__ outF) {
    int t = blockIdx.x * 256 + threadIdx.x;
    int n = t >> 4;
    if (n >= NN) return;
    int j = (t & 15) * 4;
    int c = cnt[n]; if (c > BCAP) c = BCAP;
    const int* bp = bkt + n * BCAP;
    float4 sum = *(const float4*)(outF + n * 64 + j);
    int i = 0;
    for (; i + 4 <= c; i += 4) {
        int s0 = bp[i], s1 = bp[i + 1], s2 = bp[i + 2], s3 = bp[i + 3];
        U2 w0, w1, w2, w3;
        w0.v = *(const uint2*)(y4 + (size_t)s0 * 64 + j);
        w1.v = *(const uint2*)(y4 + (size_t)s1 * 64 + j);
        w2.v = *(const uint2*)(y4 + (size_t)s2 * 64 + j);
        w3.v = *(const uint2*)(y4 + (size_t)s3 * 64 + j);
        sum.x += (us2f(w0.s[0]) + us2f(w1.s[0])) + (us2f(w2.s[0]) + us2f(w3.s[0]));
        sum.y += (us2f(w0.s[1]) + us2f(w1.s[1])) + (us2f(w2.s[1]) + us2f(w3.s[1]));
        sum.z += (us2f(w0.s[2]) + us2f(w1.s[2])) + (us2f(w2.s[2]) + us2f(w3.s[2]));
        sum.w += (us2f(w0.s[3]) + us2f(w1.s[3])) + (us2f(w2.s[3]) + us2f(w3.s[3]));
    }
    for (; i < c; ++i) {
        U2 w; w.v = *(const uint2*)(y4 + (size_t)bp[i] * 64 + j);
        sum.x += us2f(w.s[0]); sum.y += us2f(w.s[1]);
        sum.z += us2f(w.s[2]); sum.w += us2f(w.s[3]);
    }
    *(float4*)(outF + n * 64 + j) = sum;
}

// ---------------------------------------------------------------------------
// Fused gather + two-GEMM v17 = v16 + CROSS-PHASE WEIGHT PREFETCH exploiting
// barrier_lds (no vmcnt drain -> loads survive barriers): stage-2's last
// batch round also issues the NEXT chunk's first w1 batch (w1pre), which has
// stage-2 MFMAs + 2 barriers + the H-write phase to land. First chunk's
// w1pre issues before the post-prologue barrier. fused1's stage-2 widened to
// 8-deep (acc1 is dead there; live = acc2 32 + w2v 32 + w1pre 16 + arch).
// Per-phase reg audit <= ~110 for both instantiations.
//   Block = 64 nodes (2 node-tiles of 32), 512 threads = 8 waves.
//   Stage 1: wave wn owns hcol-tile (ci*8+wn) x BOTH node tiles.
//   H chunk [64 x 256] bf16, single-buffered (32KB), frag-major.
//   Stage 2 NOUT=256: wave wn owns out-tile wn x BOTH node-tiles (W2 dedup).
//   Stage 2 NOUT=128: wave (og, wr): 1 out-tile x node-tile wr.
// Outputs: outcol < NOUT/2 -> yout (bf16 if YBF16), else initout (+bias2).
// ---------------------------------------------------------------------------
template <int K, int NOUT, int F32OUT, int YBF16, int SRCF32>
__global__ __launch_bounds__(512, 4) void fused17(
    const void* __restrict__ src, const int* __restrict__ cnt,
    const int* __restrict__ bkt,
    const bf16_t* __restrict__ W1f, const float* __restrict__ bias1,
    const bf16_t* __restrict__ W2f, const float* __restrict__ bias2,
    void* __restrict__ yout, void* __restrict__ initout)
{
    constexpr int KT16 = K / 16;      // A k-tiles (16-deep): 8 or 16
    constexpr int PD   = KT16 / 2;    // w1 batch depth (4 or 8); 2 rounds
    constexpr int OT32 = NOUT / 32;   // out 32-col tiles (8 or 4)
    constexpr int OCT2 = OT32 / 4;    // out tiles per wave, old mapping (2 or 1)
    constexpr int NACC = (NOUT == 256) ? 2 : OCT2;
    constexpr int OH   = NOUT / 2;
    constexpr int SW   = K / 2;       // source row width (64 f32 / 128 bf16)
    constexpr int HALF = K / 16;      // 8-col groups per half (8 or 16)
    constexpr int STR  = F32OUT ? (NOUT + 4) : (NOUT + 8);
    __shared__ float b1sl[1024];
    __shared__ float b2sl[128];
    __shared__ __align__(16) char smem[(size_t)64 * K * 2 + 64 * 256 * 2];
    bf16_t* Asl = (bf16_t*)smem;                        // frag-major A tile [64*K]
    bf16_t* Hsl = (bf16_t*)(smem + (size_t)64 * K * 2); // frag-major H chunk [64*256]

    const int tid  = threadIdx.x;
    const int lane = tid & 63;
    const int wn   = tid >> 6;        // 0..7
    const int l31  = lane & 31;
    const int hi   = lane >> 5;
    const int og   = wn >> 1;         // old stage-2 out-col group
    const int wr   = wn & 1;          // old stage-2 node-tile
    const int bm0  = blockIdx.x * 64;

    for (int i = tid; i < 1024; i += 512) b1sl[i] = (i < 1000) ? bias1[i] : 0.f;
    if (tid < OH) b2sl[tid] = bias2[tid];

    // ---- prologue: gather + own-copy directly into Asl (frag-major)
    #pragma unroll
    for (int it = 0; it < (2 * 64 * HALF) / 512; ++it) {
        int task = it * 512 + tid;
        const bool own = task >= 64 * HALF;
        int t2 = own ? task - 64 * HALF : task;
        int i = t2 / HALF, s = t2 - (t2 / HALF) * HALF;
        int n = bm0 + i;
        int j = s * 8;
        float sum[8] = {0.f, 0.f, 0.f, 0.f, 0.f, 0.f, 0.f, 0.f};
        if (n < NN) {
            if (!own) {
                int c = cnt[n]; if (c > BCAP) c = BCAP;
                const int* bp = bkt + n * BCAP;
                int e = 0;
                for (; e + 4 <= c; e += 4) {
                    int s0 = bp[e], s1 = bp[e + 1], s2 = bp[e + 2], s3 = bp[e + 3];
                    if (SRCF32) {
                        const float* r0 = (const float*)src + (size_t)s0 * SW + j;
                        const float* r1 = (const float*)src + (size_t)s1 * SW + j;
                        const float* r2 = (const float*)src + (size_t)s2 * SW + j;
                        const float* r3 = (const float*)src + (size_t)s3 * SW + j;
                        float4 a0 = *(const float4*)r0, b0 = *(const float4*)(r0 + 4);
                        float4 a1 = *(const float4*)r1, b1 = *(const float4*)(r1 + 4);
                        float4 a2 = *(const float4*)r2, b2 = *(const float4*)(r2 + 4);
                        float4 a3 = *(const float4*)r3, b3 = *(const float4*)(r3 + 4);
                        sum[0] += (a0.x + a1.x) + (a2.x + a3.x);
                        sum[1] += (a0.y + a1.y) + (a2.y + a3.y);
                        sum[2] += (a0.z + a1.z) + (a2.z + a3.z);
                        sum[3] += (a0.w + a1.w) + (a2.w + a3.w);
                        sum[4] += (b0.x + b1.x) + (b2.x + b3.x);
                        sum[5] += (b0.y + b1.y) + (b2.y + b3.y);
                        sum[6] += (b0.z + b1.z) + (b2.z + b3.z);
                        sum[7] += (b0.w + b1.w) + (b2.w + b3.w);
                    } else {
                        U4 w0, w1, w2, w3;
                        w0.v = *(const uint4*)((const bf16_t*)src + (size_t)s0 * SW + j);
                        w1.v = *(const uint4*)((const bf16_t*)src + (size_t)s1 * SW + j);
                        w2.v = *(const uint4*)((const bf16_t*)src + (size_t)s2 * SW + j);
                        w3.v = *(const uint4*)((const bf16_t*)src + (size_t)s3 * SW + j);
                        #pragma unroll
                        for (int k = 0; k < 8; ++k)
                            sum[k] += (us2f(w0.s[k]) + us2f(w1.s[k])) + (us2f(w2.s[k]) + us2f(w3.s[k]));
                    }
                }
                for (; e < c; ++e) {
                    int sn = bp[e];
                    if (SRCF32) {
                        const float* r = (const float*)src + (size_t)sn * SW + j;
                        float4 a = *(const float4*)r;
                        float4 b = *(const float4*)(r + 4);
                        sum[0] += a.x; sum[1] += a.y; sum[2] += a.z; sum[3] += a.w;
                        sum[4] += b.x; sum[5] += b.y; sum[6] += b.z; sum[7] += b.w;
                    } else {
                        U4 w; w.v = *(const uint4*)((const bf16_t*)src + (size_t)sn * SW + j);
                        #pragma unroll
                        for (int k = 0; k < 8; ++k) sum[k] += us2f(w.s[k]);
                    }
                }
            } else {
                if (SRCF32) {
                    const float* r = (const float*)src + (size_t)n * SW + j;
                    float4 a = *(const float4*)r;
                    float4 b = *(const float4*)(r + 4);
                    sum[0] = a.x; sum[1] = a.y; sum[2] = a.z; sum[3] = a.w;
                    sum[4] = b.x; sum[5] = b.y; sum[6] = b.z; sum[7] = b.w;
                } else {
                    U4 w; w.v = *(const uint4*)((const bf16_t*)src + (size_t)n * SW + j);
                    #pragma unroll
                    for (int k = 0; k < 8; ++k) sum[k] = us2f(w.s[k]);
                }
            }
        }
        int cc = (own ? K / 2 : 0) + j;           // column in A's K-space
        int off = (((i >> 5) * KT16 + (cc >> 4)) * 64 + ((cc >> 3) & 1) * 32 + (i & 31)) * 8;
        alignas(16) bf16_t ob[8];
        #pragma unroll
        for (int k = 0; k < 8; ++k) ob[k] = f2b(sum[k]);
        *(uint4*)(&Asl[off]) = *(const uint4*)ob;
    }

    floatx16 acc2[NACC];
    #pragma unroll
    for (int oo = 0; oo < NACC; ++oo) acc2[oo] = (floatx16)FZ16;

    // prefetch chunk-0's first w1 batch BEFORE the barrier (survives it)
    short8 w1pre[PD];
    {
        const bf16_t* w1p0 = W1f + (((size_t)(0 * 8 + wn) * KT16) * 64 + lane) * 8;
        #pragma unroll
        for (int u = 0; u < PD; ++u)
            w1pre[u] = *(const short8*)(w1p0 + (size_t)u * 512);
    }

    barrier_lds();   // Asl + biases ready

    for (int ci = 0; ci < 4; ++ci) {
        // ---- stage 1: batch 0 from w1pre (already in flight/landed);
        //      batch 1 loads fresh.
        floatx16 acc1[2];
        acc1[0] = (floatx16)FZ16;
        acc1[1] = (floatx16)FZ16;

        const bf16_t* w1p = W1f + (((size_t)(ci * 8 + wn) * KT16) * 64 + lane) * 8;
        __builtin_amdgcn_s_setprio(1);
        #pragma unroll
        for (int u = 0; u < PD; ++u) {
            short8 av0 = *(const short8*)&Asl[((0 * KT16 + u) * 64 + lane) * 8];
            acc1[0] = __builtin_amdgcn_mfma_f32_32x32x16_bf16(w1pre[u], av0, acc1[0], 0, 0, 0);
            short8 av1 = *(const short8*)&Asl[((1 * KT16 + u) * 64 + lane) * 8];
            acc1[1] = __builtin_amdgcn_mfma_f32_32x32x16_bf16(w1pre[u], av1, acc1[1], 0, 0, 0);
        }
        __builtin_amdgcn_s_setprio(0);
        {
            short8 w1v[PD];
            #pragma unroll
            for (int u = 0; u < PD; ++u)
                w1v[u] = *(const short8*)(w1p + (size_t)(PD + u) * 512);
            __builtin_amdgcn_s_setprio(1);
            #pragma unroll
            for (int u = 0; u < PD; ++u) {
                int kk = PD + u;
                short8 av0 = *(const short8*)&Asl[((0 * KT16 + kk) * 64 + lane) * 8];
                acc1[0] = __builtin_amdgcn_mfma_f32_32x32x16_bf16(w1v[u], av0, acc1[0], 0, 0, 0);
                short8 av1 = *(const short8*)&Asl[((1 * KT16 + kk) * 64 + lane) * 8];
                acc1[1] = __builtin_amdgcn_mfma_f32_32x32x16_bf16(w1v[u], av1, acc1[1], 0, 0, 0);
            }
            __builtin_amdgcn_s_setprio(0);
        }

        barrier_lds();   // previous chunk's stage-2 readers done with Hsl

        // bias+relu -> frag-major H; C/D: node=l31, hcol32=(r&3)+8*(r>>2)+4*hi
        #pragma unroll
        for (int nt2 = 0; nt2 < 2; ++nt2) {
            #pragma unroll
            for (int g = 0; g < 4; ++g) {
                float4 bv = *(const float4*)&b1sl[ci * 256 + wn * 32 + 8 * g + 4 * hi];
                const float* bvp = (const float*)&bv;
                alignas(8) bf16_t hb[4];
                #pragma unroll
                for (int e = 0; e < 4; ++e)
                    hb[e] = f2b(fmaxf(acc1[nt2][4 * g + e] + bvp[e], 0.f));
                int off = ((nt2 * 16 + wn * 2 + (g >> 1)) * 64 + (g & 1) * 32 + l31) * 8 + 4 * hi;
                *(uint2*)&Hsl[off] = *(const uint2*)hb;
            }
        }

        barrier_lds();   // H chunk visible

        // ---- stage 2: two peeled 8-deep rounds; round 1 also issues the
        //      NEXT chunk's w1pre loads (they cross the barriers in flight).
        const int cin = (ci < 3) ? ci + 1 : 0;    // clamped (last: unused)
        const bf16_t* w1pn = W1f + (((size_t)(cin * 8 + wn) * KT16) * 64 + lane) * 8;
        if (NOUT == 256) {
            const bf16_t* w2p = W2f + (((size_t)wn * 64 + ci * 16) * 64 + lane) * 8;
            short8 w2v[8];
            // round 0: ks 0..7
            #pragma unroll
            for (int u = 0; u < 8; ++u)
                w2v[u] = *(const short8*)(w2p + (size_t)u * 512);
            __builtin_amdgcn_s_setprio(1);
            #pragma unroll
            for (int u = 0; u < 8; ++u) {
                short8 hf0 = *(const short8*)&Hsl[((0 * 16 + u) * 64 + lane) * 8];
                acc2[0] = __builtin_amdgcn_mfma_f32_32x32x16_bf16(w2v[u], hf0, acc2[0], 0, 0, 0);
                short8 hf1 = *(const short8*)&Hsl[((1 * 16 + u) * 64 + lane) * 8];
                acc2[1] = __builtin_amdgcn_mfma_f32_32x32x16_bf16(w2v[u], hf1, acc2[1], 0, 0, 0);
            }
            __builtin_amdgcn_s_setprio(0);
            // round 1: ks 8..15 + w1 prefetch for cin
            #pragma unroll
            for (int u = 0; u < 8; ++u)
                w2v[u] = *(const short8*)(w2p + (size_t)(8 + u) * 512);
            #pragma unroll
            for (int u = 0; u < PD; ++u)
                w1pre[u] = *(const short8*)(w1pn + (size_t)u * 512);
            __builtin_amdgcn_s_setprio(1);
            #pragma unroll
            for (int u = 0; u < 8; ++u) {
                int ks = 8 + u;
                short8 hf0 = *(const short8*)&Hsl[((0 * 16 + ks) * 64 + lane) * 8];
                acc2[0] = __builtin_amdgcn_mfma_f32_32x32x16_bf16(w2v[u], hf0, acc2[0], 0, 0, 0);
                short8 hf1 = *(const short8*)&Hsl[((1 * 16 + ks) * 64 + lane) * 8];
                acc2[1] = __builtin_amdgcn_mfma_f32_32x32x16_bf16(w2v[u], hf1, acc2[1], 0, 0, 0);
            }
            __builtin_amdgcn_s_setprio(0);
        } else {
            const bf16_t* w2p = W2f + ((((size_t)og) * 64 + ci * 16) * 64 + lane) * 8;
            short8 w2v[8];
            // round 0: ks 0..7
            #pragma unroll
            for (int u = 0; u < 8; ++u)
                w2v[u] = *(const short8*)(w2p + (size_t)u * 512);
            __builtin_amdgcn_s_setprio(1);
            #pragma unroll
            for (int u = 0; u < 8; ++u) {
                short8 hf = *(const short8*)&Hsl[((wr * 16 + u) * 64 + lane) * 8];
                acc2[0] = __builtin_amdgcn_mfma_f32_32x32x16_bf16(w2v[u], hf, acc2[0], 0, 0, 0);
            }
            __builtin_amdgcn_s_setprio(0);
            // round 1: ks 8..15 + w1 prefetch for cin
            #pragma unroll
            for (int u = 0; u < 8; ++u)
                w2v[u] = *(const short8*)(w2p + (size_t)(8 + u) * 512);
            #pragma unroll
            for (int u = 0; u < PD; ++u)
                w1pre[u] = *(const short8*)(w1pn + (size_t)u * 512);
            __builtin_amdgcn_s_setprio(1);
            #pragma unroll
            for (int u = 0; u < 8; ++u) {
                int ks = 8 + u;
                short8 hf = *(const short8*)&Hsl[((wr * 16 + ks) * 64 + lane) * 8];
                acc2[0] = __builtin_amdgcn_mfma_f32_32x32x16_bf16(w2v[u], hf, acc2[0], 0, 0, 0);
            }
            __builtin_amdgcn_s_setprio(0);
        }
    }

    // ---- epilogue: stage acc2(+bias) into LDS [node][outcol] (padded),
    //      then copy full rows out with coalesced line-aligned stores.
    barrier_lds();   // everyone done reading Hsl/Asl
    if (NOUT == 256) {
        bf16_t* st = (bf16_t*)smem;
        #pragma unroll
        for (int nt2 = 0; nt2 < 2; ++nt2) {
            const int r = nt2 * 32 + l31;
            #pragma unroll
            for (int g = 0; g < 4; ++g) {
                int oc = wn * 32 + 8 * g + 4 * hi;
                const bool isInit = (oc >= OH);
                int col = isInit ? oc - OH : oc;
                float4 bv = isInit ? *(const float4*)&b2sl[col]
                                   : make_float4(0.f, 0.f, 0.f, 0.f);
                const float* bvp = (const float*)&bv;
                alignas(8) bf16_t ob[4];
                #pragma unroll
                for (int e = 0; e < 4; ++e) ob[e] = f2b(acc2[nt2][4 * g + e] + bvp[e]);
                *(uint2*)&st[r * STR + oc] = *(const uint2*)ob;
            }
        }
    } else {
        const int r = wr * 32 + l31;   // node row within block
        float* st = (float*)smem;      // f32 staging (F32OUT=1 for NOUT=128)
        #pragma unroll
        for (int oo = 0; oo < OCT2; ++oo) {
            int o = og * OCT2 + oo;
            #pragma unroll
            for (int g = 0; g < 4; ++g) {
                int oc = o * 32 + 8 * g + 4 * hi;
                const bool isInit = (oc >= OH);
                int col = isInit ? oc - OH : oc;
                float4 bv = isInit ? *(const float4*)&b2sl[col]
                                   : make_float4(0.f, 0.f, 0.f, 0.f);
                const float* bvp = (const float*)&bv;
                float v[4];
                #pragma unroll
                for (int e = 0; e < 4; ++e) v[e] = acc2[oo][4 * g + e] + bvp[e];
                *(float4*)&st[r * STR + oc] = make_float4(v[0], v[1], v[2], v[3]);
            }
        }
    }
    barrier_lds();   // staging written
    if (NOUT == 256) {
        constexpr int CH = NOUT / 8;
        constexpr int CHH = CH / 2;
        const bf16_t* st = (const bf16_t*)smem;
        for (int t = tid; t < 64 * CH; t += 512) {
            int nd = t / CH, c = t - (t / CH) * CH;
            int node = bm0 + nd;
            if (node >= NN) continue;
            const bool isInit = (c >= CHH);
            int ch = isInit ? c - CHH : c;
            uint4 v = *(const uint4*)&st[nd * STR + c * 8];
            bf16_t* dst = isInit ? (bf16_t*)initout : (bf16_t*)yout;
            *(uint4*)(dst + (size_t)node * OH + ch * 8) = v;
        }
    } else {
        const float* st = (const float*)smem;
        for (int t = tid; t < 64 * (OH / 4); t += 512) {
            int nd = t / (OH / 4), c = t - (t / (OH / 4)) * (OH / 4);
            int node = bm0 + nd;
            if (node >= NN) continue;
            float4 v = *(const float4*)&st[nd * STR + OH + c * 4];
            *(float4*)((float*)initout + (size_t)node * OH + c * 4) = v;
        }
        if (YBF16) {
            for (int t = tid; t < 64 * (OH / 8); t += 512) {
                int nd = t / (OH / 8), c = t - (t / (OH / 8)) * (OH / 8);
                int node = bm0 + nd;
                if (node >= NN) continue;
                float4 a = *(const float4*)&st[nd * STR + c * 8];
                float4 b = *(const float4*)&st[nd * STR + c * 8 + 4];
                alignas(16) bf16_t ob[8];
                ob[0] = f2b(a.x); ob[1] = f2b(a.y); ob[2] = f2b(a.z); ob[3] = f2b(a.w);
                ob[4] = f2b(b.x); ob[5] = f2b(b.y); ob[6] = f2b(b.z); ob[7] = f2b(b.w);
                *(uint4*)((bf16_t*)yout + (size_t)node * OH + c * 8) = *(const uint4*)ob;
            }
        } else {
            for (int t = tid; t < 64 * (OH / 4); t += 512) {
                int nd = t / (OH / 4), c = t - (t / (OH / 4)) * (OH / 4);
                int node = bm0 + nd;
                if (node >= NN) continue;
                float4 v = *(const float4*)&st[nd * STR + c * 4];
                *(float4*)((float*)yout + (size_t)node * OH + c * 4) = v;
            }
        }
    }
}

// ---------------------------------------------------------------------------
// Launch
// ---------------------------------------------------------------------------
extern "C" void kernel_launch(void* const* d_in, const int* in_sizes, int n_in,
                              void* d_out, int out_size, void* d_ws, size_t ws_size,
                              hipStream_t stream) {
    const float* x       = (const float*)d_in[0];
    const int*   ei      = (const int*)d_in[1];
    const int*   batch   = (const int*)d_in[2];
    const float* W1_rel  = (const float*)d_in[3];
    const float* b1      = (const float*)d_in[4];
    const float* W1_root = (const float*)d_in[5];
    const float* W2_rel  = (const float*)d_in[6];
    const float* b2      = (const float*)d_in[7];
    const float* W2_root = (const float*)d_in[8];
    const float* W3_rel  = (const float*)d_in[9];
    const float* b3      = (const float*)d_in[10];
    const float* W3_root = (const float*)d_in[11];
    const float* W4_rel  = (const float*)d_in[12];
    const float* b4      = (const float*)d_in[13];
    const float* W4_root = (const float*)d_in[14];

    float* outF = (float*)d_out;            // [N,64] then [G,128]
    float* enc  = outF + NN * 64;

    char* ws = (char*)d_ws;                         // ~66 MB
    bf16_t* y2buf  = (bf16_t*)(ws + 0);             // [N,128] bf16
    bf16_t* h2init = (bf16_t*)(ws + 12800000ULL);   // [N,128] bf16
    bf16_t* h2buf  = (bf16_t*)(ws + 25600000ULL);   // [N,128] bf16
    bf16_t* y4buf  = (bf16_t*)(ws + 38400000ULL);   // [N,64] bf16
    int*    cnt    = (int*)(ws + 51200000ULL);      // [N]
    int*    bkt    = (int*)(ws + 51400064ULL);      // [N*64]
    bf16_t* W1f    = (bf16_t*)(ws + 64200064ULL);   // 1024x128 frag-major
    bf16_t* W2f    = (bf16_t*)(ws + 64462208ULL);   // 256x1024 frag-major
    bf16_t* W3f    = (bf16_t*)(ws + 64986496ULL);   // 1024x256 frag-major
    bf16_t* W4f    = (bf16_t*)(ws + 65510784ULL);   // 128x1024 frag-major

    const int RB64 = (NN + 63) / 64;  // 782

    // ---- adjacency + all weight packs in one launch
    hipMemsetAsync(cnt, 0, NN * sizeof(int), stream);
    setup_all<<<NB_BUILD + NB_P1 + NB_P2 + NB_P3 + NB_P4, 256, 0, stream>>>(
        ei, cnt, bkt, W1_rel, W1_root, W2_rel, W2_root,
        W3_rel, W3_root, W4_rel, W4_root, W1f, W2f, W3f, W4f);

    // ---- L1+L2 fused: A=[gather(x)|x]; h1 on-chip;
    //      y2 = h1@W2_rel^T (bf16), h2init = h1@W2_root^T + b2 (bf16)
    fused17<128, 256, 0, 0, 1><<<RB64, 512, 0, stream>>>(x, cnt, bkt, W1f, b1, W2f, b2, y2buf, h2init);

    // ---- h2 = relu(h2init + gather(y2)); encoded = mean-pool(h2), fused
    gather_relu_pool<<<GG, 256, 0, stream>>>(y2buf, h2init, cnt, bkt, batch, h2buf, enc, NN);

    // ---- L3+L4 fused: A=[gather(h2)|h2]; h3 on-chip;
    //      y4 = h3@W4_rel^T (bf16), outF = h3@W4_root^T + b4 (f32, direct)
    fused17<256, 128, 1, 1, 0><<<RB64, 512, 0, stream>>>(h2buf, cnt, bkt, W3f, b3, W4f, b4, y4buf, outF);

    // ---- out = outF + gather(y4)   (y4 bf16 halves neighbor-read traffic)
    gather_add_b16_64<<<(NN * 16 + 255) / 256, 256, 0, stream>>>(y4buf, cnt, bkt, outF);
}

// Round 13
// 258.739 us; speedup vs baseline: 8.6803x; 1.0028x over previous
//
#include <hip/hip_runtime.h>
#include <hip/hip_bf16.h>

typedef __hip_bfloat16 bf16_t;
typedef __attribute__((ext_vector_type(8))) short short8;
typedef __attribute__((ext_vector_type(16))) float floatx16;

static __device__ __forceinline__ float b2f(bf16_t v) { return __bfloat162float(v); }
static __device__ __forceinline__ bf16_t f2b(float v) { return __float2bfloat16(v); }
static __device__ __forceinline__ float us2f(unsigned short u) {
    union { unsigned int i; float f; } c; c.i = ((unsigned int)u) << 16; return c.f;
}

// LDS-only barrier: does NOT drain vmcnt -> global loads issued before the
// barrier stay in flight across it (used for fused1's weight prefetch).
static __device__ __forceinline__ void barrier_lds() {
    asm volatile("s_waitcnt lgkmcnt(0)" ::: "memory");
    __builtin_amdgcn_s_barrier();
    asm volatile("" ::: "memory");
}

// Problem constants
#define NN 50000
#define EE 200000
#define GG 2048
#define BCAP 64   // in-degree cap; mean deg = 4

union U4 { uint4 v; unsigned short s[8]; };
union U2 { uint2 v; unsigned short s[4]; };

#define FZ16 {0.f,0.f,0.f,0.f,0.f,0.f,0.f,0.f,0.f,0.f,0.f,0.f,0.f,0.f,0.f,0.f}

// 32x32x16 fragment-major layout (A and B operands share it):
//   element (i, k) of an [I x K] K-major matrix lives at
//   ((i/32 * (K/16) + k/16) * 64 + ((k%16)/8)*32 + i%32) * 8 + k%8
// One wave fragment = 64 lanes x short8 = contiguous 1KB.

// ---------------------------------------------------------------------------
// Merged setup: inverted adjacency build + all 4 weight packs in ONE launch
// ---------------------------------------------------------------------------
__device__ __forceinline__ void pack_w1_body(const float* __restrict__ Wa,
                                             const float* __restrict__ Wb,
                                             bf16_t* __restrict__ out,
                                             int K1, int K2, int idx) {
    int K = K1 + K2;
    int KT16 = K >> 4;
    int e = idx & 7;
    int l = (idx >> 3) & 63;
    int tile = idx >> 9;
    int kt = tile % KT16, t = tile / KT16;
    int c = t * 32 + (l & 31);
    int k = kt * 16 + (l >> 5) * 8 + e;
    float v = 0.f;
    if (c < 1000) v = (k < K1) ? Wa[c * K1 + k] : Wb[c * K2 + (k - K1)];
    out[idx] = f2b(v);
}
__device__ __forceinline__ void pack_w2_body(const float* __restrict__ Wa,
                                             const float* __restrict__ Wb,
                                             bf16_t* __restrict__ out,
                                             int OH, int idx) {
    int e = idx & 7;
    int l = (idx >> 3) & 63;
    int tile = idx >> 9;
    int kt2 = tile & 63, o = tile >> 6;   // K=1024 -> 64 k-tiles
    int c = o * 32 + (l & 31);
    int k = kt2 * 16 + (l >> 5) * 8 + e;
    float v = 0.f;
    if (k < 1000) v = (c < OH) ? Wa[c * 1000 + k] : Wb[(c - OH) * 1000 + k];
    out[idx] = f2b(v);
}

#define NB_BUILD 782   // (EE+255)/256
#define NB_P1 512      // 131072/256
#define NB_P2 1024     // 262144/256
#define NB_P3 1024
#define NB_P4 512

__global__ void setup_all(const int* __restrict__ ei, int* __restrict__ cnt,
                          int* __restrict__ bkt,
                          const float* __restrict__ W1_rel, const float* __restrict__ W1_root,
                          const float* __restrict__ W2_rel, const float* __restrict__ W2_root,
                          const float* __restrict__ W3_rel, const float* __restrict__ W3_root,
                          const float* __restrict__ W4_rel, const float* __restrict__ W4_root,
                          bf16_t* __restrict__ W1f, bf16_t* __restrict__ W2f,
                          bf16_t* __restrict__ W3f, bf16_t* __restrict__ W4f) {
    int b = blockIdx.x;
    int tid = threadIdx.x;
    if (b < NB_BUILD) {
        int e = b * 256 + tid;
        if (e < EE) {
            int s = ei[e];
            int d = ei[EE + e];
            int pos = atomicAdd(&cnt[d], 1);
            if (pos < BCAP) bkt[d * BCAP + pos] = s;
        }
    } else if (b < NB_BUILD + NB_P1) {
        pack_w1_body(W1_rel, W1_root, W1f, 64, 64, (b - NB_BUILD) * 256 + tid);
    } else if (b < NB_BUILD + NB_P1 + NB_P2) {
        pack_w2_body(W2_rel, W2_root, W2f, 128, (b - NB_BUILD - NB_P1) * 256 + tid);
    } else if (b < NB_BUILD + NB_P1 + NB_P2 + NB_P3) {
        pack_w1_body(W3_rel, W3_root, W3f, 128, 128, (b - NB_BUILD - NB_P1 - NB_P2) * 256 + tid);
    } else {
        pack_w2_body(W4_rel, W4_root, W4f, 64, (b - NB_BUILD - NB_P1 - NB_P2 - NB_P3) * 256 + tid);
    }
}

// ---------------------------------------------------------------------------
// Per-graph fused gather+relu+mean-pool (one block = one graph; batch sorted).
// ---------------------------------------------------------------------------
__global__ void gather_relu_pool(const bf16_t* __restrict__ y2, const bf16_t* __restrict__ init,
                                 const int* __restrict__ cnt, const int* __restrict__ bkt,
                                 const int* __restrict__ batch,
                                 bf16_t* __restrict__ h2, float* __restrict__ enc, int Nn) {
    int g = blockIdx.x;
    __shared__ int s_lo, s_hi;
    __shared__ float red[16][128];   // 8KB partials
    if (threadIdx.x == 0) {
        int lo = 0, hi = Nn;
        while (lo < hi) { int mid = (lo + hi) >> 1; if (batch[mid] < g) lo = mid + 1; else hi = mid; }
        s_lo = lo;
        hi = Nn;
        while (lo < hi) { int mid = (lo + hi) >> 1; if (batch[mid] < g + 1) lo = mid + 1; else hi = mid; }
        s_hi = lo;
    }
    __syncthreads();
    const int lo = s_lo, hi = s_hi;
    const int slot = threadIdx.x >> 4;      // 0..15 node slot
    const int j = (threadIdx.x & 15) * 8;   // col group
    float psum[8] = {0.f,0.f,0.f,0.f,0.f,0.f,0.f,0.f};
    for (int n = lo + slot; n < hi; n += 16) {
        int c = cnt[n]; if (c > BCAP) c = BCAP;
        const int* bp = bkt + n * BCAP;
        U4 u; u.v = *(const uint4*)(init + (size_t)n * 128 + j);
        float s[8];
        #pragma unroll
        for (int k = 0; k < 8; ++k) s[k] = us2f(u.s[k]);
        int i = 0;
        for (; i + 4 <= c; i += 4) {
            int s0 = bp[i], s1 = bp[i + 1], s2 = bp[i + 2], s3 = bp[i + 3];
            U4 w0, w1, w2, w3;
            w0.v = *(const uint4*)(y2 + (size_t)s0 * 128 + j);
            w1.v = *(const uint4*)(y2 + (size_t)s1 * 128 + j);
            w2.v = *(const uint4*)(y2 + (size_t)s2 * 128 + j);
            w3.v = *(const uint4*)(y2 + (size_t)s3 * 128 + j);
            #pragma unroll
            for (int k = 0; k < 8; ++k)
                s[k] += (us2f(w0.s[k]) + us2f(w1.s[k])) + (us2f(w2.s[k]) + us2f(w3.s[k]));
        }
        for (; i < c; ++i) {
            U4 w; w.v = *(const uint4*)(y2 + (size_t)bp[i] * 128 + j);
            #pragma unroll
            for (int k = 0; k < 8; ++k) s[k] += us2f(w.s[k]);
        }
        alignas(16) bf16_t ob[8];
        #pragma unroll
        for (int k = 0; k < 8; ++k) {
            s[k] = fmaxf(s[k], 0.f);
            psum[k] += s[k];
            ob[k] = f2b(s[k]);
        }
        *(uint4*)(h2 + (size_t)n * 128 + j) = *(const uint4*)ob;
    }
    #pragma unroll
    for (int k = 0; k < 8; ++k) red[slot][j + k] = psum[k];
    __syncthreads();
    if (threadIdx.x < 128) {
        int c = threadIdx.x;
        float tot = 0.f;
        #pragma unroll
        for (int r = 0; r < 16; ++r) tot += red[r][c];
        float n = (float)((hi - lo) > 0 ? (hi - lo) : 1);
        enc[(size_t)g * 128 + c] = tot / n;
    }
}

// outF[n] += sum nbr y4   (y4 bf16 [N,64]; outF f32 in-place on d_out)
__global__ void gather_add_b16_64(const bf16_t* __restrict__ y4, const int* __restrict__ cnt,
                                  const int* __restrict__ bkt, float* __restrict__ outF) {
    int t = blockIdx.x * 256 + threadIdx.x;
    int n = t >> 4;
    if (n >= NN) return;
    int j = (t & 15) * 4;
    int c = cnt[n]; if (c > BCAP) c = BCAP;
    const int* bp = bkt + n * BCAP;
    float4 sum = *(const float4*)(outF + n * 64 + j);
    int i = 0;
    for (; i + 4 <= c; i += 4) {
        int s0 = bp[i], s1 = bp[i + 1], s2 = bp[i + 2], s3 = bp[i + 3];
        U2 w0, w1, w2, w3;
        w0.v = *(const uint2*)(y4 + (size_t)s0 * 64 + j);
        w1.v = *(const uint2*)(y4 + (size_t)s1 * 64 + j);
        w2.v = *(const uint2*)(y4 + (size_t)s2 * 64 + j);
        w3.v = *(const uint2*)(y4 + (size_t)s3 * 64 + j);
        sum.x += (us2f(w0.s[0]) + us2f(w1.s[0])) + (us2f(w2.s[0]) + us2f(w3.s[0]));
        sum.y += (us2f(w0.s[1]) + us2f(w1.s[1])) + (us2f(w2.s[1]) + us2f(w3.s[1]));
        sum.z += (us2f(w0.s[2]) + us2f(w1.s[2])) + (us2f(w2.s[2]) + us2f(w3.s[2]));
        sum.w += (us2f(w0.s[3]) + us2f(w1.s[3])) + (us2f(w2.s[3]) + us2f(w3.s[3]));
    }
    for (; i < c; ++i) {
        U2 w; w.v = *(const uint2*)(y4 + (size_t)bp[i] * 64 + j);
        sum.x += us2f(w.s[0]); sum.y += us2f(w.s[1]);
        sum.z += us2f(w.s[2]); sum.w += us2f(w.s[3]);
    }
    *(float4*)(outF + n * 64 + j) = sum;
}

// ---------------------------------------------------------------------------
// Fused gather + two-GEMM v18 = hybrid of v16/v17 based on r12 A/B:
//   K=128 (fused1, NOUT=256): v17 path — PD=4 cross-phase w1 prefetch (16
//     VGPRs live across barriers, cheap) + 8-deep stage-2 with W2 dedup.
//     r12 showed this gained ~4-5us.
//   K=256 (fused2, NOUT=128): v16 path — 8-deep batches, no cross-phase
//     prefetch. r12 showed PD=8 prefetch (32 VGPRs live across H-write)
//     REGRESSED 69.7->73.4; reverted to best measured config.
//   Block = 64 nodes (2 node-tiles of 32), 512 threads = 8 waves.
// Outputs: outcol < NOUT/2 -> yout (bf16 if YBF16), else initout (+bias2).
// ---------------------------------------------------------------------------
template <int K, int NOUT, int F32OUT, int YBF16, int SRCF32>
__global__ __launch_bounds__(512, 4) void fused18(
    const void* __restrict__ src, const int* __restrict__ cnt,
    const int* __restrict__ bkt,
    const bf16_t* __restrict__ W1f, const float* __restrict__ bias1,
    const bf16_t* __restrict__ W2f, const float* __restrict__ bias2,
    void* __restrict__ yout, void* __restrict__ initout)
{
    constexpr int KT16 = K / 16;      // A k-tiles (16-deep): 8 or 16
    constexpr bool PREF = (K == 128); // cross-phase prefetch only when PD=4
    constexpr int PD   = KT16 / 2;    // w1 batch depth (4 or 8); 2 rounds
    constexpr int OT32 = NOUT / 32;   // out 32-col tiles (8 or 4)
    constexpr int OCT2 = OT32 / 4;    // out tiles per wave, old mapping (2 or 1)
    constexpr int NACC = (NOUT == 256) ? 2 : OCT2;
    constexpr int OH   = NOUT / 2;
    constexpr int SW   = K / 2;       // source row width (64 f32 / 128 bf16)
    constexpr int HALF = K / 16;      // 8-col groups per half (8 or 16)
    constexpr int STR  = F32OUT ? (NOUT + 4) : (NOUT + 8);
    __shared__ float b1sl[1024];
    __shared__ float b2sl[128];
    __shared__ __align__(16) char smem[(size_t)64 * K * 2 + 64 * 256 * 2];
    bf16_t* Asl = (bf16_t*)smem;                        // frag-major A tile [64*K]
    bf16_t* Hsl = (bf16_t*)(smem + (size_t)64 * K * 2); // frag-major H chunk [64*256]

    const int tid  = threadIdx.x;
    const int lane = tid & 63;
    const int wn   = tid >> 6;        // 0..7
    const int l31  = lane & 31;
    const int hi   = lane >> 5;
    const int og   = wn >> 1;         // old stage-2 out-col group
    const int wr   = wn & 1;          // old stage-2 node-tile
    const int bm0  = blockIdx.x * 64;

    for (int i = tid; i < 1024; i += 512) b1sl[i] = (i < 1000) ? bias1[i] : 0.f;
    if (tid < OH) b2sl[tid] = bias2[tid];

    // ---- prologue: gather + own-copy directly into Asl (frag-major)
    #pragma unroll
    for (int it = 0; it < (2 * 64 * HALF) / 512; ++it) {
        int task = it * 512 + tid;
        const bool own = task >= 64 * HALF;
        int t2 = own ? task - 64 * HALF : task;
        int i = t2 / HALF, s = t2 - (t2 / HALF) * HALF;
        int n = bm0 + i;
        int j = s * 8;
        float sum[8] = {0.f, 0.f, 0.f, 0.f, 0.f, 0.f, 0.f, 0.f};
        if (n < NN) {
            if (!own) {
                int c = cnt[n]; if (c > BCAP) c = BCAP;
                const int* bp = bkt + n * BCAP;
                int e = 0;
                for (; e + 4 <= c; e += 4) {
                    int s0 = bp[e], s1 = bp[e + 1], s2 = bp[e + 2], s3 = bp[e + 3];
                    if (SRCF32) {
                        const float* r0 = (const float*)src + (size_t)s0 * SW + j;
                        const float* r1 = (const float*)src + (size_t)s1 * SW + j;
                        const float* r2 = (const float*)src + (size_t)s2 * SW + j;
                        const float* r3 = (const float*)src + (size_t)s3 * SW + j;
                        float4 a0 = *(const float4*)r0, b0 = *(const float4*)(r0 + 4);
                        float4 a1 = *(const float4*)r1, b1 = *(const float4*)(r1 + 4);
                        float4 a2 = *(const float4*)r2, b2 = *(const float4*)(r2 + 4);
                        float4 a3 = *(const float4*)r3, b3 = *(const float4*)(r3 + 4);
                        sum[0] += (a0.x + a1.x) + (a2.x + a3.x);
                        sum[1] += (a0.y + a1.y) + (a2.y + a3.y);
                        sum[2] += (a0.z + a1.z) + (a2.z + a3.z);
                        sum[3] += (a0.w + a1.w) + (a2.w + a3.w);
                        sum[4] += (b0.x + b1.x) + (b2.x + b3.x);
                        sum[5] += (b0.y + b1.y) + (b2.y + b3.y);
                        sum[6] += (b0.z + b1.z) + (b2.z + b3.z);
                        sum[7] += (b0.w + b1.w) + (b2.w + b3.w);
                    } else {
                        U4 w0, w1, w2, w3;
                        w0.v = *(const uint4*)((const bf16_t*)src + (size_t)s0 * SW + j);
                        w1.v = *(const uint4*)((const bf16_t*)src + (size_t)s1 * SW + j);
                        w2.v = *(const uint4*)((const bf16_t*)src + (size_t)s2 * SW + j);
                        w3.v = *(const uint4*)((const bf16_t*)src + (size_t)s3 * SW + j);
                        #pragma unroll
                        for (int k = 0; k < 8; ++k)
                            sum[k] += (us2f(w0.s[k]) + us2f(w1.s[k])) + (us2f(w2.s[k]) + us2f(w3.s[k]));
                    }
                }
                for (; e < c; ++e) {
                    int sn = bp[e];
                    if (SRCF32) {
                        const float* r = (const float*)src + (size_t)sn * SW + j;
                        float4 a = *(const float4*)r;
                        float4 b = *(const float4*)(r + 4);
                        sum[0] += a.x; sum[1] += a.y; sum[2] += a.z; sum[3] += a.w;
                        sum[4] += b.x; sum[5] += b.y; sum[6] += b.z; sum[7] += b.w;
                    } else {
                        U4 w; w.v = *(const uint4*)((const bf16_t*)src + (size_t)sn * SW + j);
                        #pragma unroll
                        for (int k = 0; k < 8; ++k) sum[k] += us2f(w.s[k]);
                    }
                }
            } else {
                if (SRCF32) {
                    const float* r = (const float*)src + (size_t)n * SW + j;
                    float4 a = *(const float4*)r;
                    float4 b = *(const float4*)(r + 4);
                    sum[0] = a.x; sum[1] = a.y; sum[2] = a.z; sum[3] = a.w;
                    sum[4] = b.x; sum[5] = b.y; sum[6] = b.z; sum[7] = b.w;
                } else {
                    U4 w; w.v = *(const uint4*)((const bf16_t*)src + (size_t)n * SW + j);
                    #pragma unroll
                    for (int k = 0; k < 8; ++k) sum[k] = us2f(w.s[k]);
                }
            }
        }
        int cc = (own ? K / 2 : 0) + j;           // column in A's K-space
        int off = (((i >> 5) * KT16 + (cc >> 4)) * 64 + ((cc >> 3) & 1) * 32 + (i & 31)) * 8;
        alignas(16) bf16_t ob[8];
        #pragma unroll
        for (int k = 0; k < 8; ++k) ob[k] = f2b(sum[k]);
        *(uint4*)(&Asl[off]) = *(const uint4*)ob;
    }

    floatx16 acc2[NACC];
    #pragma unroll
    for (int oo = 0; oo < NACC; ++oo) acc2[oo] = (floatx16)FZ16;

    // (PREF only) prefetch chunk-0's first w1 batch BEFORE the barrier
    short8 w1pre[PD];
    if (PREF) {
        const bf16_t* w1p0 = W1f + (((size_t)(0 * 8 + wn) * KT16) * 64 + lane) * 8;
        #pragma unroll
        for (int u = 0; u < PD; ++u)
            w1pre[u] = *(const short8*)(w1p0 + (size_t)u * 512);
    }

    barrier_lds();   // Asl + biases ready

    for (int ci = 0; ci < 4; ++ci) {
        // ---- stage 1
        floatx16 acc1[2];
        acc1[0] = (floatx16)FZ16;
        acc1[1] = (floatx16)FZ16;

        const bf16_t* w1p = W1f + (((size_t)(ci * 8 + wn) * KT16) * 64 + lane) * 8;
        if (PREF) {
            // v17 path: batch 0 from w1pre (in flight across barrier)
            __builtin_amdgcn_s_setprio(1);
            #pragma unroll
            for (int u = 0; u < PD; ++u) {
                short8 av0 = *(const short8*)&Asl[((0 * KT16 + u) * 64 + lane) * 8];
                acc1[0] = __builtin_amdgcn_mfma_f32_32x32x16_bf16(w1pre[u], av0, acc1[0], 0, 0, 0);
                short8 av1 = *(const short8*)&Asl[((1 * KT16 + u) * 64 + lane) * 8];
                acc1[1] = __builtin_amdgcn_mfma_f32_32x32x16_bf16(w1pre[u], av1, acc1[1], 0, 0, 0);
            }
            __builtin_amdgcn_s_setprio(0);
            short8 w1v[PD];
            #pragma unroll
            for (int u = 0; u < PD; ++u)
                w1v[u] = *(const short8*)(w1p + (size_t)(PD + u) * 512);
            __builtin_amdgcn_s_setprio(1);
            #pragma unroll
            for (int u = 0; u < PD; ++u) {
                int kk = PD + u;
                short8 av0 = *(const short8*)&Asl[((0 * KT16 + kk) * 64 + lane) * 8];
                acc1[0] = __builtin_amdgcn_mfma_f32_32x32x16_bf16(w1v[u], av0, acc1[0], 0, 0, 0);
                short8 av1 = *(const short8*)&Asl[((1 * KT16 + kk) * 64 + lane) * 8];
                acc1[1] = __builtin_amdgcn_mfma_f32_32x32x16_bf16(w1v[u], av1, acc1[1], 0, 0, 0);
            }
            __builtin_amdgcn_s_setprio(0);
        } else {
            // v16 path: 8-deep batches, 2 rounds, no cross-phase prefetch
            #pragma unroll 1
            for (int kh = 0; kh < KT16 / 8; ++kh) {
                short8 w1v[8];
                #pragma unroll
                for (int u = 0; u < 8; ++u)
                    w1v[u] = *(const short8*)(w1p + (size_t)(kh * 8 + u) * 512);
                __builtin_amdgcn_s_setprio(1);
                #pragma unroll
                for (int u = 0; u < 8; ++u) {
                    int kk = kh * 8 + u;
                    short8 av0 = *(const short8*)&Asl[((0 * KT16 + kk) * 64 + lane) * 8];
                    acc1[0] = __builtin_amdgcn_mfma_f32_32x32x16_bf16(w1v[u], av0, acc1[0], 0, 0, 0);
                    short8 av1 = *(const short8*)&Asl[((1 * KT16 + kk) * 64 + lane) * 8];
                    acc1[1] = __builtin_amdgcn_mfma_f32_32x32x16_bf16(w1v[u], av1, acc1[1], 0, 0, 0);
                }
                __builtin_amdgcn_s_setprio(0);
            }
        }

        barrier_lds();   // previous chunk's stage-2 readers done with Hsl

        // bias+relu -> frag-major H; C/D: node=l31, hcol32=(r&3)+8*(r>>2)+4*hi
        #pragma unroll
        for (int nt2 = 0; nt2 < 2; ++nt2) {
            #pragma unroll
            for (int g = 0; g < 4; ++g) {
                float4 bv = *(const float4*)&b1sl[ci * 256 + wn * 32 + 8 * g + 4 * hi];
                const float* bvp = (const float*)&bv;
                alignas(8) bf16_t hb[4];
                #pragma unroll
                for (int e = 0; e < 4; ++e)
                    hb[e] = f2b(fmaxf(acc1[nt2][4 * g + e] + bvp[e], 0.f));
                int off = ((nt2 * 16 + wn * 2 + (g >> 1)) * 64 + (g & 1) * 32 + l31) * 8 + 4 * hi;
                *(uint2*)&Hsl[off] = *(const uint2*)hb;
            }
        }

        barrier_lds();   // H chunk visible

        // ---- stage 2
        if (NOUT == 256) {
            // dedup mapping + v17 cross-phase w1 prefetch (PD=4, cheap)
            const int cin = (ci < 3) ? ci + 1 : 0;
            const bf16_t* w1pn = W1f + (((size_t)(cin * 8 + wn) * KT16) * 64 + lane) * 8;
            const bf16_t* w2p = W2f + (((size_t)wn * 64 + ci * 16) * 64 + lane) * 8;
            short8 w2v[8];
            // round 0: ks 0..7
            #pragma unroll
            for (int u = 0; u < 8; ++u)
                w2v[u] = *(const short8*)(w2p + (size_t)u * 512);
            __builtin_amdgcn_s_setprio(1);
            #pragma unroll
            for (int u = 0; u < 8; ++u) {
                short8 hf0 = *(const short8*)&Hsl[((0 * 16 + u) * 64 + lane) * 8];
                acc2[0] = __builtin_amdgcn_mfma_f32_32x32x16_bf16(w2v[u], hf0, acc2[0], 0, 0, 0);
                short8 hf1 = *(const short8*)&Hsl[((1 * 16 + u) * 64 + lane) * 8];
                acc2[1] = __builtin_amdgcn_mfma_f32_32x32x16_bf16(w2v[u], hf1, acc2[1], 0, 0, 0);
            }
            __builtin_amdgcn_s_setprio(0);
            // round 1: ks 8..15 + w1 prefetch for cin
            #pragma unroll
            for (int u = 0; u < 8; ++u)
                w2v[u] = *(const short8*)(w2p + (size_t)(8 + u) * 512);
            #pragma unroll
            for (int u = 0; u < PD; ++u)
                w1pre[u] = *(const short8*)(w1pn + (size_t)u * 512);
            __builtin_amdgcn_s_setprio(1);
            #pragma unroll
            for (int u = 0; u < 8; ++u) {
                int ks = 8 + u;
                short8 hf0 = *(const short8*)&Hsl[((0 * 16 + ks) * 64 + lane) * 8];
                acc2[0] = __builtin_amdgcn_mfma_f32_32x32x16_bf16(w2v[u], hf0, acc2[0], 0, 0, 0);
                short8 hf1 = *(const short8*)&Hsl[((1 * 16 + ks) * 64 + lane) * 8];
                acc2[1] = __builtin_amdgcn_mfma_f32_32x32x16_bf16(w2v[u], hf1, acc2[1], 0, 0, 0);
            }
            __builtin_amdgcn_s_setprio(0);
        } else {
            // v16 path: wave (og, wr): 1 out-tile x node-tile wr; 8-deep
            const bf16_t* w2p = W2f + ((((size_t)og) * 64 + ci * 16) * 64 + lane) * 8;
            #pragma unroll 1
            for (int kg = 0; kg < 2; ++kg) {
                short8 w2v[8];
                #pragma unroll
                for (int u = 0; u < 8; ++u)
                    w2v[u] = *(const short8*)(w2p + (size_t)(kg * 8 + u) * 512);
                __builtin_amdgcn_s_setprio(1);
                #pragma unroll
                for (int u = 0; u < 8; ++u) {
                    int ks = kg * 8 + u;
                    short8 hf = *(const short8*)&Hsl[((wr * 16 + ks) * 64 + lane) * 8];
                    acc2[0] = __builtin_amdgcn_mfma_f32_32x32x16_bf16(w2v[u], hf, acc2[0], 0, 0, 0);
                }
                __builtin_amdgcn_s_setprio(0);
            }
        }
    }

    // ---- epilogue: stage acc2(+bias) into LDS [node][outcol] (padded),
    //      then copy full rows out with coalesced line-aligned stores.
    barrier_lds();   // everyone done reading Hsl/Asl
    if (NOUT == 256) {
        bf16_t* st = (bf16_t*)smem;
        #pragma unroll
        for (int nt2 = 0; nt2 < 2; ++nt2) {
            const int r = nt2 * 32 + l31;
            #pragma unroll
            for (int g = 0; g < 4; ++g) {
                int oc = wn * 32 + 8 * g + 4 * hi;
                const bool isInit = (oc >= OH);
                int col = isInit ? oc - OH : oc;
                float4 bv = isInit ? *(const float4*)&b2sl[col]
                                   : make_float4(0.f, 0.f, 0.f, 0.f);
                const float* bvp = (const float*)&bv;
                alignas(8) bf16_t ob[4];
                #pragma unroll
                for (int e = 0; e < 4; ++e) ob[e] = f2b(acc2[nt2][4 * g + e] + bvp[e]);
                *(uint2*)&st[r * STR + oc] = *(const uint2*)ob;
            }
        }
    } else {
        const int r = wr * 32 + l31;   // node row within block
        float* st = (float*)smem;      // f32 staging (F32OUT=1 for NOUT=128)
        #pragma unroll
        for (int oo = 0; oo < OCT2; ++oo) {
            int o = og * OCT2 + oo;
            #pragma unroll
            for (int g = 0; g < 4; ++g) {
                int oc = o * 32 + 8 * g + 4 * hi;
                const bool isInit = (oc >= OH);
                int col = isInit ? oc - OH : oc;
                float4 bv = isInit ? *(const float4*)&b2sl[col]
                                   : make_float4(0.f, 0.f, 0.f, 0.f);
                const float* bvp = (const float*)&bv;
                float v[4];
                #pragma unroll
                for (int e = 0; e < 4; ++e) v[e] = acc2[oo][4 * g + e] + bvp[e];
                *(float4*)&st[r * STR + oc] = make_float4(v[0], v[1], v[2], v[3]);
            }
        }
    }
    barrier_lds();   // staging written
    if (NOUT == 256) {
        constexpr int CH = NOUT / 8;
        constexpr int CHH = CH / 2;
        const bf16_t* st = (const bf16_t*)smem;
        for (int t = tid; t < 64 * CH; t += 512) {
            int nd = t / CH, c = t - (t / CH) * CH;
            int node = bm0 + nd;
            if (node >= NN) continue;
            const bool isInit = (c >= CHH);
            int ch = isInit ? c - CHH : c;
            uint4 v = *(const uint4*)&st[nd * STR + c * 8];
            bf16_t* dst = isInit ? (bf16_t*)initout : (bf16_t*)yout;
            *(uint4*)(dst + (size_t)node * OH + ch * 8) = v;
        }
    } else {
        const float* st = (const float*)smem;
        for (int t = tid; t < 64 * (OH / 4); t += 512) {
            int nd = t / (OH / 4), c = t - (t / (OH / 4)) * (OH / 4);
            int node = bm0 + nd;
            if (node >= NN) continue;
            float4 v = *(const float4*)&st[nd * STR + OH + c * 4];
            *(float4*)((float*)initout + (size_t)node * OH + c * 4) = v;
        }
        if (YBF16) {
            for (int t = tid; t < 64 * (OH / 8); t += 512) {
                int nd = t / (OH / 8), c = t - (t / (OH / 8)) * (OH / 8);
                int node = bm0 + nd;
                if (node >= NN) continue;
                float4 a = *(const float4*)&st[nd * STR + c * 8];
                float4 b = *(const float4*)&st[nd * STR + c * 8 + 4];
                alignas(16) bf16_t ob[8];
                ob[0] = f2b(a.x); ob[1] = f2b(a.y); ob[2] = f2b(a.z); ob[3] = f2b(a.w);
                ob[4] = f2b(b.x); ob[5] = f2b(b.y); ob[6] = f2b(b.z); ob[7] = f2b(b.w);
                *(uint4*)((bf16_t*)yout + (size_t)node * OH + c * 8) = *(const uint4*)ob;
            }
        } else {
            for (int t = tid; t < 64 * (OH / 4); t += 512) {
                int nd = t / (OH / 4), c = t - (t / (OH / 4)) * (OH / 4);
                int node = bm0 + nd;
                if (node >= NN) continue;
                float4 v = *(const float4*)&st[nd * STR + c * 4];
                *(float4*)((float*)yout + (size_t)node * OH + c * 4) = v;
            }
        }
    }
}

// ---------------------------------------------------------------------------
// Launch
// ---------------------------------------------------------------------------
extern "C" void kernel_launch(void* const* d_in, const int* in_sizes, int n_in,
                              void* d_out, int out_size, void* d_ws, size_t ws_size,
                              hipStream_t stream) {
    const float* x       = (const float*)d_in[0];
    const int*   ei      = (const int*)d_in[1];
    const int*   batch   = (const int*)d_in[2];
    const float* W1_rel  = (const float*)d_in[3];
    const float* b1      = (const float*)d_in[4];
    const float* W1_root = (const float*)d_in[5];
    const float* W2_rel  = (const float*)d_in[6];
    const float* b2      = (const float*)d_in[7];
    const float* W2_root = (const float*)d_in[8];
    const float* W3_rel  = (const float*)d_in[9];
    const float* b3      = (const float*)d_in[10];
    const float* W3_root = (const float*)d_in[11];
    const float* W4_rel  = (const float*)d_in[12];
    const float* b4      = (const float*)d_in[13];
    const float* W4_root = (const float*)d_in[14];

    float* outF = (float*)d_out;            // [N,64] then [G,128]
    float* enc  = outF + NN * 64;

    char* ws = (char*)d_ws;                         // ~66 MB
    bf16_t* y2buf  = (bf16_t*)(ws + 0);             // [N,128] bf16
    bf16_t* h2init = (bf16_t*)(ws + 12800000ULL);   // [N,128] bf16
    bf16_t* h2buf  = (bf16_t*)(ws + 25600000ULL);   // [N,128] bf16
    bf16_t* y4buf  = (bf16_t*)(ws + 38400000ULL);   // [N,64] bf16
    int*    cnt    = (int*)(ws + 51200000ULL);      // [N]
    int*    bkt    = (int*)(ws + 51400064ULL);      // [N*64]
    bf16_t* W1f    = (bf16_t*)(ws + 64200064ULL);   // 1024x128 frag-major
    bf16_t* W2f    = (bf16_t*)(ws + 64462208ULL);   // 256x1024 frag-major
    bf16_t* W3f    = (bf16_t*)(ws + 64986496ULL);   // 1024x256 frag-major
    bf16_t* W4f    = (bf16_t*)(ws + 65510784ULL);   // 128x1024 frag-major

    const int RB64 = (NN + 63) / 64;  // 782

    // ---- adjacency + all weight packs in one launch
    hipMemsetAsync(cnt, 0, NN * sizeof(int), stream);
    setup_all<<<NB_BUILD + NB_P1 + NB_P2 + NB_P3 + NB_P4, 256, 0, stream>>>(
        ei, cnt, bkt, W1_rel, W1_root, W2_rel, W2_root,
        W3_rel, W3_root, W4_rel, W4_root, W1f, W2f, W3f, W4f);

    // ---- L1+L2 fused: A=[gather(x)|x]; h1 on-chip;
    //      y2 = h1@W2_rel^T (bf16), h2init = h1@W2_root^T + b2 (bf16)
    fused18<128, 256, 0, 0, 1><<<RB64, 512, 0, stream>>>(x, cnt, bkt, W1f, b1, W2f, b2, y2buf, h2init);

    // ---- h2 = relu(h2init + gather(y2)); encoded = mean-pool(h2), fused
    gather_relu_pool<<<GG, 256, 0, stream>>>(y2buf, h2init, cnt, bkt, batch, h2buf, enc, NN);

    // ---- L3+L4 fused: A=[gather(h2)|h2]; h3 on-chip;
    //      y4 = h3@W4_rel^T (bf16), outF = h3@W4_root^T + b4 (f32, direct)
    fused18<256, 128, 1, 1, 0><<<RB64, 512, 0, stream>>>(h2buf, cnt, bkt, W3f, b3, W4f, b4, y4buf, outF);

    // ---- out = outF + gather(y4)   (y4 bf16 halves neighbor-read traffic)
    gather_add_b16_64<<<(NN * 16 + 255) / 256, 256, 0, stream>>>(y4buf, cnt, bkt, outF);
}